// Round 6
// baseline (227.195 us; speedup 1.0000x reference)
//
#include <hip/hip_runtime.h>
#include <hip/hip_bf16.h>

#define LL 768
#define TOPK 128

// workspace layout (floats)
#define WS_SEQ  0                        // 768*256
#define WS_NODE (WS_SEQ + LL*256)        // 768*32
#define WS_NBR  (WS_NODE + LL*32)        // 768*128 ints
#define WS_SOUT (WS_NBR + LL*TOPK)       // 768*16
#define WS_CSEE (WS_SOUT + LL*16)        // 32
#define WS_FIN  (WS_CSEE + 32)           // 768*2*44
#define WS_E0   (WS_FIN + LL*2*44 + 32)  // 768*128*32 floats

#define FMA_ROW32(ACC, XVAL, WPTR) do {                                   \
    const float _x = (XVAL);                                              \
    const float* __restrict__ _w = (WPTR);                                \
    _Pragma("unroll")                                                     \
    for (int _c = 0; _c < 32; ++_c) ACC[_c] = fmaf(_x, _w[_c], ACC[_c]);  \
  } while (0)

__device__ __forceinline__ float block_sum_256(float v, float* red, int t) {
#pragma unroll
  for (int o = 32; o > 0; o >>= 1) v += __shfl_xor(v, o, 64);
  __syncthreads();
  if ((t & 63) == 0) red[t >> 6] = v;
  __syncthreads();
  return red[0] + red[1] + red[2] + red[3];
}

// ---------------- Kernel P: column sums (LN-linearity hoist for C1) --------
__global__ void kernP(const float* __restrict__ W_ee, float* __restrict__ colsum_ee)
{
  const int c = threadIdx.x;   // 32 threads
  float s = 0.f;
  for (int k = 0; k < 128; ++k) s += W_ee[k*32 + c];
  colsum_ee[c] = s;
}

// ---------------- Kernel A: seq LN, state LN, node MLP + LN ----------------
__global__ __launch_bounds__(256) void kernA(
    const float* __restrict__ msa, const float* __restrict__ state,
    const float* __restrict__ W_en, const float* __restrict__ b_en,
    const float* __restrict__ Wn1, const float* __restrict__ bn1,
    const float* __restrict__ Wn2, const float* __restrict__ bn2,
    float* __restrict__ seq_ln, float* __restrict__ nodeo)
{
  const int i = blockIdx.x, t = threadIdx.x;
  __shared__ float x[256];
  __shared__ float red[4];
  __shared__ float sn[16], n0[32], tn[32], hh[64], n1v[32];

  float v = msa[i*256 + t];
  float mean = block_sum_256(v, red, t) * (1.f/256.f);
  float d = v - mean;
  float var = block_sum_256(d*d, red, t) * (1.f/256.f);
  float xn = d / sqrtf(var + 1e-5f);
  x[t] = xn;
  seq_ln[i*256 + t] = xn;

  if (t < 16) {
    float m2 = 0.f;
    for (int k = 0; k < 16; ++k) m2 += state[i*16 + k];
    m2 *= (1.f/16.f);
    float v2 = 0.f;
    for (int k = 0; k < 16; ++k) { float dd = state[i*16 + k] - m2; v2 += dd*dd; }
    v2 *= (1.f/16.f);
    sn[t] = (state[i*16 + t] - m2) / sqrtf(v2 + 1e-5f);
  }
  __syncthreads();

  if (t < 32) {
    float a = b_en[t];
    for (int k = 0; k < 256; ++k) a = fmaf(x[k], W_en[k*32 + t], a);
    for (int k = 0; k < 16; ++k)  a = fmaf(sn[k], W_en[(256+k)*32 + t], a);
    n0[t] = a;
  }
  __syncthreads();
  if (t < 32) {
    float m = 0.f;
    for (int k = 0; k < 32; ++k) m += n0[k];
    m *= (1.f/32.f);
    float vv = 0.f;
    for (int k = 0; k < 32; ++k) { float dd = n0[k] - m; vv += dd*dd; }
    vv *= (1.f/32.f);
    tn[t] = (n0[t] - m) / sqrtf(vv + 1e-5f);
  }
  __syncthreads();
  if (t < 64) {
    float a = bn1[t];
    for (int k = 0; k < 32; ++k) a = fmaf(tn[k], Wn1[k*64 + t], a);
    hh[t] = fmaxf(a, 0.f);
  }
  __syncthreads();
  if (t < 32) {
    float a = n0[t] + bn2[t];
    for (int k = 0; k < 64; ++k) a = fmaf(hh[k], Wn2[k*32 + t], a);
    n1v[t] = a;
  }
  __syncthreads();
  if (t < 32) {
    float m = 0.f;
    for (int k = 0; k < 32; ++k) m += n1v[k];
    m *= (1.f/32.f);
    float vv = 0.f;
    for (int k = 0; k < 32; ++k) { float dd = n1v[k] - m; vv += dd*dd; }
    vv *= (1.f/32.f);
    nodeo[i*32 + t] = (n1v[t] - m) / sqrtf(vv + 1e-5f);
  }
}

// ---------------- Kernel B: top-128 nearest by D, bitonic (D_bits, j) -------
__global__ __launch_bounds__(256) void kernB(const float* __restrict__ xyz,
                                             int* __restrict__ nbr)
{
  const int i = blockIdx.x, t = threadIdx.x;
  __shared__ unsigned long long keys[1024];
  const float cix = xyz[i*9+3], ciy = xyz[i*9+4], ciz = xyz[i*9+5];

  for (int j = t; j < 1024; j += 256) {
    unsigned long long kk = ~0ull;
    if (j < LL) {
      float dx = __fadd_rn(cix, -xyz[j*9+3]);
      float dy = __fadd_rn(ciy, -xyz[j*9+4]);
      float dz = __fadd_rn(ciz, -xyz[j*9+5]);
      float Dv = sqrtf(__fadd_rn(__fadd_rn(__fadd_rn(__fmul_rn(dx,dx),
                         __fmul_rn(dy,dy)), __fmul_rn(dz,dz)), 1e-8f));
      kk = (((unsigned long long)__float_as_uint(Dv)) << 32) | (unsigned)j;
    }
    keys[j] = kk;
  }
  for (int size = 2; size <= 1024; size <<= 1) {
    for (int stride = size >> 1; stride > 0; stride >>= 1) {
      __syncthreads();
      for (int p = t; p < 512; p += 256) {
        int lo = 2*p - (p & (stride - 1));
        int hi = lo + stride;
        bool up = ((lo & size) == 0);
        unsigned long long a = keys[lo], b = keys[hi];
        if ((a > b) == up) { keys[lo] = b; keys[hi] = a; }
      }
    }
  }
  __syncthreads();
  if (t < TOPK) nbr[i*TOPK + t] = (int)(keys[t] & 0xffffffffu);
}

// ---------------- Kernel C1: edge0 (pre-LN) per selected edge --------------
__global__ __launch_bounds__(256) void kernC1(
    const float* __restrict__ pair, const float* __restrict__ xyz,
    const int* __restrict__ idx,
    const float* __restrict__ W_ee, const float* __restrict__ b_ee,
    const float* __restrict__ colsum_ee,
    const int* __restrict__ nbr, float* __restrict__ e0ws)
{
  const int i = blockIdx.x >> 1, part = blockIdx.x & 1;
  const int t = threadIdx.x, lane = t & 63, wv = t >> 6;
  const int slot = lane & 15, q = lane >> 4;     // q = 0..3 k-quarter
  const int p = part*64 + wv*16 + slot;          // neighbor slot 0..127

  const int j = nbr[i*TOPK + p];
  const float cix = xyz[i*9+3], ciy = xyz[i*9+4], ciz = xyz[i*9+5];
  const float dx = __fadd_rn(cix, -xyz[j*9+3]);
  const float dy = __fadd_rn(ciy, -xyz[j*9+4]);
  const float dz = __fadd_rn(ciz, -xyz[j*9+5]);
  const float Dv = sqrtf(__fadd_rn(__fadd_rn(__fadd_rn(__fmul_rn(dx,dx),
                      __fmul_rn(dy,dy)), __fmul_rn(dz,dz)), 1e-8f));

  const float* prow = pair + (((size_t)i*LL + j) * 128) + q*32;
  float acc[32];
#pragma unroll
  for (int c = 0; c < 32; ++c) acc[c] = 0.f;
  float s = 0.f, ss = 0.f;
#pragma unroll 2
  for (int q4 = 0; q4 < 8; ++q4) {
    float4 v = ((const float4*)prow)[q4];
    s  += (v.x + v.y) + (v.z + v.w);
    ss += v.x*v.x + v.y*v.y + v.z*v.z + v.w*v.w;
    const float* wr = W_ee + (q*32 + q4*4)*32;
    FMA_ROW32(acc, v.x, wr);
    FMA_ROW32(acc, v.y, wr + 32);
    FMA_ROW32(acc, v.z, wr + 64);
    FMA_ROW32(acc, v.w, wr + 96);
  }
  s  += __shfl_xor(s, 16);  s  += __shfl_xor(s, 32);
  ss += __shfl_xor(ss, 16); ss += __shfl_xor(ss, 32);
  const float pm  = s * (1.f/128.f);
  const float pvv = ss * (1.f/128.f) - pm*pm;
  const float prs = 1.f / sqrtf(pvv + 1e-5f);

#pragma unroll
  for (int c = 0; c < 32; ++c) acc[c] *= prs;

#pragma unroll 4
  for (int kk = 0; kk < 16; ++kk) {
    const int k = q*16 + kk;
    float mu = 2.f + (float)k * (20.f/63.f);
    float u  = (Dv - mu) / 0.3125f;
    FMA_ROW32(acc, expf(-(u*u)), W_ee + (128+k)*32);
  }
  if (q == 0) {
    const float offv = (float)(idx[j] - idx[i]);
    const float sg = (offv > 0.f) ? 1.f : ((offv < 0.f) ? -1.f : 0.f);
    const float xsep = sg * logf(fabsf(offv) + 1.f);
    FMA_ROW32(acc, xsep, W_ee + 192*32);
    const float corr = -prs * pm;
#pragma unroll
    for (int c = 0; c < 32; ++c) acc[c] += b_ee[c] + corr * colsum_ee[c];
  }
#pragma unroll
  for (int c = 0; c < 32; ++c) {
    acc[c] += __shfl_xor(acc[c], 16);
    acc[c] += __shfl_xor(acc[c], 32);
  }

  float4* e4 = (float4*)e0ws;
#pragma unroll
  for (int cc = 0; cc < 2; ++cc) {
    const int c4 = q*2 + cc;
    float4 w = make_float4(acc[c4*4], acc[c4*4+1], acc[c4*4+2], acc[c4*4+3]);
    e4[((size_t)i*8 + c4)*128 + p] = w;
  }
}

// ---------------- Kernel C2: edge MLP + message MLP, 64-edge half-tiles ----
// blockIdx = i*2+part (64 edges). thread (g = t>>3, q = t&7): 2 edges
// {g, g+32} x 8 channels. Activations in LDS; 44-float partial -> ws.
__global__ __launch_bounds__(256, 4) void kernC2(
    const float* __restrict__ xyz,
    const float* __restrict__ We1, const float* __restrict__ be1,
    const float* __restrict__ We2, const float* __restrict__ be2,
    const float* __restrict__ Wm1, const float* __restrict__ bm1,
    const float* __restrict__ Wm2, const float* __restrict__ bm2,
    const float* __restrict__ node, const int* __restrict__ nbr,
    const float* __restrict__ e0ws, float* __restrict__ fin2)
{
  const int i = blockIdx.x >> 1, part = blockIdx.x & 1;
  const int t = threadIdx.x;
  const int g = t >> 3, q = t & 7;
  const int lane = t & 63, wv = t >> 6;
  __shared__ float A[64][33];      // e0 -> ed -> e2 -> ed2 (in place)
  __shared__ float Bb[64][65];     // h -> m1
  __shared__ float nd[64][33];     // neighbor node rows
  __shared__ float ni[32];
  __shared__ float relv[64][3];
  __shared__ float mA[64], sgA[64];
  __shared__ float P2[4][44];      // per-wave reduction partials
  __shared__ float fin[44];

  if (t < 32) ni[t] = node[i*32 + t];
  if (t < 128) {  // stage neighbor node rows + rel (64 rows x 2 halves)
    const int pp = t >> 1, hh2 = t & 1;
    const int jj = nbr[i*TOPK + part*64 + pp];
    const float4* nr = (const float4*)(node + jj*32 + hh2*16);
    float4 a0 = nr[0], a1 = nr[1], a2 = nr[2], a3 = nr[3];
    float* dst = &nd[pp][hh2*16];
    dst[0]=a0.x; dst[1]=a0.y; dst[2]=a0.z; dst[3]=a0.w;
    dst[4]=a1.x; dst[5]=a1.y; dst[6]=a1.z; dst[7]=a1.w;
    dst[8]=a2.x; dst[9]=a2.y; dst[10]=a2.z; dst[11]=a2.w;
    dst[12]=a3.x; dst[13]=a3.y; dst[14]=a3.z; dst[15]=a3.w;
    if (hh2 == 0) {
      relv[pp][0] = xyz[jj*9+3] - xyz[i*9+3];
      relv[pp][1] = xyz[jj*9+4] - xyz[i*9+4];
      relv[pp][2] = xyz[jj*9+5] - xyz[i*9+5];
    }
  } else {        // stage e0 rows (64 rows x 2 ch-halves of 16)
    const int tt = t - 128;
    const int pl = tt & 63, hh = tt >> 6;
    const float4* src = (const float4*)e0ws + ((size_t)i*8 + hh*4)*128 + part*64 + pl;
#pragma unroll
    for (int n = 0; n < 4; ++n) {
      float4 v = src[(size_t)n*128];
      A[pl][hh*16 + n*4 + 0] = v.x;
      A[pl][hh*16 + n*4 + 1] = v.y;
      A[pl][hh*16 + n*4 + 2] = v.z;
      A[pl][hh*16 + n*4 + 3] = v.w;
    }
  }
  __syncthreads();

  // LN(A) in place; keep (mean, sigma) to recover raw e0 for the residual
  if (t < 64) {
    float mm = 0.f;
#pragma unroll
    for (int c = 0; c < 32; ++c) mm += A[t][c];
    mm *= (1.f/32.f);
    float vv = 0.f;
#pragma unroll
    for (int c = 0; c < 32; ++c) { float dd = A[t][c]-mm; vv += dd*dd; }
    vv *= (1.f/32.f);
    const float sg = sqrtf(vv + 1e-5f);
    const float rs = 1.f / sg;
#pragma unroll
    for (int c = 0; c < 32; ++c) A[t][c] = (A[t][c]-mm)*rs;
    mA[t] = mm; sgA[t] = sg;
  }
  __syncthreads();

  // ---- h = relu(ed @ We1 + be1): 2 edges x 8 ch per thread ----
  {
    float hacc[2][8];
#pragma unroll
    for (int m = 0; m < 2; ++m)
#pragma unroll
      for (int c = 0; c < 8; ++c) hacc[m][c] = 0.f;
#pragma unroll 4
    for (int k = 0; k < 32; ++k) {
      const float4 w0 = *(const float4*)(We1 + k*64 + q*8);
      const float4 w1 = *(const float4*)(We1 + k*64 + q*8 + 4);
      const float a0 = A[g][k], a1 = A[g+32][k];
#pragma unroll
      for (int m = 0; m < 2; ++m) {
        const float av = m ? a1 : a0;
        hacc[m][0] = fmaf(av, w0.x, hacc[m][0]);
        hacc[m][1] = fmaf(av, w0.y, hacc[m][1]);
        hacc[m][2] = fmaf(av, w0.z, hacc[m][2]);
        hacc[m][3] = fmaf(av, w0.w, hacc[m][3]);
        hacc[m][4] = fmaf(av, w1.x, hacc[m][4]);
        hacc[m][5] = fmaf(av, w1.y, hacc[m][5]);
        hacc[m][6] = fmaf(av, w1.z, hacc[m][6]);
        hacc[m][7] = fmaf(av, w1.w, hacc[m][7]);
      }
    }
#pragma unroll
    for (int m = 0; m < 2; ++m) {
      const int e = g + 32*m;
#pragma unroll
      for (int c = 0; c < 8; ++c)
        Bb[e][8*q + c] = fmaxf(hacc[m][c] + be1[8*q + c], 0.f);
    }
  }
  __syncthreads();

  // ---- e2 = e0raw + h @ We2 + be2: 2 edges x 4 ch per thread ----
  {
    float e2a[2][4];
#pragma unroll
    for (int m = 0; m < 2; ++m)
#pragma unroll
      for (int c = 0; c < 4; ++c) e2a[m][c] = 0.f;
#pragma unroll 4
    for (int k = 0; k < 64; ++k) {
      const float4 w = *(const float4*)(We2 + k*32 + q*4);
      const float a0 = Bb[g][k], a1 = Bb[g+32][k];
#pragma unroll
      for (int m = 0; m < 2; ++m) {
        const float av = m ? a1 : a0;
        e2a[m][0] = fmaf(av, w.x, e2a[m][0]);
        e2a[m][1] = fmaf(av, w.y, e2a[m][1]);
        e2a[m][2] = fmaf(av, w.z, e2a[m][2]);
        e2a[m][3] = fmaf(av, w.w, e2a[m][3]);
      }
    }
    __syncthreads();   // all h reads done before A overwrite? (A!=Bb) — keeps order safe
#pragma unroll
    for (int m = 0; m < 2; ++m) {
      const int e = g + 32*m;
      const float sg = sgA[e], mm = mA[e];
#pragma unroll
      for (int c = 0; c < 4; ++c) {
        const int ch = 4*q + c;
        const float e0raw = fmaf(A[e][ch], sg, mm);   // undo LN
        A[e][ch] = e2a[m][c] + e0raw + be2[ch];
      }
    }
  }
  __syncthreads();

  // LN(e2) in place
  if (t < 64) {
    float mm = 0.f;
#pragma unroll
    for (int c = 0; c < 32; ++c) mm += A[t][c];
    mm *= (1.f/32.f);
    float vv = 0.f;
#pragma unroll
    for (int c = 0; c < 32; ++c) { float dd = A[t][c]-mm; vv += dd*dd; }
    vv *= (1.f/32.f);
    const float rs = 1.f / sqrtf(vv + 1e-5f);
#pragma unroll
    for (int c = 0; c < 32; ++c) A[t][c] = (A[t][c]-mm)*rs;
  }
  __syncthreads();

  // ---- m1 = relu([ni, nj, ed2] @ Wm1 + bm1): 2 edges x 8 ch ----
  {
    float tmp[8];   // ni part — same for all edges
#pragma unroll
    for (int c = 0; c < 8; ++c) tmp[c] = bm1[8*q + c];
#pragma unroll 4
    for (int k = 0; k < 32; ++k) {
      const float4 w0 = *(const float4*)(Wm1 + k*64 + q*8);
      const float4 w1 = *(const float4*)(Wm1 + k*64 + q*8 + 4);
      const float av = ni[k];
      tmp[0] = fmaf(av, w0.x, tmp[0]); tmp[1] = fmaf(av, w0.y, tmp[1]);
      tmp[2] = fmaf(av, w0.z, tmp[2]); tmp[3] = fmaf(av, w0.w, tmp[3]);
      tmp[4] = fmaf(av, w1.x, tmp[4]); tmp[5] = fmaf(av, w1.y, tmp[5]);
      tmp[6] = fmaf(av, w1.z, tmp[6]); tmp[7] = fmaf(av, w1.w, tmp[7]);
    }
    float macc[2][8];
#pragma unroll
    for (int m = 0; m < 2; ++m)
#pragma unroll
      for (int c = 0; c < 8; ++c) macc[m][c] = 0.f;
#pragma unroll 4
    for (int k = 0; k < 32; ++k) {  // h_j part
      const float4 w0 = *(const float4*)(Wm1 + (32+k)*64 + q*8);
      const float4 w1 = *(const float4*)(Wm1 + (32+k)*64 + q*8 + 4);
      const float a0 = nd[g][k], a1 = nd[g+32][k];
#pragma unroll
      for (int m = 0; m < 2; ++m) {
        const float av = m ? a1 : a0;
        macc[m][0] = fmaf(av, w0.x, macc[m][0]);
        macc[m][1] = fmaf(av, w0.y, macc[m][1]);
        macc[m][2] = fmaf(av, w0.z, macc[m][2]);
        macc[m][3] = fmaf(av, w0.w, macc[m][3]);
        macc[m][4] = fmaf(av, w1.x, macc[m][4]);
        macc[m][5] = fmaf(av, w1.y, macc[m][5]);
        macc[m][6] = fmaf(av, w1.z, macc[m][6]);
        macc[m][7] = fmaf(av, w1.w, macc[m][7]);
      }
    }
#pragma unroll 4
    for (int k = 0; k < 32; ++k) {  // edge part
      const float4 w0 = *(const float4*)(Wm1 + (64+k)*64 + q*8);
      const float4 w1 = *(const float4*)(Wm1 + (64+k)*64 + q*8 + 4);
      const float a0 = A[g][k], a1 = A[g+32][k];
#pragma unroll
      for (int m = 0; m < 2; ++m) {
        const float av = m ? a1 : a0;
        macc[m][0] = fmaf(av, w0.x, macc[m][0]);
        macc[m][1] = fmaf(av, w0.y, macc[m][1]);
        macc[m][2] = fmaf(av, w0.z, macc[m][2]);
        macc[m][3] = fmaf(av, w0.w, macc[m][3]);
        macc[m][4] = fmaf(av, w1.x, macc[m][4]);
        macc[m][5] = fmaf(av, w1.y, macc[m][5]);
        macc[m][6] = fmaf(av, w1.z, macc[m][6]);
        macc[m][7] = fmaf(av, w1.w, macc[m][7]);
      }
    }
    __syncthreads();   // h reads (e2 phase) and A reads done before Bb overwrite
#pragma unroll
    for (int m = 0; m < 2; ++m) {
      const int e = g + 32*m;
#pragma unroll
      for (int c = 0; c < 8; ++c)
        Bb[e][8*q + c] = fmaxf(macc[m][c] + tmp[c], 0.f);
    }
  }
  __syncthreads();

  // ---- m2 partial: 2 edges x 5 outputs; expand + wave reduce ----
  {
    float p2[2][5];
#pragma unroll
    for (int m = 0; m < 2; ++m)
#pragma unroll
      for (int o = 0; o < 5; ++o) p2[m][o] = 0.f;
#pragma unroll 4
    for (int k = 0; k < 64; ++k) {
      const float* wr = Wm2 + k*40 + 5*q;
      const float w0 = wr[0], w1 = wr[1], w2 = wr[2], w3 = wr[3], w4 = wr[4];
      const float a0 = Bb[g][k], a1 = Bb[g+32][k];
#pragma unroll
      for (int m = 0; m < 2; ++m) {
        const float av = m ? a1 : a0;
        p2[m][0] = fmaf(av, w0, p2[m][0]);
        p2[m][1] = fmaf(av, w1, p2[m][1]);
        p2[m][2] = fmaf(av, w2, p2[m][2]);
        p2[m][3] = fmaf(av, w3, p2[m][3]);
        p2[m][4] = fmaf(av, w4, p2[m][4]);
      }
    }
    const float b0 = bm2[5*q], b1 = bm2[5*q+1], b2 = bm2[5*q+2],
                b3 = bm2[5*q+3], b4 = bm2[5*q+4];
    float outv[9];
#pragma unroll
    for (int s = 0; s < 9; ++s) outv[s] = 0.f;
#pragma unroll
    for (int m = 0; m < 2; ++m) {
      const int e = g + 32*m;
      const float v0 = p2[m][0]+b0, v1 = p2[m][1]+b1, v2 = p2[m][2]+b2,
                  v3 = p2[m][3]+b3, v4 = p2[m][4]+b4;
      if (q == 6) {   // o=30,31 plain; o=32,33 x rel; o=34 plain
        outv[0] += v0; outv[1] += v1;
        outv[2] = fmaf(v2, relv[e][0], outv[2]);
        outv[3] = fmaf(v2, relv[e][1], outv[3]);
        outv[4] = fmaf(v2, relv[e][2], outv[4]);
        outv[5] = fmaf(v3, relv[e][0], outv[5]);
        outv[6] = fmaf(v3, relv[e][1], outv[6]);
        outv[7] = fmaf(v3, relv[e][2], outv[7]);
        outv[8] += v4;
      } else {
        outv[0] += v0; outv[1] += v1; outv[2] += v2; outv[3] += v3; outv[4] += v4;
      }
    }
    // reduce across the 8 lanes sharing q (lane bits 3..5); all lanes active
#pragma unroll
    for (int s = 0; s < 9; ++s) {
      float v = outv[s];
      v += __shfl_xor(v, 8); v += __shfl_xor(v, 16); v += __shfl_xor(v, 32);
      outv[s] = v;
    }
    if ((lane >> 3) == 0) {   // one lane per q-group
      if (q == 6) {
#pragma unroll
        for (int s = 0; s < 9; ++s) P2[wv][30 + s] = outv[s];
      } else {
        const int base = (q == 7) ? 39 : 5*q;
#pragma unroll
        for (int s = 0; s < 5; ++s) P2[wv][base + s] = outv[s];
      }
    }
  }
  __syncthreads();

  if (t < 44) {
    fin2[(size_t)(i*2 + part)*44 + t] = P2[0][t] + P2[1][t] + P2[2][t] + P2[3][t];
  }
}

// ---------------- Kernel C3: combine partials, state_out + frame update ----
__global__ __launch_bounds__(64) void kernC3(
    const float* __restrict__ xyz, const unsigned char* __restrict__ rmask,
    const float* __restrict__ Wl0, const float* __restrict__ bl0,
    const float* __restrict__ node, const float* __restrict__ fin2,
    float* __restrict__ soutf, float* __restrict__ out)
{
  const int i = blockIdx.x, t = threadIdx.x;
  __shared__ float fin[44];
  __shared__ float ni[32];
  if (t < 44) fin[t] = fin2[(size_t)(i*2)*44 + t] + fin2[(size_t)(i*2+1)*44 + t];
  if (t < 32) ni[t] = node[i*32 + t];
  __syncthreads();

  if (t < 16) {  // state_out = [node_i, m_l0] @ Wl0 + bl0
    float a = bl0[t];
#pragma unroll
    for (int k = 0; k < 32; ++k) a = fmaf(ni[k], Wl0[k*16 + t], a);
#pragma unroll
    for (int k = 0; k < 32; ++k) a = fmaf(fin[k] * (1.f/128.f), Wl0[(32+k)*16 + t], a);
    soutf[i*16 + t] = a;
    out[LL*9 + i*16 + t] = a;
  }
  if (t == 0) {  // frame update
    float ve[6], wa[6];
#pragma unroll
    for (int qq = 0; qq < 6; ++qq) ve[qq] = fin[32 + qq] * (1.f/128.f);
#pragma unroll
    for (int qq = 0; qq < 6; ++qq) wa[qq] = fin[38 + qq] * (1.f/128.f);
    float l1[9];
#pragma unroll
    for (int a = 0; a < 3; ++a)
#pragma unroll
      for (int d = 0; d < 3; ++d) l1[a*3 + d] = xyz[i*9 + a*3 + d] - xyz[i*9 + 3 + d];
    float T[3], Rv[3];
#pragma unroll
    for (int d = 0; d < 3; ++d) {
      float va0 = wa[0]*l1[d] + wa[1]*l1[3 + d] + wa[2]*l1[6 + d];
      float va1 = wa[3]*l1[d] + wa[4]*l1[3 + d] + wa[5]*l1[6 + d];
      T[d]  = (ve[d] + va0) / 10.f;
      Rv[d] = (ve[3 + d] + va1) / 100.f;
    }
    float qn = sqrtf(1.f + Rv[0]*Rv[0] + Rv[1]*Rv[1] + Rv[2]*Rv[2]);
    float qA = 1.f/qn, qB = Rv[0]/qn, qC = Rv[1]/qn, qD = Rv[2]/qn;
    float Rm[9];
    Rm[0] = qA*qA + qB*qB - qC*qC - qD*qD;
    Rm[1] = 2.f*qB*qC - 2.f*qA*qD;
    Rm[2] = 2.f*qB*qD + 2.f*qA*qC;
    Rm[3] = 2.f*qB*qC + 2.f*qA*qD;
    Rm[4] = qA*qA - qB*qB + qC*qC - qD*qD;
    Rm[5] = 2.f*qC*qD - 2.f*qA*qB;
    Rm[6] = 2.f*qB*qD - 2.f*qA*qC;
    Rm[7] = 2.f*qC*qD + 2.f*qA*qB;
    Rm[8] = qA*qA - qB*qB - qC*qC + qD*qD;
    if (rmask[i]) {
      Rm[0] = 1.f; Rm[1] = 0.f; Rm[2] = 0.f;
      Rm[3] = 0.f; Rm[4] = 1.f; Rm[5] = 0.f;
      Rm[6] = 0.f; Rm[7] = 0.f; Rm[8] = 1.f;
    }
#pragma unroll
    for (int a = 0; a < 3; ++a)
#pragma unroll
      for (int di = 0; di < 3; ++di) {
        float xn = Rm[di*3+0]*l1[a*3+0] + Rm[di*3+1]*l1[a*3+1] + Rm[di*3+2]*l1[a*3+2]
                 + xyz[i*9 + 3 + di] + T[di];
        out[i*9 + a*3 + di] = xn;
      }
  }
}

// ---------------- Kernel D: si MLP stack -> alpha ---------------------------
__global__ __launch_bounds__(128) void kernD(
    const float* __restrict__ seq_ln, const float* __restrict__ st_out,
    const float* __restrict__ Ws0, const float* __restrict__ bs0,
    const float* __restrict__ Wsi, const float* __restrict__ bsi,
    const float* __restrict__ Wp1, const float* __restrict__ bp1,
    const float* __restrict__ Wp2, const float* __restrict__ bp2,
    const float* __restrict__ Wp3, const float* __restrict__ bp3,
    const float* __restrict__ Wp4, const float* __restrict__ bp4,
    const float* __restrict__ Wout, const float* __restrict__ bout,
    float* __restrict__ out)
{
  const int i = blockIdx.x, t = threadIdx.x;
  __shared__ float x0[256], stn[16], ra[128], ga[128], rb[128], gb[128], rc[128];
  x0[t]       = seq_ln[i*256 + t];
  x0[128 + t] = seq_ln[i*256 + 128 + t];
  if (t < 16) {
    float m = 0.f;
    for (int k = 0; k < 16; ++k) m += st_out[i*16 + k];
    m *= (1.f/16.f);
    float v = 0.f;
    for (int k = 0; k < 16; ++k) { float dd = st_out[i*16 + k] - m; v += dd*dd; }
    v *= (1.f/16.f);
    stn[t] = (st_out[i*16 + t] - m) / sqrtf(v + 1e-5f);
  }
  __syncthreads();

  float si = bs0[t] + bsi[t];
  for (int k = 0; k < 256; ++k) si = fmaf(x0[k], Ws0[k*128 + t], si);
  for (int k = 0; k < 16; ++k)  si = fmaf(stn[k], Wsi[k*128 + t], si);
  ra[t] = fmaxf(si, 0.f);
  __syncthreads();
  float h = bp1[t];
  for (int k = 0; k < 128; ++k) h = fmaf(ra[k], Wp1[k*128 + t], h);
  ga[t] = fmaxf(h, 0.f);
  __syncthreads();
  float d2 = bp2[t];
  for (int k = 0; k < 128; ++k) d2 = fmaf(ga[k], Wp2[k*128 + t], d2);
  si += d2;
  rb[t] = fmaxf(si, 0.f);
  __syncthreads();
  float h2 = bp3[t];
  for (int k = 0; k < 128; ++k) h2 = fmaf(rb[k], Wp3[k*128 + t], h2);
  gb[t] = fmaxf(h2, 0.f);
  __syncthreads();
  float d4 = bp4[t];
  for (int k = 0; k < 128; ++k) d4 = fmaf(gb[k], Wp4[k*128 + t], d4);
  si += d4;
  rc[t] = fmaxf(si, 0.f);
  __syncthreads();
  if (t < 20) {
    float a = bout[t];
    for (int k = 0; k < 128; ++k) a = fmaf(rc[k], Wout[k*20 + t], a);
    out[19200 + i*20 + t] = a;
  }
}

extern "C" void kernel_launch(void* const* d_in, const int* in_sizes, int n_in,
                              void* d_out, int out_size, void* d_ws, size_t ws_size,
                              hipStream_t stream)
{
  (void)in_sizes; (void)n_in; (void)out_size; (void)ws_size;
  const float* msa   = (const float*)d_in[0];
  const float* pair  = (const float*)d_in[1];
  const float* xyz   = (const float*)d_in[2];
  const float* state = (const float*)d_in[3];
  const int*   idx   = (const int*)d_in[4];
  const unsigned char* rmask = (const unsigned char*)d_in[5];
  const float* W_en = (const float*)d_in[6];
  const float* b_en = (const float*)d_in[7];
  const float* Wn1  = (const float*)d_in[8];
  const float* bn1  = (const float*)d_in[9];
  const float* Wn2  = (const float*)d_in[10];
  const float* bn2  = (const float*)d_in[11];
  const float* W_ee = (const float*)d_in[12];
  const float* b_ee = (const float*)d_in[13];
  const float* We1  = (const float*)d_in[14];
  const float* be1  = (const float*)d_in[15];
  const float* We2  = (const float*)d_in[16];
  const float* be2  = (const float*)d_in[17];
  const float* Wm1  = (const float*)d_in[18];
  const float* bm1  = (const float*)d_in[19];
  const float* Wm2  = (const float*)d_in[20];
  const float* bm2  = (const float*)d_in[21];
  const float* Wl0  = (const float*)d_in[22];
  const float* bl0  = (const float*)d_in[23];
  const float* Ws0  = (const float*)d_in[24];
  const float* bs0  = (const float*)d_in[25];
  const float* Wsi  = (const float*)d_in[26];
  const float* bsi  = (const float*)d_in[27];
  const float* Wp1  = (const float*)d_in[28];
  const float* bp1  = (const float*)d_in[29];
  const float* Wp2  = (const float*)d_in[30];
  const float* bp2  = (const float*)d_in[31];
  const float* Wp3  = (const float*)d_in[32];
  const float* bp3  = (const float*)d_in[33];
  const float* Wp4  = (const float*)d_in[34];
  const float* bp4  = (const float*)d_in[35];
  const float* Wout = (const float*)d_in[36];
  const float* bout = (const float*)d_in[37];

  float* wsf    = (float*)d_ws;
  float* seq_ln = wsf + WS_SEQ;
  float* nodev  = wsf + WS_NODE;
  int*   nbr    = (int*)(wsf + WS_NBR);
  float* soutf  = wsf + WS_SOUT;
  float* csee   = wsf + WS_CSEE;
  float* fin2   = wsf + WS_FIN;
  float* e0ws   = wsf + WS_E0;
  float* out = (float*)d_out;

  kernP<<<1, 32, 0, stream>>>(W_ee, csee);
  kernA<<<LL, 256, 0, stream>>>(msa, state, W_en, b_en, Wn1, bn1, Wn2, bn2, seq_ln, nodev);
  kernB<<<LL, 256, 0, stream>>>(xyz, nbr);
  kernC1<<<LL*2, 256, 0, stream>>>(pair, xyz, idx, W_ee, b_ee, csee, nbr, e0ws);
  kernC2<<<LL*2, 256, 0, stream>>>(xyz, We1, be1, We2, be2, Wm1, bm1, Wm2, bm2,
                                   nodev, nbr, e0ws, fin2);
  kernC3<<<LL, 64, 0, stream>>>(xyz, rmask, Wl0, bl0, nodev, fin2, soutf, out);
  kernD<<<LL, 128, 0, stream>>>(seq_ln, soutf, Ws0, bs0, Wsi, bsi, Wp1, bp1, Wp2, bp2,
                                Wp3, bp3, Wp4, bp4, Wout, bout, out);
}

// Round 7
// 191.218 us; speedup vs baseline: 1.1881x; 1.1881x over previous
//
#include <hip/hip_runtime.h>
#include <hip/hip_bf16.h>

#define LL 768
#define TOPK 128

// workspace layout (floats)
#define WS_SEQ  0                        // 768*256
#define WS_NODE (WS_SEQ + LL*256)        // 768*32
#define WS_NBR  (WS_NODE + LL*32)        // 768*128 ints
#define WS_SOUT (WS_NBR + LL*TOPK)       // 768*16
#define WS_CSEE (WS_SOUT + LL*16)        // 32
#define WS_E0   (WS_CSEE + 64)           // 768*128*32 floats

#define FMA_ROW32(ACC, XVAL, WPTR) do {                                   \
    const float _x = (XVAL);                                              \
    const float* __restrict__ _w = (WPTR);                                \
    _Pragma("unroll")                                                     \
    for (int _c = 0; _c < 32; ++_c) ACC[_c] = fmaf(_x, _w[_c], ACC[_c]);  \
  } while (0)

// bf16 pair pack/unpack (RNE)
__device__ __forceinline__ unsigned bfpack(float a, float b) {
  unsigned ua = __float_as_uint(a);
  ua = (ua + 0x7fffu + ((ua >> 16) & 1u)) >> 16;
  unsigned ub = __float_as_uint(b);
  ub = (ub + 0x7fffu + ((ub >> 16) & 1u)) & 0xffff0000u;
  return ua | ub;
}
__device__ __forceinline__ float bflo(unsigned v) { return __uint_as_float(v << 16); }
__device__ __forceinline__ float bfhi(unsigned v) { return __uint_as_float(v & 0xffff0000u); }

__device__ __forceinline__ float block_sum_256(float v, float* red, int t) {
#pragma unroll
  for (int o = 32; o > 0; o >>= 1) v += __shfl_xor(v, o, 64);
  __syncthreads();
  if ((t & 63) == 0) red[t >> 6] = v;
  __syncthreads();
  return red[0] + red[1] + red[2] + red[3];
}

// ---------------- Kernel P: column sums (LN-linearity hoist for C1) --------
__global__ void kernP(const float* __restrict__ W_ee, float* __restrict__ colsum_ee)
{
  const int c = threadIdx.x;   // 32 threads
  float s = 0.f;
  for (int k = 0; k < 128; ++k) s += W_ee[k*32 + c];
  colsum_ee[c] = s;
}

// ---------------- Kernel A: seq LN, state LN, node MLP + LN ----------------
__global__ __launch_bounds__(256) void kernA(
    const float* __restrict__ msa, const float* __restrict__ state,
    const float* __restrict__ W_en, const float* __restrict__ b_en,
    const float* __restrict__ Wn1, const float* __restrict__ bn1,
    const float* __restrict__ Wn2, const float* __restrict__ bn2,
    float* __restrict__ seq_ln, float* __restrict__ nodeo)
{
  const int i = blockIdx.x, t = threadIdx.x;
  __shared__ float x[256];
  __shared__ float red[4];
  __shared__ float sn[16], n0[32], tn[32], hh[64], n1v[32];

  float v = msa[i*256 + t];
  float mean = block_sum_256(v, red, t) * (1.f/256.f);
  float d = v - mean;
  float var = block_sum_256(d*d, red, t) * (1.f/256.f);
  float xn = d / sqrtf(var + 1e-5f);
  x[t] = xn;
  seq_ln[i*256 + t] = xn;

  if (t < 16) {
    float m2 = 0.f;
    for (int k = 0; k < 16; ++k) m2 += state[i*16 + k];
    m2 *= (1.f/16.f);
    float v2 = 0.f;
    for (int k = 0; k < 16; ++k) { float dd = state[i*16 + k] - m2; v2 += dd*dd; }
    v2 *= (1.f/16.f);
    sn[t] = (state[i*16 + t] - m2) / sqrtf(v2 + 1e-5f);
  }
  __syncthreads();

  if (t < 32) {
    float a = b_en[t];
    for (int k = 0; k < 256; ++k) a = fmaf(x[k], W_en[k*32 + t], a);
    for (int k = 0; k < 16; ++k)  a = fmaf(sn[k], W_en[(256+k)*32 + t], a);
    n0[t] = a;
  }
  __syncthreads();
  if (t < 32) {
    float m = 0.f;
    for (int k = 0; k < 32; ++k) m += n0[k];
    m *= (1.f/32.f);
    float vv = 0.f;
    for (int k = 0; k < 32; ++k) { float dd = n0[k] - m; vv += dd*dd; }
    vv *= (1.f/32.f);
    tn[t] = (n0[t] - m) / sqrtf(vv + 1e-5f);
  }
  __syncthreads();
  if (t < 64) {
    float a = bn1[t];
    for (int k = 0; k < 32; ++k) a = fmaf(tn[k], Wn1[k*64 + t], a);
    hh[t] = fmaxf(a, 0.f);
  }
  __syncthreads();
  if (t < 32) {
    float a = n0[t] + bn2[t];
    for (int k = 0; k < 64; ++k) a = fmaf(hh[k], Wn2[k*32 + t], a);
    n1v[t] = a;
  }
  __syncthreads();
  if (t < 32) {
    float m = 0.f;
    for (int k = 0; k < 32; ++k) m += n1v[k];
    m *= (1.f/32.f);
    float vv = 0.f;
    for (int k = 0; k < 32; ++k) { float dd = n1v[k] - m; vv += dd*dd; }
    vv *= (1.f/32.f);
    nodeo[i*32 + t] = (n1v[t] - m) / sqrtf(vv + 1e-5f);
  }
}

// ---------------- Kernel B: top-128 nearest by D, bitonic (D_bits, j) -------
__global__ __launch_bounds__(256) void kernB(const float* __restrict__ xyz,
                                             int* __restrict__ nbr)
{
  const int i = blockIdx.x, t = threadIdx.x;
  __shared__ unsigned long long keys[1024];
  const float cix = xyz[i*9+3], ciy = xyz[i*9+4], ciz = xyz[i*9+5];

  for (int j = t; j < 1024; j += 256) {
    unsigned long long kk = ~0ull;
    if (j < LL) {
      float dx = __fadd_rn(cix, -xyz[j*9+3]);
      float dy = __fadd_rn(ciy, -xyz[j*9+4]);
      float dz = __fadd_rn(ciz, -xyz[j*9+5]);
      float Dv = sqrtf(__fadd_rn(__fadd_rn(__fadd_rn(__fmul_rn(dx,dx),
                         __fmul_rn(dy,dy)), __fmul_rn(dz,dz)), 1e-8f));
      kk = (((unsigned long long)__float_as_uint(Dv)) << 32) | (unsigned)j;
    }
    keys[j] = kk;
  }
  for (int size = 2; size <= 1024; size <<= 1) {
    for (int stride = size >> 1; stride > 0; stride >>= 1) {
      __syncthreads();
      for (int p = t; p < 512; p += 256) {
        int lo = 2*p - (p & (stride - 1));
        int hi = lo + stride;
        bool up = ((lo & size) == 0);
        unsigned long long a = keys[lo], b = keys[hi];
        if ((a > b) == up) { keys[lo] = b; keys[hi] = a; }
      }
    }
  }
  __syncthreads();
  if (t < TOPK) nbr[i*TOPK + t] = (int)(keys[t] & 0xffffffffu);
}

// ---------------- Kernel C1: edge0 (pre-LN) per selected edge --------------
__global__ __launch_bounds__(256) void kernC1(
    const float* __restrict__ pair, const float* __restrict__ xyz,
    const int* __restrict__ idx,
    const float* __restrict__ W_ee, const float* __restrict__ b_ee,
    const float* __restrict__ colsum_ee,
    const int* __restrict__ nbr, float* __restrict__ e0ws)
{
  const int i = blockIdx.x >> 1, part = blockIdx.x & 1;
  const int t = threadIdx.x, lane = t & 63, wv = t >> 6;
  const int slot = lane & 15, q = lane >> 4;     // q = 0..3 k-quarter
  const int p = part*64 + wv*16 + slot;          // neighbor slot 0..127

  const int j = nbr[i*TOPK + p];
  const float cix = xyz[i*9+3], ciy = xyz[i*9+4], ciz = xyz[i*9+5];
  const float dx = __fadd_rn(cix, -xyz[j*9+3]);
  const float dy = __fadd_rn(ciy, -xyz[j*9+4]);
  const float dz = __fadd_rn(ciz, -xyz[j*9+5]);
  const float Dv = sqrtf(__fadd_rn(__fadd_rn(__fadd_rn(__fmul_rn(dx,dx),
                      __fmul_rn(dy,dy)), __fmul_rn(dz,dz)), 1e-8f));

  const float* prow = pair + (((size_t)i*LL + j) * 128) + q*32;
  float acc[32];
#pragma unroll
  for (int c = 0; c < 32; ++c) acc[c] = 0.f;
  float s = 0.f, ss = 0.f;
#pragma unroll 2
  for (int q4 = 0; q4 < 8; ++q4) {
    float4 v = ((const float4*)prow)[q4];
    s  += (v.x + v.y) + (v.z + v.w);
    ss += v.x*v.x + v.y*v.y + v.z*v.z + v.w*v.w;
    const float* wr = W_ee + (q*32 + q4*4)*32;
    FMA_ROW32(acc, v.x, wr);
    FMA_ROW32(acc, v.y, wr + 32);
    FMA_ROW32(acc, v.z, wr + 64);
    FMA_ROW32(acc, v.w, wr + 96);
  }
  s  += __shfl_xor(s, 16);  s  += __shfl_xor(s, 32);
  ss += __shfl_xor(ss, 16); ss += __shfl_xor(ss, 32);
  const float pm  = s * (1.f/128.f);
  const float pvv = ss * (1.f/128.f) - pm*pm;
  const float prs = 1.f / sqrtf(pvv + 1e-5f);

#pragma unroll
  for (int c = 0; c < 32; ++c) acc[c] *= prs;

#pragma unroll 4
  for (int kk = 0; kk < 16; ++kk) {
    const int k = q*16 + kk;
    float mu = 2.f + (float)k * (20.f/63.f);
    float u  = (Dv - mu) / 0.3125f;
    FMA_ROW32(acc, expf(-(u*u)), W_ee + (128+k)*32);
  }
  if (q == 0) {
    const float offv = (float)(idx[j] - idx[i]);
    const float sg = (offv > 0.f) ? 1.f : ((offv < 0.f) ? -1.f : 0.f);
    const float xsep = sg * logf(fabsf(offv) + 1.f);
    FMA_ROW32(acc, xsep, W_ee + 192*32);
    const float corr = -prs * pm;
#pragma unroll
    for (int c = 0; c < 32; ++c) acc[c] += b_ee[c] + corr * colsum_ee[c];
  }
#pragma unroll
  for (int c = 0; c < 32; ++c) {
    acc[c] += __shfl_xor(acc[c], 16);
    acc[c] += __shfl_xor(acc[c], 32);
  }

  float4* e4 = (float4*)e0ws;
#pragma unroll
  for (int cc = 0; cc < 2; ++cc) {
    const int c4 = q*2 + cc;
    float4 w = make_float4(acc[c4*4], acc[c4*4+1], acc[c4*4+2], acc[c4*4+3]);
    e4[((size_t)i*8 + c4)*128 + p] = w;
  }
}

// ---------------- Kernel C2: edge MLP + message MLP + reduce ---------------
// 128 edges/block (i = blockIdx). thread (g = t>>3, q = t&7): 4 edges
// {g, g+32, g+64, g+96} x 8 channels. A f32; Bb/nd bf16-packed in LDS.
// Exactly 768 blocks = 3 blocks/CU resident (LDS ~46 KB).
__global__ __launch_bounds__(256, 3) void kernC2(
    const float* __restrict__ xyz, const unsigned char* __restrict__ rmask,
    const float* __restrict__ We1, const float* __restrict__ be1,
    const float* __restrict__ We2, const float* __restrict__ be2,
    const float* __restrict__ Wm1, const float* __restrict__ bm1,
    const float* __restrict__ Wm2, const float* __restrict__ bm2,
    const float* __restrict__ Wl0, const float* __restrict__ bl0,
    const float* __restrict__ node, const int* __restrict__ nbr,
    const float* __restrict__ e0ws,
    float* __restrict__ soutf, float* __restrict__ out)
{
  const int i = blockIdx.x, t = threadIdx.x;
  const int g = t >> 3, q = t & 7;
  const int lane = t & 63, wv = t >> 6;
  __shared__ float    A[128][33];   // e0 -> ed -> e2 -> ed2 (f32, in place)
  __shared__ unsigned Bb[128][33];  // h -> m1 (bf16 pairs; [e][kk] = ch 2kk,2kk+1)
  __shared__ unsigned nd[128][17];  // node rows (bf16 pairs)
  __shared__ float ni[32];
  __shared__ float relv[128][3];
  __shared__ float mA[128], sgA[128];
  __shared__ float P2[4][44];
  __shared__ float fin[44];

  if (t < 32) ni[t] = node[i*32 + t];
  {  // stage neighbor node rows (bf16) + rel: thread t -> row t>>1, half t&1
    const int pp = t >> 1, hh2 = t & 1;
    const int jj = nbr[i*TOPK + pp];
    const float4* nr = (const float4*)(node + jj*32 + hh2*16);
    float4 a0 = nr[0], a1 = nr[1], a2 = nr[2], a3 = nr[3];
    unsigned* dst = &nd[pp][hh2*8];
    dst[0] = bfpack(a0.x, a0.y); dst[1] = bfpack(a0.z, a0.w);
    dst[2] = bfpack(a1.x, a1.y); dst[3] = bfpack(a1.z, a1.w);
    dst[4] = bfpack(a2.x, a2.y); dst[5] = bfpack(a2.z, a2.w);
    dst[6] = bfpack(a3.x, a3.y); dst[7] = bfpack(a3.z, a3.w);
    if (hh2 == 0) {
      relv[pp][0] = xyz[jj*9+3] - xyz[i*9+3];
      relv[pp][1] = xyz[jj*9+4] - xyz[i*9+4];
      relv[pp][2] = xyz[jj*9+5] - xyz[i*9+5];
    }
  }
  {  // stage e0 rows from C1 output (f32)
    const int p = t & 127, hh = t >> 7;
    const float4* src = (const float4*)e0ws + ((size_t)i*8 + hh*4)*128 + p;
#pragma unroll
    for (int n = 0; n < 4; ++n) {
      float4 v = src[(size_t)n*128];
      A[p][hh*16 + n*4 + 0] = v.x;
      A[p][hh*16 + n*4 + 1] = v.y;
      A[p][hh*16 + n*4 + 2] = v.z;
      A[p][hh*16 + n*4 + 3] = v.w;
    }
  }
  __syncthreads();

  // LN(A) in place; keep (mean, sigma) to recover raw e0 for the residual
  if (t < 128) {
    float mm = 0.f;
#pragma unroll
    for (int c = 0; c < 32; ++c) mm += A[t][c];
    mm *= (1.f/32.f);
    float vv = 0.f;
#pragma unroll
    for (int c = 0; c < 32; ++c) { float dd = A[t][c]-mm; vv += dd*dd; }
    vv *= (1.f/32.f);
    const float sg = sqrtf(vv + 1e-5f);
    const float rs = 1.f / sg;
#pragma unroll
    for (int c = 0; c < 32; ++c) A[t][c] = (A[t][c]-mm)*rs;
    mA[t] = mm; sgA[t] = sg;
  }
  __syncthreads();

  // ---- h = relu(ed @ We1 + be1): 4 edges x 8 ch; write bf16 pairs ----
  {
    float hacc[4][8];
#pragma unroll
    for (int m = 0; m < 4; ++m)
#pragma unroll
      for (int c = 0; c < 8; ++c) hacc[m][c] = 0.f;
#pragma unroll 4
    for (int k = 0; k < 32; ++k) {
      const float4 w0 = *(const float4*)(We1 + k*64 + q*8);
      const float4 w1 = *(const float4*)(We1 + k*64 + q*8 + 4);
      const float a0 = A[g][k], a1 = A[g+32][k], a2 = A[g+64][k], a3 = A[g+96][k];
#pragma unroll
      for (int m = 0; m < 4; ++m) {
        const float av = (m==0)?a0:(m==1)?a1:(m==2)?a2:a3;
        hacc[m][0] = fmaf(av, w0.x, hacc[m][0]);
        hacc[m][1] = fmaf(av, w0.y, hacc[m][1]);
        hacc[m][2] = fmaf(av, w0.z, hacc[m][2]);
        hacc[m][3] = fmaf(av, w0.w, hacc[m][3]);
        hacc[m][4] = fmaf(av, w1.x, hacc[m][4]);
        hacc[m][5] = fmaf(av, w1.y, hacc[m][5]);
        hacc[m][6] = fmaf(av, w1.z, hacc[m][6]);
        hacc[m][7] = fmaf(av, w1.w, hacc[m][7]);
      }
    }
#pragma unroll
    for (int m = 0; m < 4; ++m) {
      const int e = g + 32*m;
#pragma unroll
      for (int n = 0; n < 4; ++n) {
        const float lo = fmaxf(hacc[m][2*n]   + be1[8*q + 2*n],   0.f);
        const float hi = fmaxf(hacc[m][2*n+1] + be1[8*q + 2*n+1], 0.f);
        Bb[e][4*q + n] = bfpack(lo, hi);
      }
    }
  }
  __syncthreads();

  // ---- e2 = e0raw + h @ We2 + be2: 4 edges x 4 ch per thread ----
  {
    float e2a[4][4];
#pragma unroll
    for (int m = 0; m < 4; ++m)
#pragma unroll
      for (int c = 0; c < 4; ++c) e2a[m][c] = 0.f;
#pragma unroll 4
    for (int kk = 0; kk < 32; ++kk) {   // k = 2kk, 2kk+1
      const float4 wl = *(const float4*)(We2 + (2*kk)*32   + q*4);
      const float4 wh = *(const float4*)(We2 + (2*kk+1)*32 + q*4);
      const unsigned v0 = Bb[g][kk], v1 = Bb[g+32][kk],
                     v2 = Bb[g+64][kk], v3 = Bb[g+96][kk];
#pragma unroll
      for (int m = 0; m < 4; ++m) {
        const unsigned v = (m==0)?v0:(m==1)?v1:(m==2)?v2:v3;
        const float al = bflo(v), ah = bfhi(v);
        e2a[m][0] = fmaf(al, wl.x, fmaf(ah, wh.x, e2a[m][0]));
        e2a[m][1] = fmaf(al, wl.y, fmaf(ah, wh.y, e2a[m][1]));
        e2a[m][2] = fmaf(al, wl.z, fmaf(ah, wh.z, e2a[m][2]));
        e2a[m][3] = fmaf(al, wl.w, fmaf(ah, wh.w, e2a[m][3]));
      }
    }
#pragma unroll
    for (int m = 0; m < 4; ++m) {
      const int e = g + 32*m;
      const float sg = sgA[e], mm = mA[e];
#pragma unroll
      for (int c = 0; c < 4; ++c) {
        const int ch = 4*q + c;
        const float e0raw = fmaf(A[e][ch], sg, mm);   // undo LN
        A[e][ch] = e2a[m][c] + e0raw + be2[ch];
      }
    }
  }
  __syncthreads();

  // LN(e2) in place
  if (t < 128) {
    float mm = 0.f;
#pragma unroll
    for (int c = 0; c < 32; ++c) mm += A[t][c];
    mm *= (1.f/32.f);
    float vv = 0.f;
#pragma unroll
    for (int c = 0; c < 32; ++c) { float dd = A[t][c]-mm; vv += dd*dd; }
    vv *= (1.f/32.f);
    const float rs = 1.f / sqrtf(vv + 1e-5f);
#pragma unroll
    for (int c = 0; c < 32; ++c) A[t][c] = (A[t][c]-mm)*rs;
  }
  __syncthreads();

  // ---- m1 = relu([ni, nj, ed2] @ Wm1 + bm1): 4 edges x 8 ch ----
  {
    float tmp[8];   // ni part — identical for all edges
#pragma unroll
    for (int c = 0; c < 8; ++c) tmp[c] = bm1[8*q + c];
#pragma unroll 4
    for (int k = 0; k < 32; ++k) {
      const float4 w0 = *(const float4*)(Wm1 + k*64 + q*8);
      const float4 w1 = *(const float4*)(Wm1 + k*64 + q*8 + 4);
      const float av = ni[k];
      tmp[0] = fmaf(av, w0.x, tmp[0]); tmp[1] = fmaf(av, w0.y, tmp[1]);
      tmp[2] = fmaf(av, w0.z, tmp[2]); tmp[3] = fmaf(av, w0.w, tmp[3]);
      tmp[4] = fmaf(av, w1.x, tmp[4]); tmp[5] = fmaf(av, w1.y, tmp[5]);
      tmp[6] = fmaf(av, w1.z, tmp[6]); tmp[7] = fmaf(av, w1.w, tmp[7]);
    }
    float macc[4][8];
#pragma unroll
    for (int m = 0; m < 4; ++m)
#pragma unroll
      for (int c = 0; c < 8; ++c) macc[m][c] = 0.f;
#pragma unroll 4
    for (int kk = 0; kk < 16; ++kk) {   // h_j part (bf16 pairs), k = 2kk,2kk+1
      const float4 w0l = *(const float4*)(Wm1 + (32+2*kk)*64 + q*8);
      const float4 w1l = *(const float4*)(Wm1 + (32+2*kk)*64 + q*8 + 4);
      const float4 w0h = *(const float4*)(Wm1 + (33+2*kk)*64 + q*8);
      const float4 w1h = *(const float4*)(Wm1 + (33+2*kk)*64 + q*8 + 4);
      const unsigned v0 = nd[g][kk], v1 = nd[g+32][kk],
                     v2 = nd[g+64][kk], v3 = nd[g+96][kk];
#pragma unroll
      for (int m = 0; m < 4; ++m) {
        const unsigned v = (m==0)?v0:(m==1)?v1:(m==2)?v2:v3;
        const float al = bflo(v), ah = bfhi(v);
        macc[m][0] = fmaf(al, w0l.x, fmaf(ah, w0h.x, macc[m][0]));
        macc[m][1] = fmaf(al, w0l.y, fmaf(ah, w0h.y, macc[m][1]));
        macc[m][2] = fmaf(al, w0l.z, fmaf(ah, w0h.z, macc[m][2]));
        macc[m][3] = fmaf(al, w0l.w, fmaf(ah, w0h.w, macc[m][3]));
        macc[m][4] = fmaf(al, w1l.x, fmaf(ah, w1h.x, macc[m][4]));
        macc[m][5] = fmaf(al, w1l.y, fmaf(ah, w1h.y, macc[m][5]));
        macc[m][6] = fmaf(al, w1l.z, fmaf(ah, w1h.z, macc[m][6]));
        macc[m][7] = fmaf(al, w1l.w, fmaf(ah, w1h.w, macc[m][7]));
      }
    }
#pragma unroll 4
    for (int k = 0; k < 32; ++k) {  // edge part (f32 A)
      const float4 w0 = *(const float4*)(Wm1 + (64+k)*64 + q*8);
      const float4 w1 = *(const float4*)(Wm1 + (64+k)*64 + q*8 + 4);
      const float a0 = A[g][k], a1 = A[g+32][k], a2 = A[g+64][k], a3 = A[g+96][k];
#pragma unroll
      for (int m = 0; m < 4; ++m) {
        const float av = (m==0)?a0:(m==1)?a1:(m==2)?a2:a3;
        macc[m][0] = fmaf(av, w0.x, macc[m][0]);
        macc[m][1] = fmaf(av, w0.y, macc[m][1]);
        macc[m][2] = fmaf(av, w0.z, macc[m][2]);
        macc[m][3] = fmaf(av, w0.w, macc[m][3]);
        macc[m][4] = fmaf(av, w1.x, macc[m][4]);
        macc[m][5] = fmaf(av, w1.y, macc[m][5]);
        macc[m][6] = fmaf(av, w1.z, macc[m][6]);
        macc[m][7] = fmaf(av, w1.w, macc[m][7]);
      }
    }
    __syncthreads();   // e2-phase Bb reads done (already sync-separated); order-safe
#pragma unroll
    for (int m = 0; m < 4; ++m) {
      const int e = g + 32*m;
#pragma unroll
      for (int n = 0; n < 4; ++n) {
        const float lo = fmaxf(macc[m][2*n]   + tmp[2*n],   0.f);
        const float hi = fmaxf(macc[m][2*n+1] + tmp[2*n+1], 0.f);
        Bb[e][4*q + n] = bfpack(lo, hi);
      }
    }
  }
  __syncthreads();

  // ---- m2 partial: 4 edges x 5 outputs; expand + wave-shuffle reduce ----
  {
    float p2[4][5];
#pragma unroll
    for (int m = 0; m < 4; ++m)
#pragma unroll
      for (int o = 0; o < 5; ++o) p2[m][o] = 0.f;
#pragma unroll 4
    for (int kk = 0; kk < 32; ++kk) {   // k = 2kk, 2kk+1
      const float* wr0 = Wm2 + (2*kk)*40   + 5*q;
      const float* wr1 = Wm2 + (2*kk+1)*40 + 5*q;
      const unsigned v0 = Bb[g][kk], v1 = Bb[g+32][kk],
                     v2 = Bb[g+64][kk], v3 = Bb[g+96][kk];
#pragma unroll
      for (int m = 0; m < 4; ++m) {
        const unsigned v = (m==0)?v0:(m==1)?v1:(m==2)?v2:v3;
        const float al = bflo(v), ah = bfhi(v);
#pragma unroll
        for (int o = 0; o < 5; ++o)
          p2[m][o] = fmaf(al, wr0[o], fmaf(ah, wr1[o], p2[m][o]));
      }
    }
    const float b0 = bm2[5*q], b1 = bm2[5*q+1], b2 = bm2[5*q+2],
                b3 = bm2[5*q+3], b4 = bm2[5*q+4];
    float outv[9];
#pragma unroll
    for (int s = 0; s < 9; ++s) outv[s] = 0.f;
#pragma unroll
    for (int m = 0; m < 4; ++m) {
      const int e = g + 32*m;
      const float v0 = p2[m][0]+b0, v1 = p2[m][1]+b1, v2 = p2[m][2]+b2,
                  v3 = p2[m][3]+b3, v4 = p2[m][4]+b4;
      if (q == 6) {   // o=30,31 plain; o=32,33 x rel; o=34 plain
        outv[0] += v0; outv[1] += v1;
        outv[2] = fmaf(v2, relv[e][0], outv[2]);
        outv[3] = fmaf(v2, relv[e][1], outv[3]);
        outv[4] = fmaf(v2, relv[e][2], outv[4]);
        outv[5] = fmaf(v3, relv[e][0], outv[5]);
        outv[6] = fmaf(v3, relv[e][1], outv[6]);
        outv[7] = fmaf(v3, relv[e][2], outv[7]);
        outv[8] += v4;
      } else {
        outv[0] += v0; outv[1] += v1; outv[2] += v2; outv[3] += v3; outv[4] += v4;
      }
    }
    // reduce across the 8 lanes sharing q (lane bits 3..5)
#pragma unroll
    for (int s = 0; s < 9; ++s) {
      float v = outv[s];
      v += __shfl_xor(v, 8); v += __shfl_xor(v, 16); v += __shfl_xor(v, 32);
      outv[s] = v;
    }
    if ((lane >> 3) == 0) {   // one lane per q-group
      if (q == 6) {
#pragma unroll
        for (int s = 0; s < 9; ++s) P2[wv][30 + s] = outv[s];
      } else {
        const int base = (q == 7) ? 39 : 5*q;
#pragma unroll
        for (int s = 0; s < 5; ++s) P2[wv][base + s] = outv[s];
      }
    }
  }
  __syncthreads();
  if (t < 44) fin[t] = P2[0][t] + P2[1][t] + P2[2][t] + P2[3][t];
  __syncthreads();

  if (t < 16) {  // state_out = [node_i, m_l0] @ Wl0 + bl0
    float a = bl0[t];
#pragma unroll
    for (int k = 0; k < 32; ++k) a = fmaf(ni[k], Wl0[k*16 + t], a);
#pragma unroll
    for (int k = 0; k < 32; ++k) a = fmaf(fin[k] * (1.f/128.f), Wl0[(32+k)*16 + t], a);
    soutf[i*16 + t] = a;
    out[LL*9 + i*16 + t] = a;
  }
  if (t == 0) {  // frame update
    float ve[6], wa[6];
#pragma unroll
    for (int qq = 0; qq < 6; ++qq) ve[qq] = fin[32 + qq] * (1.f/128.f);
#pragma unroll
    for (int qq = 0; qq < 6; ++qq) wa[qq] = fin[38 + qq] * (1.f/128.f);
    float l1[9];
#pragma unroll
    for (int a = 0; a < 3; ++a)
#pragma unroll
      for (int d = 0; d < 3; ++d) l1[a*3 + d] = xyz[i*9 + a*3 + d] - xyz[i*9 + 3 + d];
    float T[3], Rv[3];
#pragma unroll
    for (int d = 0; d < 3; ++d) {
      float va0 = wa[0]*l1[d] + wa[1]*l1[3 + d] + wa[2]*l1[6 + d];
      float va1 = wa[3]*l1[d] + wa[4]*l1[3 + d] + wa[5]*l1[6 + d];
      T[d]  = (ve[d] + va0) / 10.f;
      Rv[d] = (ve[3 + d] + va1) / 100.f;
    }
    float qn = sqrtf(1.f + Rv[0]*Rv[0] + Rv[1]*Rv[1] + Rv[2]*Rv[2]);
    float qA = 1.f/qn, qB = Rv[0]/qn, qC = Rv[1]/qn, qD = Rv[2]/qn;
    float Rm[9];
    Rm[0] = qA*qA + qB*qB - qC*qC - qD*qD;
    Rm[1] = 2.f*qB*qC - 2.f*qA*qD;
    Rm[2] = 2.f*qB*qD + 2.f*qA*qC;
    Rm[3] = 2.f*qB*qC + 2.f*qA*qD;
    Rm[4] = qA*qA - qB*qB + qC*qC - qD*qD;
    Rm[5] = 2.f*qC*qD - 2.f*qA*qB;
    Rm[6] = 2.f*qB*qD - 2.f*qA*qC;
    Rm[7] = 2.f*qC*qD + 2.f*qA*qB;
    Rm[8] = qA*qA - qB*qB - qC*qC + qD*qD;
    if (rmask[i]) {
      Rm[0] = 1.f; Rm[1] = 0.f; Rm[2] = 0.f;
      Rm[3] = 0.f; Rm[4] = 1.f; Rm[5] = 0.f;
      Rm[6] = 0.f; Rm[7] = 0.f; Rm[8] = 1.f;
    }
#pragma unroll
    for (int a = 0; a < 3; ++a)
#pragma unroll
      for (int di = 0; di < 3; ++di) {
        float xn = Rm[di*3+0]*l1[a*3+0] + Rm[di*3+1]*l1[a*3+1] + Rm[di*3+2]*l1[a*3+2]
                 + xyz[i*9 + 3 + di] + T[di];
        out[i*9 + a*3 + di] = xn;
      }
  }
}

// ---------------- Kernel D: si MLP stack -> alpha ---------------------------
__global__ __launch_bounds__(128) void kernD(
    const float* __restrict__ seq_ln, const float* __restrict__ st_out,
    const float* __restrict__ Ws0, const float* __restrict__ bs0,
    const float* __restrict__ Wsi, const float* __restrict__ bsi,
    const float* __restrict__ Wp1, const float* __restrict__ bp1,
    const float* __restrict__ Wp2, const float* __restrict__ bp2,
    const float* __restrict__ Wp3, const float* __restrict__ bp3,
    const float* __restrict__ Wp4, const float* __restrict__ bp4,
    const float* __restrict__ Wout, const float* __restrict__ bout,
    float* __restrict__ out)
{
  const int i = blockIdx.x, t = threadIdx.x;
  __shared__ float x0[256], stn[16], ra[128], ga[128], rb[128], gb[128], rc[128];
  x0[t]       = seq_ln[i*256 + t];
  x0[128 + t] = seq_ln[i*256 + 128 + t];
  if (t < 16) {
    float m = 0.f;
    for (int k = 0; k < 16; ++k) m += st_out[i*16 + k];
    m *= (1.f/16.f);
    float v = 0.f;
    for (int k = 0; k < 16; ++k) { float dd = st_out[i*16 + k] - m; v += dd*dd; }
    v *= (1.f/16.f);
    stn[t] = (st_out[i*16 + t] - m) / sqrtf(v + 1e-5f);
  }
  __syncthreads();

  float si = bs0[t] + bsi[t];
  for (int k = 0; k < 256; ++k) si = fmaf(x0[k], Ws0[k*128 + t], si);
  for (int k = 0; k < 16; ++k)  si = fmaf(stn[k], Wsi[k*128 + t], si);
  ra[t] = fmaxf(si, 0.f);
  __syncthreads();
  float h = bp1[t];
  for (int k = 0; k < 128; ++k) h = fmaf(ra[k], Wp1[k*128 + t], h);
  ga[t] = fmaxf(h, 0.f);
  __syncthreads();
  float d2 = bp2[t];
  for (int k = 0; k < 128; ++k) d2 = fmaf(ga[k], Wp2[k*128 + t], d2);
  si += d2;
  rb[t] = fmaxf(si, 0.f);
  __syncthreads();
  float h2 = bp3[t];
  for (int k = 0; k < 128; ++k) h2 = fmaf(rb[k], Wp3[k*128 + t], h2);
  gb[t] = fmaxf(h2, 0.f);
  __syncthreads();
  float d4 = bp4[t];
  for (int k = 0; k < 128; ++k) d4 = fmaf(gb[k], Wp4[k*128 + t], d4);
  si += d4;
  rc[t] = fmaxf(si, 0.f);
  __syncthreads();
  if (t < 20) {
    float a = bout[t];
    for (int k = 0; k < 128; ++k) a = fmaf(rc[k], Wout[k*20 + t], a);
    out[19200 + i*20 + t] = a;
  }
}

extern "C" void kernel_launch(void* const* d_in, const int* in_sizes, int n_in,
                              void* d_out, int out_size, void* d_ws, size_t ws_size,
                              hipStream_t stream)
{
  (void)in_sizes; (void)n_in; (void)out_size; (void)ws_size;
  const float* msa   = (const float*)d_in[0];
  const float* pair  = (const float*)d_in[1];
  const float* xyz   = (const float*)d_in[2];
  const float* state = (const float*)d_in[3];
  const int*   idx   = (const int*)d_in[4];
  const unsigned char* rmask = (const unsigned char*)d_in[5];
  const float* W_en = (const float*)d_in[6];
  const float* b_en = (const float*)d_in[7];
  const float* Wn1  = (const float*)d_in[8];
  const float* bn1  = (const float*)d_in[9];
  const float* Wn2  = (const float*)d_in[10];
  const float* bn2  = (const float*)d_in[11];
  const float* W_ee = (const float*)d_in[12];
  const float* b_ee = (const float*)d_in[13];
  const float* We1  = (const float*)d_in[14];
  const float* be1  = (const float*)d_in[15];
  const float* We2  = (const float*)d_in[16];
  const float* be2  = (const float*)d_in[17];
  const float* Wm1  = (const float*)d_in[18];
  const float* bm1  = (const float*)d_in[19];
  const float* Wm2  = (const float*)d_in[20];
  const float* bm2  = (const float*)d_in[21];
  const float* Wl0  = (const float*)d_in[22];
  const float* bl0  = (const float*)d_in[23];
  const float* Ws0  = (const float*)d_in[24];
  const float* bs0  = (const float*)d_in[25];
  const float* Wsi  = (const float*)d_in[26];
  const float* bsi  = (const float*)d_in[27];
  const float* Wp1  = (const float*)d_in[28];
  const float* bp1  = (const float*)d_in[29];
  const float* Wp2  = (const float*)d_in[30];
  const float* bp2  = (const float*)d_in[31];
  const float* Wp3  = (const float*)d_in[32];
  const float* bp3  = (const float*)d_in[33];
  const float* Wp4  = (const float*)d_in[34];
  const float* bp4  = (const float*)d_in[35];
  const float* Wout = (const float*)d_in[36];
  const float* bout = (const float*)d_in[37];

  float* wsf    = (float*)d_ws;
  float* seq_ln = wsf + WS_SEQ;
  float* nodev  = wsf + WS_NODE;
  int*   nbr    = (int*)(wsf + WS_NBR);
  float* soutf  = wsf + WS_SOUT;
  float* csee   = wsf + WS_CSEE;
  float* e0ws   = wsf + WS_E0;
  float* out = (float*)d_out;

  kernP<<<1, 32, 0, stream>>>(W_ee, csee);
  kernA<<<LL, 256, 0, stream>>>(msa, state, W_en, b_en, Wn1, bn1, Wn2, bn2, seq_ln, nodev);
  kernB<<<LL, 256, 0, stream>>>(xyz, nbr);
  kernC1<<<LL*2, 256, 0, stream>>>(pair, xyz, idx, W_ee, b_ee, csee, nbr, e0ws);
  kernC2<<<LL, 256, 0, stream>>>(xyz, rmask, We1, be1, We2, be2, Wm1, bm1, Wm2, bm2,
                                 Wl0, bl0, nodev, nbr, e0ws, soutf, out);
  kernD<<<LL, 128, 0, stream>>>(seq_ln, soutf, Ws0, bs0, Wsi, bsi, Wp1, bp1, Wp2, bp2,
                                Wp3, bp3, Wp4, bp4, Wout, bout, out);
}

// Round 8
// 175.276 us; speedup vs baseline: 1.2962x; 1.0910x over previous
//
#include <hip/hip_runtime.h>
#include <hip/hip_bf16.h>

#define LL 768
#define TOPK 128

// workspace layout (floats)
#define WS_SEQ  0                        // 768*256
#define WS_NODE (WS_SEQ + LL*256)        // 768*32
#define WS_NBR  (WS_NODE + LL*32)        // 768*128 ints
#define WS_SOUT (WS_NBR + LL*TOPK)       // 768*16
#define WS_CSEE (WS_SOUT + LL*16)        // 32
#define WS_E0   (WS_CSEE + 64)           // 768*128*32 floats

#define FMA_ROW32(ACC, XVAL, WPTR) do {                                   \
    const float _x = (XVAL);                                              \
    const float* __restrict__ _w = (WPTR);                                \
    _Pragma("unroll")                                                     \
    for (int _c = 0; _c < 32; ++_c) ACC[_c] = fmaf(_x, _w[_c], ACC[_c]);  \
  } while (0)

// bf16 pair pack/unpack (RNE)
__device__ __forceinline__ unsigned bfpack(float a, float b) {
  unsigned ua = __float_as_uint(a);
  ua = (ua + 0x7fffu + ((ua >> 16) & 1u)) >> 16;
  unsigned ub = __float_as_uint(b);
  ub = (ub + 0x7fffu + ((ub >> 16) & 1u)) & 0xffff0000u;
  return ua | ub;
}
__device__ __forceinline__ float bflo(unsigned v) { return __uint_as_float(v << 16); }
__device__ __forceinline__ float bfhi(unsigned v) { return __uint_as_float(v & 0xffff0000u); }

__device__ __forceinline__ float block_sum_256(float v, float* red, int t) {
#pragma unroll
  for (int o = 32; o > 0; o >>= 1) v += __shfl_xor(v, o, 64);
  __syncthreads();
  if ((t & 63) == 0) red[t >> 6] = v;
  __syncthreads();
  return red[0] + red[1] + red[2] + red[3];
}

// ---------------- Kernel P: column sums (LN-linearity hoist for C1) --------
__global__ __launch_bounds__(256) void kernP(const float* __restrict__ W_ee,
                                             float* __restrict__ colsum_ee)
{
  __shared__ float part[8][33];
  const int c = threadIdx.x & 31, sg = threadIdx.x >> 5;
  float s = 0.f;
  for (int k = sg*16; k < sg*16 + 16; ++k) s += W_ee[k*32 + c];
  part[sg][c] = s;
  __syncthreads();
  if (threadIdx.x < 32) {
    float tot = 0.f;
#pragma unroll
    for (int g = 0; g < 8; ++g) tot += part[g][threadIdx.x];
    colsum_ee[threadIdx.x] = tot;
  }
}

// ---------------- Kernel A: seq LN, state LN, node MLP + LN ----------------
__global__ __launch_bounds__(256) void kernA(
    const float* __restrict__ msa, const float* __restrict__ state,
    const float* __restrict__ W_en, const float* __restrict__ b_en,
    const float* __restrict__ Wn1, const float* __restrict__ bn1,
    const float* __restrict__ Wn2, const float* __restrict__ bn2,
    float* __restrict__ seq_ln, float* __restrict__ nodeo)
{
  const int i = blockIdx.x, t = threadIdx.x;
  __shared__ float x[256];
  __shared__ float red[4];
  __shared__ float sn[16], n0[32], tn[32], hh[64], n1v[32];

  float v = msa[i*256 + t];
  float mean = block_sum_256(v, red, t) * (1.f/256.f);
  float d = v - mean;
  float var = block_sum_256(d*d, red, t) * (1.f/256.f);
  float xn = d / sqrtf(var + 1e-5f);
  x[t] = xn;
  seq_ln[i*256 + t] = xn;

  if (t < 16) {
    float m2 = 0.f;
    for (int k = 0; k < 16; ++k) m2 += state[i*16 + k];
    m2 *= (1.f/16.f);
    float v2 = 0.f;
    for (int k = 0; k < 16; ++k) { float dd = state[i*16 + k] - m2; v2 += dd*dd; }
    v2 *= (1.f/16.f);
    sn[t] = (state[i*16 + t] - m2) / sqrtf(v2 + 1e-5f);
  }
  __syncthreads();

  if (t < 32) {
    float a = b_en[t];
    for (int k = 0; k < 256; ++k) a = fmaf(x[k], W_en[k*32 + t], a);
    for (int k = 0; k < 16; ++k)  a = fmaf(sn[k], W_en[(256+k)*32 + t], a);
    n0[t] = a;
  }
  __syncthreads();
  if (t < 32) {
    float m = 0.f;
    for (int k = 0; k < 32; ++k) m += n0[k];
    m *= (1.f/32.f);
    float vv = 0.f;
    for (int k = 0; k < 32; ++k) { float dd = n0[k] - m; vv += dd*dd; }
    vv *= (1.f/32.f);
    tn[t] = (n0[t] - m) / sqrtf(vv + 1e-5f);
  }
  __syncthreads();
  if (t < 64) {
    float a = bn1[t];
    for (int k = 0; k < 32; ++k) a = fmaf(tn[k], Wn1[k*64 + t], a);
    hh[t] = fmaxf(a, 0.f);
  }
  __syncthreads();
  if (t < 32) {
    float a = n0[t] + bn2[t];
    for (int k = 0; k < 64; ++k) a = fmaf(hh[k], Wn2[k*32 + t], a);
    n1v[t] = a;
  }
  __syncthreads();
  if (t < 32) {
    float m = 0.f;
    for (int k = 0; k < 32; ++k) m += n1v[k];
    m *= (1.f/32.f);
    float vv = 0.f;
    for (int k = 0; k < 32; ++k) { float dd = n1v[k] - m; vv += dd*dd; }
    vv *= (1.f/32.f);
    nodeo[i*32 + t] = (n1v[t] - m) / sqrtf(vv + 1e-5f);
  }
}

// ---------------- Kernel B: top-128 nearest via 4-pass radix select --------
// Keys = f32 bits of D (D>0 so uint order == float order). Exact threshold,
// deterministic stable compaction in ascending-j order (ties: lowest j first,
// matching top_k's index tie-break). Downstream is permutation-invariant.
__global__ __launch_bounds__(256) void kernB(const float* __restrict__ xyz,
                                             int* __restrict__ nbr)
{
  const int i = blockIdx.x, t = threadIdx.x;
  const int lane = t & 63, wv = t >> 6;
  __shared__ unsigned hist[256];
  __shared__ int selBin, below;
  __shared__ unsigned wcL[4], wcE[4];

  const float cix = xyz[i*9+3], ciy = xyz[i*9+4], ciz = xyz[i*9+5];
  unsigned key[3];
#pragma unroll
  for (int r = 0; r < 3; ++r) {
    const int j = r*256 + t;
    float dx = __fadd_rn(cix, -xyz[j*9+3]);
    float dy = __fadd_rn(ciy, -xyz[j*9+4]);
    float dz = __fadd_rn(ciz, -xyz[j*9+5]);
    float Dv = sqrtf(__fadd_rn(__fadd_rn(__fadd_rn(__fmul_rn(dx,dx),
                       __fmul_rn(dy,dy)), __fmul_rn(dz,dz)), 1e-8f));
    key[r] = __float_as_uint(Dv);
  }

  // 4-pass radix select for rank 127 (0-based)
  unsigned prefix = 0;
  int rank = 127, cntLess = 0;
#pragma unroll
  for (int pass = 0; pass < 4; ++pass) {
    const int shift = 24 - pass*8;
    const unsigned hiMask = (pass == 0) ? 0u : (0xFFFFFFFFu << (shift + 8));
    hist[t] = 0;
    __syncthreads();
#pragma unroll
    for (int r = 0; r < 3; ++r)
      if ((key[r] & hiMask) == (prefix & hiMask))
        atomicAdd(&hist[(key[r] >> shift) & 0xffu], 1u);
    __syncthreads();
    if (t < 64) {   // wave-0 scan over 256 bins (4 per lane)
      unsigned s0 = hist[t*4], s1 = hist[t*4+1], s2 = hist[t*4+2], s3 = hist[t*4+3];
      int tot = (int)(s0 + s1 + s2 + s3);
      int inc = tot;
#pragma unroll
      for (int o = 1; o < 64; o <<= 1) {
        int v = __shfl_up(inc, o);
        if (t >= o) inc += v;
      }
      int excl = inc - tot;
      if (rank >= excl && rank < inc) {
        int c = excl, bsel = t*4;
        if (rank >= c + (int)s0) { c += (int)s0; bsel = t*4+1;
          if (rank >= c + (int)s1) { c += (int)s1; bsel = t*4+2;
            if (rank >= c + (int)s2) { c += (int)s2; bsel = t*4+3; } } }
        selBin = bsel; below = c;
      }
    }
    __syncthreads();
    prefix |= ((unsigned)selBin) << shift;
    rank -= below;
    cntLess += below;
    __syncthreads();
  }
  const unsigned thr = prefix;
  const int needEq = TOPK - cntLess;
  (void)needEq;

  // stable compaction: keys < thr first (j-ascending), then == thr (j-ascending)
  const unsigned long long lmask = (1ull << lane) - 1ull;
  unsigned baseLt = 0, baseEq = (unsigned)cntLess;
#pragma unroll
  for (int r = 0; r < 3; ++r) {
    const int j = r*256 + t;
    const bool pl = key[r] < thr;
    const bool pe = key[r] == thr;
    unsigned long long balL = __ballot(pl);
    unsigned long long balE = __ballot(pe);
    unsigned preL = (unsigned)__popcll(balL & lmask);
    unsigned preE = (unsigned)__popcll(balE & lmask);
    if (lane == 0) { wcL[wv] = (unsigned)__popcll(balL); wcE[wv] = (unsigned)__popcll(balE); }
    __syncthreads();
    unsigned wbL = 0, wbE = 0, totL = 0, totE = 0;
#pragma unroll
    for (int w = 0; w < 4; ++w) {
      if (w < wv) { wbL += wcL[w]; wbE += wcE[w]; }
      totL += wcL[w]; totE += wcE[w];
    }
    if (pl) nbr[i*TOPK + baseLt + wbL + preL] = j;
    if (pe) {
      unsigned pos = baseEq + wbE + preE;
      if (pos < TOPK) nbr[i*TOPK + pos] = j;
    }
    baseLt += totL; baseEq += totE;
    __syncthreads();
  }
}

// ---------------- Kernel C1: edge0 (pre-LN) per selected edge --------------
__global__ __launch_bounds__(256) void kernC1(
    const float* __restrict__ pair, const float* __restrict__ xyz,
    const int* __restrict__ idx,
    const float* __restrict__ W_ee, const float* __restrict__ b_ee,
    const float* __restrict__ colsum_ee,
    const int* __restrict__ nbr, float* __restrict__ e0ws)
{
  const int i = blockIdx.x >> 1, part = blockIdx.x & 1;
  const int t = threadIdx.x, lane = t & 63, wv = t >> 6;
  const int slot = lane & 15, q = lane >> 4;     // q = 0..3 k-quarter
  const int p = part*64 + wv*16 + slot;          // neighbor slot 0..127

  const int j = nbr[i*TOPK + p];
  const float cix = xyz[i*9+3], ciy = xyz[i*9+4], ciz = xyz[i*9+5];
  const float dx = __fadd_rn(cix, -xyz[j*9+3]);
  const float dy = __fadd_rn(ciy, -xyz[j*9+4]);
  const float dz = __fadd_rn(ciz, -xyz[j*9+5]);
  const float Dv = sqrtf(__fadd_rn(__fadd_rn(__fadd_rn(__fmul_rn(dx,dx),
                      __fmul_rn(dy,dy)), __fmul_rn(dz,dz)), 1e-8f));

  const float* prow = pair + (((size_t)i*LL + j) * 128) + q*32;
  float acc[32];
#pragma unroll
  for (int c = 0; c < 32; ++c) acc[c] = 0.f;
  float s = 0.f, ss = 0.f;
#pragma unroll 2
  for (int q4 = 0; q4 < 8; ++q4) {
    float4 v = ((const float4*)prow)[q4];
    s  += (v.x + v.y) + (v.z + v.w);
    ss += v.x*v.x + v.y*v.y + v.z*v.z + v.w*v.w;
    const float* wr = W_ee + (q*32 + q4*4)*32;
    FMA_ROW32(acc, v.x, wr);
    FMA_ROW32(acc, v.y, wr + 32);
    FMA_ROW32(acc, v.z, wr + 64);
    FMA_ROW32(acc, v.w, wr + 96);
  }
  s  += __shfl_xor(s, 16);  s  += __shfl_xor(s, 32);
  ss += __shfl_xor(ss, 16); ss += __shfl_xor(ss, 32);
  const float pm  = s * (1.f/128.f);
  const float pvv = ss * (1.f/128.f) - pm*pm;
  const float prs = 1.f / sqrtf(pvv + 1e-5f);

#pragma unroll
  for (int c = 0; c < 32; ++c) acc[c] *= prs;

#pragma unroll 4
  for (int kk = 0; kk < 16; ++kk) {
    const int k = q*16 + kk;
    float mu = 2.f + (float)k * (20.f/63.f);
    float u  = (Dv - mu) / 0.3125f;
    FMA_ROW32(acc, expf(-(u*u)), W_ee + (128+k)*32);
  }
  if (q == 0) {
    const float offv = (float)(idx[j] - idx[i]);
    const float sg = (offv > 0.f) ? 1.f : ((offv < 0.f) ? -1.f : 0.f);
    const float xsep = sg * logf(fabsf(offv) + 1.f);
    FMA_ROW32(acc, xsep, W_ee + 192*32);
    const float corr = -prs * pm;
#pragma unroll
    for (int c = 0; c < 32; ++c) acc[c] += b_ee[c] + corr * colsum_ee[c];
  }
#pragma unroll
  for (int c = 0; c < 32; ++c) {
    acc[c] += __shfl_xor(acc[c], 16);
    acc[c] += __shfl_xor(acc[c], 32);
  }

  float4* e4 = (float4*)e0ws;
#pragma unroll
  for (int cc = 0; cc < 2; ++cc) {
    const int c4 = q*2 + cc;
    float4 w = make_float4(acc[c4*4], acc[c4*4+1], acc[c4*4+2], acc[c4*4+3]);
    e4[((size_t)i*8 + c4)*128 + p] = w;
  }
}

// ---------------- Kernel C2: edge MLP + message MLP + reduce ---------------
// 128 edges/block (i = blockIdx). thread (g = t>>3, q = t&7): 4 edges
// {g, g+32, g+64, g+96} x 8 channels. A f32; Bb/nd bf16-packed in LDS.
// Exactly 768 blocks = 3 blocks/CU resident (LDS ~46 KB).
__global__ __launch_bounds__(256, 3) void kernC2(
    const float* __restrict__ xyz, const unsigned char* __restrict__ rmask,
    const float* __restrict__ We1, const float* __restrict__ be1,
    const float* __restrict__ We2, const float* __restrict__ be2,
    const float* __restrict__ Wm1, const float* __restrict__ bm1,
    const float* __restrict__ Wm2, const float* __restrict__ bm2,
    const float* __restrict__ Wl0, const float* __restrict__ bl0,
    const float* __restrict__ node, const int* __restrict__ nbr,
    const float* __restrict__ e0ws,
    float* __restrict__ soutf, float* __restrict__ out)
{
  const int i = blockIdx.x, t = threadIdx.x;
  const int g = t >> 3, q = t & 7;
  const int lane = t & 63, wv = t >> 6;
  __shared__ float    A[128][33];   // e0 -> ed -> e2 -> ed2 (f32, in place)
  __shared__ unsigned Bb[128][33];  // h -> m1 (bf16 pairs; [e][kk] = ch 2kk,2kk+1)
  __shared__ unsigned nd[128][17];  // node rows (bf16 pairs)
  __shared__ float ni[32];
  __shared__ float relv[128][3];
  __shared__ float mA[128], sgA[128];
  __shared__ float P2[4][44];
  __shared__ float fin[44];

  if (t < 32) ni[t] = node[i*32 + t];
  {  // stage neighbor node rows (bf16) + rel: thread t -> row t>>1, half t&1
    const int pp = t >> 1, hh2 = t & 1;
    const int jj = nbr[i*TOPK + pp];
    const float4* nr = (const float4*)(node + jj*32 + hh2*16);
    float4 a0 = nr[0], a1 = nr[1], a2 = nr[2], a3 = nr[3];
    unsigned* dst = &nd[pp][hh2*8];
    dst[0] = bfpack(a0.x, a0.y); dst[1] = bfpack(a0.z, a0.w);
    dst[2] = bfpack(a1.x, a1.y); dst[3] = bfpack(a1.z, a1.w);
    dst[4] = bfpack(a2.x, a2.y); dst[5] = bfpack(a2.z, a2.w);
    dst[6] = bfpack(a3.x, a3.y); dst[7] = bfpack(a3.z, a3.w);
    if (hh2 == 0) {
      relv[pp][0] = xyz[jj*9+3] - xyz[i*9+3];
      relv[pp][1] = xyz[jj*9+4] - xyz[i*9+4];
      relv[pp][2] = xyz[jj*9+5] - xyz[i*9+5];
    }
  }
  {  // stage e0 rows from C1 output (f32)
    const int p = t & 127, hh = t >> 7;
    const float4* src = (const float4*)e0ws + ((size_t)i*8 + hh*4)*128 + p;
#pragma unroll
    for (int n = 0; n < 4; ++n) {
      float4 v = src[(size_t)n*128];
      A[p][hh*16 + n*4 + 0] = v.x;
      A[p][hh*16 + n*4 + 1] = v.y;
      A[p][hh*16 + n*4 + 2] = v.z;
      A[p][hh*16 + n*4 + 3] = v.w;
    }
  }
  __syncthreads();

  // LN(A) in place; keep (mean, sigma) to recover raw e0 for the residual
  if (t < 128) {
    float mm = 0.f;
#pragma unroll
    for (int c = 0; c < 32; ++c) mm += A[t][c];
    mm *= (1.f/32.f);
    float vv = 0.f;
#pragma unroll
    for (int c = 0; c < 32; ++c) { float dd = A[t][c]-mm; vv += dd*dd; }
    vv *= (1.f/32.f);
    const float sg = sqrtf(vv + 1e-5f);
    const float rs = 1.f / sg;
#pragma unroll
    for (int c = 0; c < 32; ++c) A[t][c] = (A[t][c]-mm)*rs;
    mA[t] = mm; sgA[t] = sg;
  }
  __syncthreads();

  // ---- h = relu(ed @ We1 + be1): 4 edges x 8 ch; write bf16 pairs ----
  {
    float hacc[4][8];
#pragma unroll
    for (int m = 0; m < 4; ++m)
#pragma unroll
      for (int c = 0; c < 8; ++c) hacc[m][c] = 0.f;
#pragma unroll 4
    for (int k = 0; k < 32; ++k) {
      const float4 w0 = *(const float4*)(We1 + k*64 + q*8);
      const float4 w1 = *(const float4*)(We1 + k*64 + q*8 + 4);
      const float a0 = A[g][k], a1 = A[g+32][k], a2 = A[g+64][k], a3 = A[g+96][k];
#pragma unroll
      for (int m = 0; m < 4; ++m) {
        const float av = (m==0)?a0:(m==1)?a1:(m==2)?a2:a3;
        hacc[m][0] = fmaf(av, w0.x, hacc[m][0]);
        hacc[m][1] = fmaf(av, w0.y, hacc[m][1]);
        hacc[m][2] = fmaf(av, w0.z, hacc[m][2]);
        hacc[m][3] = fmaf(av, w0.w, hacc[m][3]);
        hacc[m][4] = fmaf(av, w1.x, hacc[m][4]);
        hacc[m][5] = fmaf(av, w1.y, hacc[m][5]);
        hacc[m][6] = fmaf(av, w1.z, hacc[m][6]);
        hacc[m][7] = fmaf(av, w1.w, hacc[m][7]);
      }
    }
#pragma unroll
    for (int m = 0; m < 4; ++m) {
      const int e = g + 32*m;
#pragma unroll
      for (int n = 0; n < 4; ++n) {
        const float lo = fmaxf(hacc[m][2*n]   + be1[8*q + 2*n],   0.f);
        const float hi = fmaxf(hacc[m][2*n+1] + be1[8*q + 2*n+1], 0.f);
        Bb[e][4*q + n] = bfpack(lo, hi);
      }
    }
  }
  __syncthreads();

  // ---- e2 = e0raw + h @ We2 + be2: 4 edges x 4 ch per thread ----
  {
    float e2a[4][4];
#pragma unroll
    for (int m = 0; m < 4; ++m)
#pragma unroll
      for (int c = 0; c < 4; ++c) e2a[m][c] = 0.f;
#pragma unroll 4
    for (int kk = 0; kk < 32; ++kk) {   // k = 2kk, 2kk+1
      const float4 wl = *(const float4*)(We2 + (2*kk)*32   + q*4);
      const float4 wh = *(const float4*)(We2 + (2*kk+1)*32 + q*4);
      const unsigned v0 = Bb[g][kk], v1 = Bb[g+32][kk],
                     v2 = Bb[g+64][kk], v3 = Bb[g+96][kk];
#pragma unroll
      for (int m = 0; m < 4; ++m) {
        const unsigned v = (m==0)?v0:(m==1)?v1:(m==2)?v2:v3;
        const float al = bflo(v), ah = bfhi(v);
        e2a[m][0] = fmaf(al, wl.x, fmaf(ah, wh.x, e2a[m][0]));
        e2a[m][1] = fmaf(al, wl.y, fmaf(ah, wh.y, e2a[m][1]));
        e2a[m][2] = fmaf(al, wl.z, fmaf(ah, wh.z, e2a[m][2]));
        e2a[m][3] = fmaf(al, wl.w, fmaf(ah, wh.w, e2a[m][3]));
      }
    }
#pragma unroll
    for (int m = 0; m < 4; ++m) {
      const int e = g + 32*m;
      const float sg = sgA[e], mm = mA[e];
#pragma unroll
      for (int c = 0; c < 4; ++c) {
        const int ch = 4*q + c;
        const float e0raw = fmaf(A[e][ch], sg, mm);   // undo LN
        A[e][ch] = e2a[m][c] + e0raw + be2[ch];
      }
    }
  }
  __syncthreads();

  // LN(e2) in place
  if (t < 128) {
    float mm = 0.f;
#pragma unroll
    for (int c = 0; c < 32; ++c) mm += A[t][c];
    mm *= (1.f/32.f);
    float vv = 0.f;
#pragma unroll
    for (int c = 0; c < 32; ++c) { float dd = A[t][c]-mm; vv += dd*dd; }
    vv *= (1.f/32.f);
    const float rs = 1.f / sqrtf(vv + 1e-5f);
#pragma unroll
    for (int c = 0; c < 32; ++c) A[t][c] = (A[t][c]-mm)*rs;
  }
  __syncthreads();

  // ---- m1 = relu([ni, nj, ed2] @ Wm1 + bm1): 4 edges x 8 ch ----
  {
    float tmp[8];   // ni part — identical for all edges
#pragma unroll
    for (int c = 0; c < 8; ++c) tmp[c] = bm1[8*q + c];
#pragma unroll 4
    for (int k = 0; k < 32; ++k) {
      const float4 w0 = *(const float4*)(Wm1 + k*64 + q*8);
      const float4 w1 = *(const float4*)(Wm1 + k*64 + q*8 + 4);
      const float av = ni[k];
      tmp[0] = fmaf(av, w0.x, tmp[0]); tmp[1] = fmaf(av, w0.y, tmp[1]);
      tmp[2] = fmaf(av, w0.z, tmp[2]); tmp[3] = fmaf(av, w0.w, tmp[3]);
      tmp[4] = fmaf(av, w1.x, tmp[4]); tmp[5] = fmaf(av, w1.y, tmp[5]);
      tmp[6] = fmaf(av, w1.z, tmp[6]); tmp[7] = fmaf(av, w1.w, tmp[7]);
    }
    float macc[4][8];
#pragma unroll
    for (int m = 0; m < 4; ++m)
#pragma unroll
      for (int c = 0; c < 8; ++c) macc[m][c] = 0.f;
#pragma unroll 4
    for (int kk = 0; kk < 16; ++kk) {   // h_j part (bf16 pairs), k = 2kk,2kk+1
      const float4 w0l = *(const float4*)(Wm1 + (32+2*kk)*64 + q*8);
      const float4 w1l = *(const float4*)(Wm1 + (32+2*kk)*64 + q*8 + 4);
      const float4 w0h = *(const float4*)(Wm1 + (33+2*kk)*64 + q*8);
      const float4 w1h = *(const float4*)(Wm1 + (33+2*kk)*64 + q*8 + 4);
      const unsigned v0 = nd[g][kk], v1 = nd[g+32][kk],
                     v2 = nd[g+64][kk], v3 = nd[g+96][kk];
#pragma unroll
      for (int m = 0; m < 4; ++m) {
        const unsigned v = (m==0)?v0:(m==1)?v1:(m==2)?v2:v3;
        const float al = bflo(v), ah = bfhi(v);
        macc[m][0] = fmaf(al, w0l.x, fmaf(ah, w0h.x, macc[m][0]));
        macc[m][1] = fmaf(al, w0l.y, fmaf(ah, w0h.y, macc[m][1]));
        macc[m][2] = fmaf(al, w0l.z, fmaf(ah, w0h.z, macc[m][2]));
        macc[m][3] = fmaf(al, w0l.w, fmaf(ah, w0h.w, macc[m][3]));
        macc[m][4] = fmaf(al, w1l.x, fmaf(ah, w1h.x, macc[m][4]));
        macc[m][5] = fmaf(al, w1l.y, fmaf(ah, w1h.y, macc[m][5]));
        macc[m][6] = fmaf(al, w1l.z, fmaf(ah, w1h.z, macc[m][6]));
        macc[m][7] = fmaf(al, w1l.w, fmaf(ah, w1h.w, macc[m][7]));
      }
    }
#pragma unroll 4
    for (int k = 0; k < 32; ++k) {  // edge part (f32 A)
      const float4 w0 = *(const float4*)(Wm1 + (64+k)*64 + q*8);
      const float4 w1 = *(const float4*)(Wm1 + (64+k)*64 + q*8 + 4);
      const float a0 = A[g][k], a1 = A[g+32][k], a2 = A[g+64][k], a3 = A[g+96][k];
#pragma unroll
      for (int m = 0; m < 4; ++m) {
        const float av = (m==0)?a0:(m==1)?a1:(m==2)?a2:a3;
        macc[m][0] = fmaf(av, w0.x, macc[m][0]);
        macc[m][1] = fmaf(av, w0.y, macc[m][1]);
        macc[m][2] = fmaf(av, w0.z, macc[m][2]);
        macc[m][3] = fmaf(av, w0.w, macc[m][3]);
        macc[m][4] = fmaf(av, w1.x, macc[m][4]);
        macc[m][5] = fmaf(av, w1.y, macc[m][5]);
        macc[m][6] = fmaf(av, w1.z, macc[m][6]);
        macc[m][7] = fmaf(av, w1.w, macc[m][7]);
      }
    }
    __syncthreads();   // e2-phase Bb reads done (already sync-separated); order-safe
#pragma unroll
    for (int m = 0; m < 4; ++m) {
      const int e = g + 32*m;
#pragma unroll
      for (int n = 0; n < 4; ++n) {
        const float lo = fmaxf(macc[m][2*n]   + tmp[2*n],   0.f);
        const float hi = fmaxf(macc[m][2*n+1] + tmp[2*n+1], 0.f);
        Bb[e][4*q + n] = bfpack(lo, hi);
      }
    }
  }
  __syncthreads();

  // ---- m2 partial: 4 edges x 5 outputs; expand + wave-shuffle reduce ----
  {
    float p2[4][5];
#pragma unroll
    for (int m = 0; m < 4; ++m)
#pragma unroll
      for (int o = 0; o < 5; ++o) p2[m][o] = 0.f;
#pragma unroll 4
    for (int kk = 0; kk < 32; ++kk) {   // k = 2kk, 2kk+1
      const float* wr0 = Wm2 + (2*kk)*40   + 5*q;
      const float* wr1 = Wm2 + (2*kk+1)*40 + 5*q;
      const unsigned v0 = Bb[g][kk], v1 = Bb[g+32][kk],
                     v2 = Bb[g+64][kk], v3 = Bb[g+96][kk];
#pragma unroll
      for (int m = 0; m < 4; ++m) {
        const unsigned v = (m==0)?v0:(m==1)?v1:(m==2)?v2:v3;
        const float al = bflo(v), ah = bfhi(v);
#pragma unroll
        for (int o = 0; o < 5; ++o)
          p2[m][o] = fmaf(al, wr0[o], fmaf(ah, wr1[o], p2[m][o]));
      }
    }
    const float b0 = bm2[5*q], b1 = bm2[5*q+1], b2 = bm2[5*q+2],
                b3 = bm2[5*q+3], b4 = bm2[5*q+4];
    float outv[9];
#pragma unroll
    for (int s = 0; s < 9; ++s) outv[s] = 0.f;
#pragma unroll
    for (int m = 0; m < 4; ++m) {
      const int e = g + 32*m;
      const float v0 = p2[m][0]+b0, v1 = p2[m][1]+b1, v2 = p2[m][2]+b2,
                  v3 = p2[m][3]+b3, v4 = p2[m][4]+b4;
      if (q == 6) {   // o=30,31 plain; o=32,33 x rel; o=34 plain
        outv[0] += v0; outv[1] += v1;
        outv[2] = fmaf(v2, relv[e][0], outv[2]);
        outv[3] = fmaf(v2, relv[e][1], outv[3]);
        outv[4] = fmaf(v2, relv[e][2], outv[4]);
        outv[5] = fmaf(v3, relv[e][0], outv[5]);
        outv[6] = fmaf(v3, relv[e][1], outv[6]);
        outv[7] = fmaf(v3, relv[e][2], outv[7]);
        outv[8] += v4;
      } else {
        outv[0] += v0; outv[1] += v1; outv[2] += v2; outv[3] += v3; outv[4] += v4;
      }
    }
    // reduce across the 8 lanes sharing q (lane bits 3..5)
#pragma unroll
    for (int s = 0; s < 9; ++s) {
      float v = outv[s];
      v += __shfl_xor(v, 8); v += __shfl_xor(v, 16); v += __shfl_xor(v, 32);
      outv[s] = v;
    }
    if ((lane >> 3) == 0) {   // one lane per q-group
      if (q == 6) {
#pragma unroll
        for (int s = 0; s < 9; ++s) P2[wv][30 + s] = outv[s];
      } else {
        const int base = (q == 7) ? 39 : 5*q;
#pragma unroll
        for (int s = 0; s < 5; ++s) P2[wv][base + s] = outv[s];
      }
    }
  }
  __syncthreads();
  if (t < 44) fin[t] = P2[0][t] + P2[1][t] + P2[2][t] + P2[3][t];
  __syncthreads();

  if (t < 16) {  // state_out = [node_i, m_l0] @ Wl0 + bl0
    float a = bl0[t];
#pragma unroll
    for (int k = 0; k < 32; ++k) a = fmaf(ni[k], Wl0[k*16 + t], a);
#pragma unroll
    for (int k = 0; k < 32; ++k) a = fmaf(fin[k] * (1.f/128.f), Wl0[(32+k)*16 + t], a);
    soutf[i*16 + t] = a;
    out[LL*9 + i*16 + t] = a;
  }
  if (t == 0) {  // frame update
    float ve[6], wa[6];
#pragma unroll
    for (int qq = 0; qq < 6; ++qq) ve[qq] = fin[32 + qq] * (1.f/128.f);
#pragma unroll
    for (int qq = 0; qq < 6; ++qq) wa[qq] = fin[38 + qq] * (1.f/128.f);
    float l1[9];
#pragma unroll
    for (int a = 0; a < 3; ++a)
#pragma unroll
      for (int d = 0; d < 3; ++d) l1[a*3 + d] = xyz[i*9 + a*3 + d] - xyz[i*9 + 3 + d];
    float T[3], Rv[3];
#pragma unroll
    for (int d = 0; d < 3; ++d) {
      float va0 = wa[0]*l1[d] + wa[1]*l1[3 + d] + wa[2]*l1[6 + d];
      float va1 = wa[3]*l1[d] + wa[4]*l1[3 + d] + wa[5]*l1[6 + d];
      T[d]  = (ve[d] + va0) / 10.f;
      Rv[d] = (ve[3 + d] + va1) / 100.f;
    }
    float qn = sqrtf(1.f + Rv[0]*Rv[0] + Rv[1]*Rv[1] + Rv[2]*Rv[2]);
    float qA = 1.f/qn, qB = Rv[0]/qn, qC = Rv[1]/qn, qD = Rv[2]/qn;
    float Rm[9];
    Rm[0] = qA*qA + qB*qB - qC*qC - qD*qD;
    Rm[1] = 2.f*qB*qC - 2.f*qA*qD;
    Rm[2] = 2.f*qB*qD + 2.f*qA*qC;
    Rm[3] = 2.f*qB*qC + 2.f*qA*qD;
    Rm[4] = qA*qA - qB*qB + qC*qC - qD*qD;
    Rm[5] = 2.f*qC*qD - 2.f*qA*qB;
    Rm[6] = 2.f*qB*qD - 2.f*qA*qC;
    Rm[7] = 2.f*qC*qD + 2.f*qA*qB;
    Rm[8] = qA*qA - qB*qB - qC*qC + qD*qD;
    if (rmask[i]) {
      Rm[0] = 1.f; Rm[1] = 0.f; Rm[2] = 0.f;
      Rm[3] = 0.f; Rm[4] = 1.f; Rm[5] = 0.f;
      Rm[6] = 0.f; Rm[7] = 0.f; Rm[8] = 1.f;
    }
#pragma unroll
    for (int a = 0; a < 3; ++a)
#pragma unroll
      for (int di = 0; di < 3; ++di) {
        float xn = Rm[di*3+0]*l1[a*3+0] + Rm[di*3+1]*l1[a*3+1] + Rm[di*3+2]*l1[a*3+2]
                 + xyz[i*9 + 3 + di] + T[di];
        out[i*9 + a*3 + di] = xn;
      }
  }
}

// ---------------- Kernel D: si MLP stack -> alpha ---------------------------
__global__ __launch_bounds__(128) void kernD(
    const float* __restrict__ seq_ln, const float* __restrict__ st_out,
    const float* __restrict__ Ws0, const float* __restrict__ bs0,
    const float* __restrict__ Wsi, const float* __restrict__ bsi,
    const float* __restrict__ Wp1, const float* __restrict__ bp1,
    const float* __restrict__ Wp2, const float* __restrict__ bp2,
    const float* __restrict__ Wp3, const float* __restrict__ bp3,
    const float* __restrict__ Wp4, const float* __restrict__ bp4,
    const float* __restrict__ Wout, const float* __restrict__ bout,
    float* __restrict__ out)
{
  const int i = blockIdx.x, t = threadIdx.x;
  __shared__ float x0[256], stn[16], ra[128], ga[128], rb[128], gb[128], rc[128];
  x0[t]       = seq_ln[i*256 + t];
  x0[128 + t] = seq_ln[i*256 + 128 + t];
  if (t < 16) {
    float m = 0.f;
    for (int k = 0; k < 16; ++k) m += st_out[i*16 + k];
    m *= (1.f/16.f);
    float v = 0.f;
    for (int k = 0; k < 16; ++k) { float dd = st_out[i*16 + k] - m; v += dd*dd; }
    v *= (1.f/16.f);
    stn[t] = (st_out[i*16 + t] - m) / sqrtf(v + 1e-5f);
  }
  __syncthreads();

  float si = bs0[t] + bsi[t];
  for (int k = 0; k < 256; ++k) si = fmaf(x0[k], Ws0[k*128 + t], si);
  for (int k = 0; k < 16; ++k)  si = fmaf(stn[k], Wsi[k*128 + t], si);
  ra[t] = fmaxf(si, 0.f);
  __syncthreads();
  float h = bp1[t];
  for (int k = 0; k < 128; ++k) h = fmaf(ra[k], Wp1[k*128 + t], h);
  ga[t] = fmaxf(h, 0.f);
  __syncthreads();
  float d2 = bp2[t];
  for (int k = 0; k < 128; ++k) d2 = fmaf(ga[k], Wp2[k*128 + t], d2);
  si += d2;
  rb[t] = fmaxf(si, 0.f);
  __syncthreads();
  float h2 = bp3[t];
  for (int k = 0; k < 128; ++k) h2 = fmaf(rb[k], Wp3[k*128 + t], h2);
  gb[t] = fmaxf(h2, 0.f);
  __syncthreads();
  float d4 = bp4[t];
  for (int k = 0; k < 128; ++k) d4 = fmaf(gb[k], Wp4[k*128 + t], d4);
  si += d4;
  rc[t] = fmaxf(si, 0.f);
  __syncthreads();
  if (t < 20) {
    float a = bout[t];
    for (int k = 0; k < 128; ++k) a = fmaf(rc[k], Wout[k*20 + t], a);
    out[19200 + i*20 + t] = a;
  }
}

extern "C" void kernel_launch(void* const* d_in, const int* in_sizes, int n_in,
                              void* d_out, int out_size, void* d_ws, size_t ws_size,
                              hipStream_t stream)
{
  (void)in_sizes; (void)n_in; (void)out_size; (void)ws_size;
  const float* msa   = (const float*)d_in[0];
  const float* pair  = (const float*)d_in[1];
  const float* xyz   = (const float*)d_in[2];
  const float* state = (const float*)d_in[3];
  const int*   idx   = (const int*)d_in[4];
  const unsigned char* rmask = (const unsigned char*)d_in[5];
  const float* W_en = (const float*)d_in[6];
  const float* b_en = (const float*)d_in[7];
  const float* Wn1  = (const float*)d_in[8];
  const float* bn1  = (const float*)d_in[9];
  const float* Wn2  = (const float*)d_in[10];
  const float* bn2  = (const float*)d_in[11];
  const float* W_ee = (const float*)d_in[12];
  const float* b_ee = (const float*)d_in[13];
  const float* We1  = (const float*)d_in[14];
  const float* be1  = (const float*)d_in[15];
  const float* We2  = (const float*)d_in[16];
  const float* be2  = (const float*)d_in[17];
  const float* Wm1  = (const float*)d_in[18];
  const float* bm1  = (const float*)d_in[19];
  const float* Wm2  = (const float*)d_in[20];
  const float* bm2  = (const float*)d_in[21];
  const float* Wl0  = (const float*)d_in[22];
  const float* bl0  = (const float*)d_in[23];
  const float* Ws0  = (const float*)d_in[24];
  const float* bs0  = (const float*)d_in[25];
  const float* Wsi  = (const float*)d_in[26];
  const float* bsi  = (const float*)d_in[27];
  const float* Wp1  = (const float*)d_in[28];
  const float* bp1  = (const float*)d_in[29];
  const float* Wp2  = (const float*)d_in[30];
  const float* bp2  = (const float*)d_in[31];
  const float* Wp3  = (const float*)d_in[32];
  const float* bp3  = (const float*)d_in[33];
  const float* Wp4  = (const float*)d_in[34];
  const float* bp4  = (const float*)d_in[35];
  const float* Wout = (const float*)d_in[36];
  const float* bout = (const float*)d_in[37];

  float* wsf    = (float*)d_ws;
  float* seq_ln = wsf + WS_SEQ;
  float* nodev  = wsf + WS_NODE;
  int*   nbr    = (int*)(wsf + WS_NBR);
  float* soutf  = wsf + WS_SOUT;
  float* csee   = wsf + WS_CSEE;
  float* e0ws   = wsf + WS_E0;
  float* out = (float*)d_out;

  kernP<<<1, 256, 0, stream>>>(W_ee, csee);
  kernA<<<LL, 256, 0, stream>>>(msa, state, W_en, b_en, Wn1, bn1, Wn2, bn2, seq_ln, nodev);
  kernB<<<LL, 256, 0, stream>>>(xyz, nbr);
  kernC1<<<LL*2, 256, 0, stream>>>(pair, xyz, idx, W_ee, b_ee, csee, nbr, e0ws);
  kernC2<<<LL, 256, 0, stream>>>(xyz, rmask, We1, be1, We2, be2, Wm1, bm1, Wm2, bm2,
                                 Wl0, bl0, nodev, nbr, e0ws, soutf, out);
  kernD<<<LL, 128, 0, stream>>>(seq_ln, soutf, Ws0, bs0, Wsi, bsi, Wp1, bp1, Wp2, bp2,
                                Wp3, bp3, Wp4, bp4, Wout, bout, out);
}

// Round 9
// 168.648 us; speedup vs baseline: 1.3472x; 1.0393x over previous
//
#include <hip/hip_runtime.h>
#include <hip/hip_bf16.h>

#define LL 768
#define TOPK 128

// workspace layout (floats)
#define WS_SEQ  0                        // 768*256
#define WS_NODE (WS_SEQ + LL*256)        // 768*32
#define WS_NBR  (WS_NODE + LL*32)        // 768*128 ints
#define WS_SOUT (WS_NBR + LL*TOPK)       // 768*16
#define WS_CSEE (WS_SOUT + LL*16)        // 32
#define WS_E0   (WS_CSEE + 64)           // 768*128*32 floats

#define FMA_ROW32(ACC, XVAL, WPTR) do {                                   \
    const float _x = (XVAL);                                              \
    const float* __restrict__ _w = (WPTR);                                \
    _Pragma("unroll")                                                     \
    for (int _c = 0; _c < 32; ++_c) ACC[_c] = fmaf(_x, _w[_c], ACC[_c]);  \
  } while (0)

// bf16 pair pack/unpack (RNE)
__device__ __forceinline__ unsigned bfpack(float a, float b) {
  unsigned ua = __float_as_uint(a);
  ua = (ua + 0x7fffu + ((ua >> 16) & 1u)) >> 16;
  unsigned ub = __float_as_uint(b);
  ub = (ub + 0x7fffu + ((ub >> 16) & 1u)) & 0xffff0000u;
  return ua | ub;
}
__device__ __forceinline__ float bflo(unsigned v) { return __uint_as_float(v << 16); }
__device__ __forceinline__ float bfhi(unsigned v) { return __uint_as_float(v & 0xffff0000u); }

__device__ __forceinline__ float block_sum_256(float v, float* red, int t) {
#pragma unroll
  for (int o = 32; o > 0; o >>= 1) v += __shfl_xor(v, o, 64);
  __syncthreads();
  if ((t & 63) == 0) red[t >> 6] = v;
  __syncthreads();
  return red[0] + red[1] + red[2] + red[3];
}

// ---------------- Kernel P: column sums (LN-linearity hoist for C1) --------
__global__ __launch_bounds__(256) void kernP(const float* __restrict__ W_ee,
                                             float* __restrict__ colsum_ee)
{
  __shared__ float part[8][33];
  const int c = threadIdx.x & 31, sg = threadIdx.x >> 5;
  float s = 0.f;
  for (int k = sg*16; k < sg*16 + 16; ++k) s += W_ee[k*32 + c];
  part[sg][c] = s;
  __syncthreads();
  if (threadIdx.x < 32) {
    float tot = 0.f;
#pragma unroll
    for (int g = 0; g < 8; ++g) tot += part[g][threadIdx.x];
    colsum_ee[threadIdx.x] = tot;
  }
}

// ---------------- Kernel A: seq LN, state LN, node MLP + LN ----------------
__global__ __launch_bounds__(256) void kernA(
    const float* __restrict__ msa, const float* __restrict__ state,
    const float* __restrict__ W_en, const float* __restrict__ b_en,
    const float* __restrict__ Wn1, const float* __restrict__ bn1,
    const float* __restrict__ Wn2, const float* __restrict__ bn2,
    float* __restrict__ seq_ln, float* __restrict__ nodeo)
{
  const int i = blockIdx.x, t = threadIdx.x;
  __shared__ float x[256];
  __shared__ float red[4];
  __shared__ float sn[16], n0[32], tn[32], hh[64], n1v[32];

  float v = msa[i*256 + t];
  float mean = block_sum_256(v, red, t) * (1.f/256.f);
  float d = v - mean;
  float var = block_sum_256(d*d, red, t) * (1.f/256.f);
  float xn = d / sqrtf(var + 1e-5f);
  x[t] = xn;
  seq_ln[i*256 + t] = xn;

  if (t < 16) {
    float m2 = 0.f;
    for (int k = 0; k < 16; ++k) m2 += state[i*16 + k];
    m2 *= (1.f/16.f);
    float v2 = 0.f;
    for (int k = 0; k < 16; ++k) { float dd = state[i*16 + k] - m2; v2 += dd*dd; }
    v2 *= (1.f/16.f);
    sn[t] = (state[i*16 + t] - m2) / sqrtf(v2 + 1e-5f);
  }
  __syncthreads();

  if (t < 32) {
    float a = b_en[t];
    for (int k = 0; k < 256; ++k) a = fmaf(x[k], W_en[k*32 + t], a);
    for (int k = 0; k < 16; ++k)  a = fmaf(sn[k], W_en[(256+k)*32 + t], a);
    n0[t] = a;
  }
  __syncthreads();
  if (t < 32) {
    float m = 0.f;
    for (int k = 0; k < 32; ++k) m += n0[k];
    m *= (1.f/32.f);
    float vv = 0.f;
    for (int k = 0; k < 32; ++k) { float dd = n0[k] - m; vv += dd*dd; }
    vv *= (1.f/32.f);
    tn[t] = (n0[t] - m) / sqrtf(vv + 1e-5f);
  }
  __syncthreads();
  if (t < 64) {
    float a = bn1[t];
    for (int k = 0; k < 32; ++k) a = fmaf(tn[k], Wn1[k*64 + t], a);
    hh[t] = fmaxf(a, 0.f);
  }
  __syncthreads();
  if (t < 32) {
    float a = n0[t] + bn2[t];
    for (int k = 0; k < 64; ++k) a = fmaf(hh[k], Wn2[k*32 + t], a);
    n1v[t] = a;
  }
  __syncthreads();
  if (t < 32) {
    float m = 0.f;
    for (int k = 0; k < 32; ++k) m += n1v[k];
    m *= (1.f/32.f);
    float vv = 0.f;
    for (int k = 0; k < 32; ++k) { float dd = n1v[k] - m; vv += dd*dd; }
    vv *= (1.f/32.f);
    nodeo[i*32 + t] = (n1v[t] - m) / sqrtf(vv + 1e-5f);
  }
}

// ---------------- Kernel B: top-128 nearest via 4-pass radix select --------
__global__ __launch_bounds__(256) void kernB(const float* __restrict__ xyz,
                                             int* __restrict__ nbr)
{
  const int i = blockIdx.x, t = threadIdx.x;
  const int lane = t & 63, wv = t >> 6;
  __shared__ unsigned hist[256];
  __shared__ int selBin, below;
  __shared__ unsigned wcL[4], wcE[4];

  const float cix = xyz[i*9+3], ciy = xyz[i*9+4], ciz = xyz[i*9+5];
  unsigned key[3];
#pragma unroll
  for (int r = 0; r < 3; ++r) {
    const int j = r*256 + t;
    float dx = __fadd_rn(cix, -xyz[j*9+3]);
    float dy = __fadd_rn(ciy, -xyz[j*9+4]);
    float dz = __fadd_rn(ciz, -xyz[j*9+5]);
    float Dv = sqrtf(__fadd_rn(__fadd_rn(__fadd_rn(__fmul_rn(dx,dx),
                       __fmul_rn(dy,dy)), __fmul_rn(dz,dz)), 1e-8f));
    key[r] = __float_as_uint(Dv);
  }

  unsigned prefix = 0;
  int rank = 127, cntLess = 0;
#pragma unroll
  for (int pass = 0; pass < 4; ++pass) {
    const int shift = 24 - pass*8;
    const unsigned hiMask = (pass == 0) ? 0u : (0xFFFFFFFFu << (shift + 8));
    hist[t] = 0;
    __syncthreads();
#pragma unroll
    for (int r = 0; r < 3; ++r)
      if ((key[r] & hiMask) == (prefix & hiMask))
        atomicAdd(&hist[(key[r] >> shift) & 0xffu], 1u);
    __syncthreads();
    if (t < 64) {
      unsigned s0 = hist[t*4], s1 = hist[t*4+1], s2 = hist[t*4+2], s3 = hist[t*4+3];
      int tot = (int)(s0 + s1 + s2 + s3);
      int inc = tot;
#pragma unroll
      for (int o = 1; o < 64; o <<= 1) {
        int v = __shfl_up(inc, o);
        if (t >= o) inc += v;
      }
      int excl = inc - tot;
      if (rank >= excl && rank < inc) {
        int c = excl, bsel = t*4;
        if (rank >= c + (int)s0) { c += (int)s0; bsel = t*4+1;
          if (rank >= c + (int)s1) { c += (int)s1; bsel = t*4+2;
            if (rank >= c + (int)s2) { c += (int)s2; bsel = t*4+3; } } }
        selBin = bsel; below = c;
      }
    }
    __syncthreads();
    prefix |= ((unsigned)selBin) << shift;
    rank -= below;
    cntLess += below;
    __syncthreads();
  }
  const unsigned thr = prefix;

  const unsigned long long lmask = (1ull << lane) - 1ull;
  unsigned baseLt = 0, baseEq = (unsigned)cntLess;
#pragma unroll
  for (int r = 0; r < 3; ++r) {
    const int j = r*256 + t;
    const bool pl = key[r] < thr;
    const bool pe = key[r] == thr;
    unsigned long long balL = __ballot(pl);
    unsigned long long balE = __ballot(pe);
    unsigned preL = (unsigned)__popcll(balL & lmask);
    unsigned preE = (unsigned)__popcll(balE & lmask);
    if (lane == 0) { wcL[wv] = (unsigned)__popcll(balL); wcE[wv] = (unsigned)__popcll(balE); }
    __syncthreads();
    unsigned wbL = 0, wbE = 0, totL = 0, totE = 0;
#pragma unroll
    for (int w = 0; w < 4; ++w) {
      if (w < wv) { wbL += wcL[w]; wbE += wcE[w]; }
      totL += wcL[w]; totE += wcE[w];
    }
    if (pl) nbr[i*TOPK + baseLt + wbL + preL] = j;
    if (pe) {
      unsigned pos = baseEq + wbE + preE;
      if (pos < TOPK) nbr[i*TOPK + pos] = j;
    }
    baseLt += totL; baseEq += totE;
    __syncthreads();
  }
}

// ---------------- Kernel C1: edge0 (pre-LN) per selected edge --------------
__global__ __launch_bounds__(256) void kernC1(
    const float* __restrict__ pair, const float* __restrict__ xyz,
    const int* __restrict__ idx,
    const float* __restrict__ W_ee, const float* __restrict__ b_ee,
    const float* __restrict__ colsum_ee,
    const int* __restrict__ nbr, float* __restrict__ e0ws)
{
  const int i = blockIdx.x >> 1, part = blockIdx.x & 1;
  const int t = threadIdx.x, lane = t & 63, wv = t >> 6;
  const int slot = lane & 15, q = lane >> 4;     // q = 0..3 k-quarter
  const int p = part*64 + wv*16 + slot;          // neighbor slot 0..127

  const int j = nbr[i*TOPK + p];
  const float cix = xyz[i*9+3], ciy = xyz[i*9+4], ciz = xyz[i*9+5];
  const float dx = __fadd_rn(cix, -xyz[j*9+3]);
  const float dy = __fadd_rn(ciy, -xyz[j*9+4]);
  const float dz = __fadd_rn(ciz, -xyz[j*9+5]);
  const float Dv = sqrtf(__fadd_rn(__fadd_rn(__fadd_rn(__fmul_rn(dx,dx),
                      __fmul_rn(dy,dy)), __fmul_rn(dz,dz)), 1e-8f));

  const float* prow = pair + (((size_t)i*LL + j) * 128) + q*32;
  float acc[32];
#pragma unroll
  for (int c = 0; c < 32; ++c) acc[c] = 0.f;
  float s = 0.f, ss = 0.f;
#pragma unroll 2
  for (int q4 = 0; q4 < 8; ++q4) {
    float4 v = ((const float4*)prow)[q4];
    s  += (v.x + v.y) + (v.z + v.w);
    ss += v.x*v.x + v.y*v.y + v.z*v.z + v.w*v.w;
    const float* wr = W_ee + (q*32 + q4*4)*32;
    FMA_ROW32(acc, v.x, wr);
    FMA_ROW32(acc, v.y, wr + 32);
    FMA_ROW32(acc, v.z, wr + 64);
    FMA_ROW32(acc, v.w, wr + 96);
  }
  s  += __shfl_xor(s, 16);  s  += __shfl_xor(s, 32);
  ss += __shfl_xor(ss, 16); ss += __shfl_xor(ss, 32);
  const float pm  = s * (1.f/128.f);
  const float pvv = ss * (1.f/128.f) - pm*pm;
  const float prs = 1.f / sqrtf(pvv + 1e-5f);

#pragma unroll
  for (int c = 0; c < 32; ++c) acc[c] *= prs;

#pragma unroll 4
  for (int kk = 0; kk < 16; ++kk) {
    const int k = q*16 + kk;
    float mu = 2.f + (float)k * (20.f/63.f);
    float u  = (Dv - mu) / 0.3125f;
    FMA_ROW32(acc, expf(-(u*u)), W_ee + (128+k)*32);
  }
  if (q == 0) {
    const float offv = (float)(idx[j] - idx[i]);
    const float sg = (offv > 0.f) ? 1.f : ((offv < 0.f) ? -1.f : 0.f);
    const float xsep = sg * logf(fabsf(offv) + 1.f);
    FMA_ROW32(acc, xsep, W_ee + 192*32);
    const float corr = -prs * pm;
#pragma unroll
    for (int c = 0; c < 32; ++c) acc[c] += b_ee[c] + corr * colsum_ee[c];
  }
#pragma unroll
  for (int c = 0; c < 32; ++c) {
    acc[c] += __shfl_xor(acc[c], 16);
    acc[c] += __shfl_xor(acc[c], 32);
  }

  float4* e4 = (float4*)e0ws;
#pragma unroll
  for (int cc = 0; cc < 2; ++cc) {
    const int c4 = q*2 + cc;
    float4 w = make_float4(acc[c4*4], acc[c4*4+1], acc[c4*4+2], acc[c4*4+3]);
    e4[((size_t)i*8 + c4)*128 + p] = w;
  }
}

// ---------------- Kernel C2: edge MLP + message MLP + reduce ---------------
// 128 edges/block. lane l owns edges {l, l+64}; wave wv owns a CONTIGUOUS
// channel strip (16 ch of h/m1, 8 of e2, 10 of m2) -> all weight loads are
// wave-uniform => scalar s_load (no per-lane VMEM latency). Acts in LDS.
__global__ __launch_bounds__(256, 3) void kernC2(
    const float* __restrict__ xyz, const unsigned char* __restrict__ rmask,
    const float* __restrict__ We1, const float* __restrict__ be1,
    const float* __restrict__ We2, const float* __restrict__ be2,
    const float* __restrict__ Wm1, const float* __restrict__ bm1,
    const float* __restrict__ Wm2, const float* __restrict__ bm2,
    const float* __restrict__ Wl0, const float* __restrict__ bl0,
    const float* __restrict__ node, const int* __restrict__ nbr,
    const float* __restrict__ e0ws,
    float* __restrict__ soutf, float* __restrict__ out)
{
  const int i = blockIdx.x, t = threadIdx.x;
  const int lane = t & 63;
  const int wv = __builtin_amdgcn_readfirstlane(t >> 6);   // wave-uniform 0..3
  __shared__ float    A[128][33];   // e0 -> ed -> e2 -> ed2 (f32, in place)
  __shared__ unsigned Bb[128][33];  // h -> m1 (bf16 pairs)
  __shared__ unsigned nd[128][17];  // node rows (bf16 pairs)
  __shared__ float ni[32];
  __shared__ float relv[128][3];
  __shared__ float mA[128], sgA[128];
  __shared__ float P2[4][14];
  __shared__ float fin[44];

  if (t < 32) ni[t] = node[i*32 + t];
  {  // stage neighbor node rows (bf16) + rel
    const int pp = t >> 1, hh2 = t & 1;
    const int jj = nbr[i*TOPK + pp];
    const float4* nr = (const float4*)(node + jj*32 + hh2*16);
    float4 a0 = nr[0], a1 = nr[1], a2 = nr[2], a3 = nr[3];
    unsigned* dst = &nd[pp][hh2*8];
    dst[0] = bfpack(a0.x, a0.y); dst[1] = bfpack(a0.z, a0.w);
    dst[2] = bfpack(a1.x, a1.y); dst[3] = bfpack(a1.z, a1.w);
    dst[4] = bfpack(a2.x, a2.y); dst[5] = bfpack(a2.z, a2.w);
    dst[6] = bfpack(a3.x, a3.y); dst[7] = bfpack(a3.z, a3.w);
    if (hh2 == 0) {
      relv[pp][0] = xyz[jj*9+3] - xyz[i*9+3];
      relv[pp][1] = xyz[jj*9+4] - xyz[i*9+4];
      relv[pp][2] = xyz[jj*9+5] - xyz[i*9+5];
    }
  }
  {  // stage e0 rows from C1 output (f32)
    const int p = t & 127, hh = t >> 7;
    const float4* src = (const float4*)e0ws + ((size_t)i*8 + hh*4)*128 + p;
#pragma unroll
    for (int n = 0; n < 4; ++n) {
      float4 v = src[(size_t)n*128];
      A[p][hh*16 + n*4 + 0] = v.x;
      A[p][hh*16 + n*4 + 1] = v.y;
      A[p][hh*16 + n*4 + 2] = v.z;
      A[p][hh*16 + n*4 + 3] = v.w;
    }
  }
  __syncthreads();

  // LN(A) in place; keep (mean, sigma) to recover raw e0 for the residual
  if (t < 128) {
    float mm = 0.f;
#pragma unroll
    for (int c = 0; c < 32; ++c) mm += A[t][c];
    mm *= (1.f/32.f);
    float vv = 0.f;
#pragma unroll
    for (int c = 0; c < 32; ++c) { float dd = A[t][c]-mm; vv += dd*dd; }
    vv *= (1.f/32.f);
    const float sg = sqrtf(vv + 1e-5f);
    const float rs = 1.f / sg;
#pragma unroll
    for (int c = 0; c < 32; ++c) A[t][c] = (A[t][c]-mm)*rs;
    mA[t] = mm; sgA[t] = sg;
  }
  __syncthreads();

  // ---- h = relu(ed @ We1 + be1): 2 edges x 16 ch (cols [16wv,16wv+16)) ----
  {
    float hacc[2][16];
#pragma unroll
    for (int m = 0; m < 2; ++m)
#pragma unroll
      for (int c = 0; c < 16; ++c) hacc[m][c] = 0.f;
#pragma unroll 4
    for (int k = 0; k < 32; ++k) {
      const float* wb = We1 + k*64 + 16*wv;     // wave-uniform -> s_load
      const float4 w0 = *(const float4*)(wb);
      const float4 w1 = *(const float4*)(wb + 4);
      const float4 w2 = *(const float4*)(wb + 8);
      const float4 w3 = *(const float4*)(wb + 12);
      const float a0 = A[lane][k], a1 = A[lane+64][k];
#pragma unroll
      for (int m = 0; m < 2; ++m) {
        const float av = m ? a1 : a0;
        hacc[m][0]  = fmaf(av, w0.x, hacc[m][0]);
        hacc[m][1]  = fmaf(av, w0.y, hacc[m][1]);
        hacc[m][2]  = fmaf(av, w0.z, hacc[m][2]);
        hacc[m][3]  = fmaf(av, w0.w, hacc[m][3]);
        hacc[m][4]  = fmaf(av, w1.x, hacc[m][4]);
        hacc[m][5]  = fmaf(av, w1.y, hacc[m][5]);
        hacc[m][6]  = fmaf(av, w1.z, hacc[m][6]);
        hacc[m][7]  = fmaf(av, w1.w, hacc[m][7]);
        hacc[m][8]  = fmaf(av, w2.x, hacc[m][8]);
        hacc[m][9]  = fmaf(av, w2.y, hacc[m][9]);
        hacc[m][10] = fmaf(av, w2.z, hacc[m][10]);
        hacc[m][11] = fmaf(av, w2.w, hacc[m][11]);
        hacc[m][12] = fmaf(av, w3.x, hacc[m][12]);
        hacc[m][13] = fmaf(av, w3.y, hacc[m][13]);
        hacc[m][14] = fmaf(av, w3.z, hacc[m][14]);
        hacc[m][15] = fmaf(av, w3.w, hacc[m][15]);
      }
    }
#pragma unroll
    for (int m = 0; m < 2; ++m) {
      const int e = lane + 64*m;
#pragma unroll
      for (int n = 0; n < 8; ++n) {
        const float lo = fmaxf(hacc[m][2*n]   + be1[16*wv + 2*n],   0.f);
        const float hi = fmaxf(hacc[m][2*n+1] + be1[16*wv + 2*n+1], 0.f);
        Bb[e][8*wv + n] = bfpack(lo, hi);
      }
    }
  }
  __syncthreads();

  // ---- e2 = e0raw + h @ We2 + be2: 2 edges x 8 ch (cols [8wv,8wv+8)) ----
  {
    float e2a[2][8];
#pragma unroll
    for (int m = 0; m < 2; ++m)
#pragma unroll
      for (int c = 0; c < 8; ++c) e2a[m][c] = 0.f;
#pragma unroll 4
    for (int kk = 0; kk < 32; ++kk) {   // k = 2kk, 2kk+1
      const float* wbl = We2 + (2*kk)*32   + 8*wv;   // uniform
      const float* wbh = We2 + (2*kk+1)*32 + 8*wv;
      const float4 wl0 = *(const float4*)(wbl);
      const float4 wl1 = *(const float4*)(wbl + 4);
      const float4 wh0 = *(const float4*)(wbh);
      const float4 wh1 = *(const float4*)(wbh + 4);
      const unsigned v0 = Bb[lane][kk], v1 = Bb[lane+64][kk];
#pragma unroll
      for (int m = 0; m < 2; ++m) {
        const unsigned v = m ? v1 : v0;
        const float al = bflo(v), ah = bfhi(v);
        e2a[m][0] = fmaf(al, wl0.x, fmaf(ah, wh0.x, e2a[m][0]));
        e2a[m][1] = fmaf(al, wl0.y, fmaf(ah, wh0.y, e2a[m][1]));
        e2a[m][2] = fmaf(al, wl0.z, fmaf(ah, wh0.z, e2a[m][2]));
        e2a[m][3] = fmaf(al, wl0.w, fmaf(ah, wh0.w, e2a[m][3]));
        e2a[m][4] = fmaf(al, wl1.x, fmaf(ah, wh1.x, e2a[m][4]));
        e2a[m][5] = fmaf(al, wl1.y, fmaf(ah, wh1.y, e2a[m][5]));
        e2a[m][6] = fmaf(al, wl1.z, fmaf(ah, wh1.z, e2a[m][6]));
        e2a[m][7] = fmaf(al, wl1.w, fmaf(ah, wh1.w, e2a[m][7]));
      }
    }
#pragma unroll
    for (int m = 0; m < 2; ++m) {
      const int e = lane + 64*m;
      const float sg = sgA[e], mm = mA[e];
#pragma unroll
      for (int c = 0; c < 8; ++c) {
        const int ch = 8*wv + c;
        const float e0raw = fmaf(A[e][ch], sg, mm);   // undo LN
        A[e][ch] = e2a[m][c] + e0raw + be2[ch];
      }
    }
  }
  __syncthreads();

  // LN(e2) in place
  if (t < 128) {
    float mm = 0.f;
#pragma unroll
    for (int c = 0; c < 32; ++c) mm += A[t][c];
    mm *= (1.f/32.f);
    float vv = 0.f;
#pragma unroll
    for (int c = 0; c < 32; ++c) { float dd = A[t][c]-mm; vv += dd*dd; }
    vv *= (1.f/32.f);
    const float rs = 1.f / sqrtf(vv + 1e-5f);
#pragma unroll
    for (int c = 0; c < 32; ++c) A[t][c] = (A[t][c]-mm)*rs;
  }
  __syncthreads();

  // ---- m1 = relu([ni, nj, ed2] @ Wm1 + bm1): 2 edges x 16 ch ----
  {
    float tmp[16];   // ni part — identical for both edges
#pragma unroll
    for (int c = 0; c < 16; ++c) tmp[c] = bm1[16*wv + c];
#pragma unroll 4
    for (int k = 0; k < 32; ++k) {
      const float* wb = Wm1 + k*64 + 16*wv;   // uniform
      const float av = ni[k];
#pragma unroll
      for (int c = 0; c < 16; ++c) tmp[c] = fmaf(av, wb[c], tmp[c]);
    }
    float macc[2][16];
#pragma unroll
    for (int m = 0; m < 2; ++m)
#pragma unroll
      for (int c = 0; c < 16; ++c) macc[m][c] = 0.f;
#pragma unroll 4
    for (int kk = 0; kk < 16; ++kk) {   // h_j part (bf16 pairs), k = 2kk,2kk+1
      const float* wbl = Wm1 + (32+2*kk)*64 + 16*wv;   // uniform
      const float* wbh = Wm1 + (33+2*kk)*64 + 16*wv;
      const unsigned v0 = nd[lane][kk], v1 = nd[lane+64][kk];
#pragma unroll
      for (int m = 0; m < 2; ++m) {
        const unsigned v = m ? v1 : v0;
        const float al = bflo(v), ah = bfhi(v);
#pragma unroll
        for (int c = 0; c < 16; ++c)
          macc[m][c] = fmaf(al, wbl[c], fmaf(ah, wbh[c], macc[m][c]));
      }
    }
#pragma unroll 4
    for (int k = 0; k < 32; ++k) {  // edge part (f32 A)
      const float* wb = Wm1 + (64+k)*64 + 16*wv;   // uniform
      const float a0 = A[lane][k], a1 = A[lane+64][k];
#pragma unroll
      for (int m = 0; m < 2; ++m) {
        const float av = m ? a1 : a0;
#pragma unroll
        for (int c = 0; c < 16; ++c)
          macc[m][c] = fmaf(av, wb[c], macc[m][c]);
      }
    }
    __syncthreads();   // all Bb reads (e2 phase) complete before overwrite
#pragma unroll
    for (int m = 0; m < 2; ++m) {
      const int e = lane + 64*m;
#pragma unroll
      for (int n = 0; n < 8; ++n) {
        const float lo = fmaxf(macc[m][2*n]   + tmp[2*n],   0.f);
        const float hi = fmaxf(macc[m][2*n+1] + tmp[2*n+1], 0.f);
        Bb[e][8*wv + n] = bfpack(lo, hi);
      }
    }
  }
  __syncthreads();

  // ---- m2: 2 edges x 10 outs (cols [10wv,10wv+10)); expand + wave reduce ----
  {
    float p2[2][10];
#pragma unroll
    for (int m = 0; m < 2; ++m)
#pragma unroll
      for (int o = 0; o < 10; ++o) p2[m][o] = 0.f;
#pragma unroll 4
    for (int kk = 0; kk < 32; ++kk) {   // k = 2kk, 2kk+1
      const float* wr0 = Wm2 + (2*kk)*40   + 10*wv;   // uniform
      const float* wr1 = Wm2 + (2*kk+1)*40 + 10*wv;
      const unsigned v0 = Bb[lane][kk], v1 = Bb[lane+64][kk];
#pragma unroll
      for (int m = 0; m < 2; ++m) {
        const unsigned v = m ? v1 : v0;
        const float al = bflo(v), ah = bfhi(v);
#pragma unroll
        for (int o = 0; o < 10; ++o)
          p2[m][o] = fmaf(al, wr0[o], fmaf(ah, wr1[o], p2[m][o]));
      }
    }
    float outv[14];
#pragma unroll
    for (int s = 0; s < 14; ++s) outv[s] = 0.f;
#pragma unroll
    for (int m = 0; m < 2; ++m) {
      const int e = lane + 64*m;
      if (wv == 3) {   // outs 30..39: 30,31 plain; 32,33 x rel; 34..39 plain
        const float v0 = p2[m][0] + bm2[30], v1 = p2[m][1] + bm2[31];
        const float v2 = p2[m][2] + bm2[32], v3 = p2[m][3] + bm2[33];
        outv[0] += v0; outv[1] += v1;
        outv[2] = fmaf(v2, relv[e][0], outv[2]);
        outv[3] = fmaf(v2, relv[e][1], outv[3]);
        outv[4] = fmaf(v2, relv[e][2], outv[4]);
        outv[5] = fmaf(v3, relv[e][0], outv[5]);
        outv[6] = fmaf(v3, relv[e][1], outv[6]);
        outv[7] = fmaf(v3, relv[e][2], outv[7]);
#pragma unroll
        for (int o = 4; o < 10; ++o) outv[4 + o] += p2[m][o] + bm2[30 + o];
      } else {
#pragma unroll
        for (int o = 0; o < 10; ++o) outv[o] += p2[m][o] + bm2[10*wv + o];
      }
    }
    // full-wave reduce (each wave covers ALL 128 edges for its channels)
#pragma unroll
    for (int s = 0; s < 14; ++s) {
      float v = outv[s];
#pragma unroll
      for (int o = 1; o < 64; o <<= 1) v += __shfl_xor(v, o);
      outv[s] = v;
    }
    if (lane == 0) {
      const int nsl = (wv == 3) ? 14 : 10;
      for (int s = 0; s < nsl; ++s) P2[wv][s] = outv[s];
    }
  }
  __syncthreads();
  if (t < 44) fin[t] = (t < 30) ? P2[t/10][t%10] : P2[3][t-30];
  __syncthreads();

  if (t < 16) {  // state_out = [node_i, m_l0] @ Wl0 + bl0
    float a = bl0[t];
#pragma unroll
    for (int k = 0; k < 32; ++k) a = fmaf(ni[k], Wl0[k*16 + t], a);
#pragma unroll
    for (int k = 0; k < 32; ++k) a = fmaf(fin[k] * (1.f/128.f), Wl0[(32+k)*16 + t], a);
    soutf[i*16 + t] = a;
    out[LL*9 + i*16 + t] = a;
  }
  if (t == 0) {  // frame update
    float ve[6], wa[6];
#pragma unroll
    for (int qq = 0; qq < 6; ++qq) ve[qq] = fin[32 + qq] * (1.f/128.f);
#pragma unroll
    for (int qq = 0; qq < 6; ++qq) wa[qq] = fin[38 + qq] * (1.f/128.f);
    float l1[9];
#pragma unroll
    for (int a = 0; a < 3; ++a)
#pragma unroll
      for (int d = 0; d < 3; ++d) l1[a*3 + d] = xyz[i*9 + a*3 + d] - xyz[i*9 + 3 + d];
    float T[3], Rv[3];
#pragma unroll
    for (int d = 0; d < 3; ++d) {
      float va0 = wa[0]*l1[d] + wa[1]*l1[3 + d] + wa[2]*l1[6 + d];
      float va1 = wa[3]*l1[d] + wa[4]*l1[3 + d] + wa[5]*l1[6 + d];
      T[d]  = (ve[d] + va0) / 10.f;
      Rv[d] = (ve[3 + d] + va1) / 100.f;
    }
    float qn = sqrtf(1.f + Rv[0]*Rv[0] + Rv[1]*Rv[1] + Rv[2]*Rv[2]);
    float qA = 1.f/qn, qB = Rv[0]/qn, qC = Rv[1]/qn, qD = Rv[2]/qn;
    float Rm[9];
    Rm[0] = qA*qA + qB*qB - qC*qC - qD*qD;
    Rm[1] = 2.f*qB*qC - 2.f*qA*qD;
    Rm[2] = 2.f*qB*qD + 2.f*qA*qC;
    Rm[3] = 2.f*qB*qC + 2.f*qA*qD;
    Rm[4] = qA*qA - qB*qB + qC*qC - qD*qD;
    Rm[5] = 2.f*qC*qD - 2.f*qA*qB;
    Rm[6] = 2.f*qB*qD - 2.f*qA*qC;
    Rm[7] = 2.f*qC*qD + 2.f*qA*qB;
    Rm[8] = qA*qA - qB*qB - qC*qC + qD*qD;
    if (rmask[i]) {
      Rm[0] = 1.f; Rm[1] = 0.f; Rm[2] = 0.f;
      Rm[3] = 0.f; Rm[4] = 1.f; Rm[5] = 0.f;
      Rm[6] = 0.f; Rm[7] = 0.f; Rm[8] = 1.f;
    }
#pragma unroll
    for (int a = 0; a < 3; ++a)
#pragma unroll
      for (int di = 0; di < 3; ++di) {
        float xn = Rm[di*3+0]*l1[a*3+0] + Rm[di*3+1]*l1[a*3+1] + Rm[di*3+2]*l1[a*3+2]
                 + xyz[i*9 + 3 + di] + T[di];
        out[i*9 + a*3 + di] = xn;
      }
  }
}

// ---------------- Kernel D: si MLP stack -> alpha ---------------------------
__global__ __launch_bounds__(128) void kernD(
    const float* __restrict__ seq_ln, const float* __restrict__ st_out,
    const float* __restrict__ Ws0, const float* __restrict__ bs0,
    const float* __restrict__ Wsi, const float* __restrict__ bsi,
    const float* __restrict__ Wp1, const float* __restrict__ bp1,
    const float* __restrict__ Wp2, const float* __restrict__ bp2,
    const float* __restrict__ Wp3, const float* __restrict__ bp3,
    const float* __restrict__ Wp4, const float* __restrict__ bp4,
    const float* __restrict__ Wout, const float* __restrict__ bout,
    float* __restrict__ out)
{
  const int i = blockIdx.x, t = threadIdx.x;
  __shared__ float x0[256], stn[16], ra[128], ga[128], rb[128], gb[128], rc[128];
  x0[t]       = seq_ln[i*256 + t];
  x0[128 + t] = seq_ln[i*256 + 128 + t];
  if (t < 16) {
    float m = 0.f;
    for (int k = 0; k < 16; ++k) m += st_out[i*16 + k];
    m *= (1.f/16.f);
    float v = 0.f;
    for (int k = 0; k < 16; ++k) { float dd = st_out[i*16 + k] - m; v += dd*dd; }
    v *= (1.f/16.f);
    stn[t] = (st_out[i*16 + t] - m) / sqrtf(v + 1e-5f);
  }
  __syncthreads();

  float si = bs0[t] + bsi[t];
  for (int k = 0; k < 256; ++k) si = fmaf(x0[k], Ws0[k*128 + t], si);
  for (int k = 0; k < 16; ++k)  si = fmaf(stn[k], Wsi[k*128 + t], si);
  ra[t] = fmaxf(si, 0.f);
  __syncthreads();
  float h = bp1[t];
  for (int k = 0; k < 128; ++k) h = fmaf(ra[k], Wp1[k*128 + t], h);
  ga[t] = fmaxf(h, 0.f);
  __syncthreads();
  float d2 = bp2[t];
  for (int k = 0; k < 128; ++k) d2 = fmaf(ga[k], Wp2[k*128 + t], d2);
  si += d2;
  rb[t] = fmaxf(si, 0.f);
  __syncthreads();
  float h2 = bp3[t];
  for (int k = 0; k < 128; ++k) h2 = fmaf(rb[k], Wp3[k*128 + t], h2);
  gb[t] = fmaxf(h2, 0.f);
  __syncthreads();
  float d4 = bp4[t];
  for (int k = 0; k < 128; ++k) d4 = fmaf(gb[k], Wp4[k*128 + t], d4);
  si += d4;
  rc[t] = fmaxf(si, 0.f);
  __syncthreads();
  if (t < 20) {
    float a = bout[t];
    for (int k = 0; k < 128; ++k) a = fmaf(rc[k], Wout[k*20 + t], a);
    out[19200 + i*20 + t] = a;
  }
}

extern "C" void kernel_launch(void* const* d_in, const int* in_sizes, int n_in,
                              void* d_out, int out_size, void* d_ws, size_t ws_size,
                              hipStream_t stream)
{
  (void)in_sizes; (void)n_in; (void)out_size; (void)ws_size;
  const float* msa   = (const float*)d_in[0];
  const float* pair  = (const float*)d_in[1];
  const float* xyz   = (const float*)d_in[2];
  const float* state = (const float*)d_in[3];
  const int*   idx   = (const int*)d_in[4];
  const unsigned char* rmask = (const unsigned char*)d_in[5];
  const float* W_en = (const float*)d_in[6];
  const float* b_en = (const float*)d_in[7];
  const float* Wn1  = (const float*)d_in[8];
  const float* bn1  = (const float*)d_in[9];
  const float* Wn2  = (const float*)d_in[10];
  const float* bn2  = (const float*)d_in[11];
  const float* W_ee = (const float*)d_in[12];
  const float* b_ee = (const float*)d_in[13];
  const float* We1  = (const float*)d_in[14];
  const float* be1  = (const float*)d_in[15];
  const float* We2  = (const float*)d_in[16];
  const float* be2  = (const float*)d_in[17];
  const float* Wm1  = (const float*)d_in[18];
  const float* bm1  = (const float*)d_in[19];
  const float* Wm2  = (const float*)d_in[20];
  const float* bm2  = (const float*)d_in[21];
  const float* Wl0  = (const float*)d_in[22];
  const float* bl0  = (const float*)d_in[23];
  const float* Ws0  = (const float*)d_in[24];
  const float* bs0  = (const float*)d_in[25];
  const float* Wsi  = (const float*)d_in[26];
  const float* bsi  = (const float*)d_in[27];
  const float* Wp1  = (const float*)d_in[28];
  const float* bp1  = (const float*)d_in[29];
  const float* Wp2  = (const float*)d_in[30];
  const float* bp2  = (const float*)d_in[31];
  const float* Wp3  = (const float*)d_in[32];
  const float* bp3  = (const float*)d_in[33];
  const float* Wp4  = (const float*)d_in[34];
  const float* bp4  = (const float*)d_in[35];
  const float* Wout = (const float*)d_in[36];
  const float* bout = (const float*)d_in[37];

  float* wsf    = (float*)d_ws;
  float* seq_ln = wsf + WS_SEQ;
  float* nodev  = wsf + WS_NODE;
  int*   nbr    = (int*)(wsf + WS_NBR);
  float* soutf  = wsf + WS_SOUT;
  float* csee   = wsf + WS_CSEE;
  float* e0ws   = wsf + WS_E0;
  float* out = (float*)d_out;

  kernP<<<1, 256, 0, stream>>>(W_ee, csee);
  kernA<<<LL, 256, 0, stream>>>(msa, state, W_en, b_en, Wn1, bn1, Wn2, bn2, seq_ln, nodev);
  kernB<<<LL, 256, 0, stream>>>(xyz, nbr);
  kernC1<<<LL*2, 256, 0, stream>>>(pair, xyz, idx, W_ee, b_ee, csee, nbr, e0ws);
  kernC2<<<LL, 256, 0, stream>>>(xyz, rmask, We1, be1, We2, be2, Wm1, bm1, Wm2, bm2,
                                 Wl0, bl0, nodev, nbr, e0ws, soutf, out);
  kernD<<<LL, 128, 0, stream>>>(seq_ln, soutf, Ws0, bs0, Wsi, bsi, Wp1, bp1, Wp2, bp2,
                                Wp3, bp3, Wp4, bp4, Wout, bout, out);
}

// Round 10
// 131.087 us; speedup vs baseline: 1.7332x; 1.2865x over previous
//
#include <hip/hip_runtime.h>
#include <hip/hip_bf16.h>

#define LL 768
#define TOPK 128

// workspace layout (floats)
#define WS_SEQ  0                        // 768*256
#define WS_NODE (WS_SEQ + LL*256)        // 768*32
#define WS_NBR  (WS_NODE + LL*32)        // 768*128 ints
#define WS_SOUT (WS_NBR + LL*TOPK)       // 768*16
#define WS_CSEE (WS_SOUT + LL*16)        // 32

// bf16 pair pack/unpack (RNE)
__device__ __forceinline__ unsigned bfpack(float a, float b) {
  unsigned ua = __float_as_uint(a);
  ua = (ua + 0x7fffu + ((ua >> 16) & 1u)) >> 16;
  unsigned ub = __float_as_uint(b);
  ub = (ub + 0x7fffu + ((ub >> 16) & 1u)) & 0xffff0000u;
  return ua | ub;
}
__device__ __forceinline__ float bflo(unsigned v) { return __uint_as_float(v << 16); }
__device__ __forceinline__ float bfhi(unsigned v) { return __uint_as_float(v & 0xffff0000u); }

__device__ __forceinline__ float block_sum_256(float v, float* red, int t) {
#pragma unroll
  for (int o = 32; o > 0; o >>= 1) v += __shfl_xor(v, o, 64);
  __syncthreads();
  if ((t & 63) == 0) red[t >> 6] = v;
  __syncthreads();
  return red[0] + red[1] + red[2] + red[3];
}

// ---------------- Kernel P: column sums (LN-linearity hoist) ---------------
__global__ __launch_bounds__(256) void kernP(const float* __restrict__ W_ee,
                                             float* __restrict__ colsum_ee)
{
  __shared__ float part[8][33];
  const int c = threadIdx.x & 31, sg = threadIdx.x >> 5;
  float s = 0.f;
  for (int k = sg*16; k < sg*16 + 16; ++k) s += W_ee[k*32 + c];
  part[sg][c] = s;
  __syncthreads();
  if (threadIdx.x < 32) {
    float tot = 0.f;
#pragma unroll
    for (int g = 0; g < 8; ++g) tot += part[g][threadIdx.x];
    colsum_ee[threadIdx.x] = tot;
  }
}

// ---------------- Kernel A: seq LN, state LN, node MLP + LN ----------------
__global__ __launch_bounds__(256) void kernA(
    const float* __restrict__ msa, const float* __restrict__ state,
    const float* __restrict__ W_en, const float* __restrict__ b_en,
    const float* __restrict__ Wn1, const float* __restrict__ bn1,
    const float* __restrict__ Wn2, const float* __restrict__ bn2,
    float* __restrict__ seq_ln, float* __restrict__ nodeo)
{
  const int i = blockIdx.x, t = threadIdx.x;
  __shared__ float x[256];
  __shared__ float red[4];
  __shared__ float sn[16], n0[32], tn[32], hh[64], n1v[32];

  float v = msa[i*256 + t];
  float mean = block_sum_256(v, red, t) * (1.f/256.f);
  float d = v - mean;
  float var = block_sum_256(d*d, red, t) * (1.f/256.f);
  float xn = d / sqrtf(var + 1e-5f);
  x[t] = xn;
  seq_ln[i*256 + t] = xn;

  if (t < 16) {
    float m2 = 0.f;
    for (int k = 0; k < 16; ++k) m2 += state[i*16 + k];
    m2 *= (1.f/16.f);
    float v2 = 0.f;
    for (int k = 0; k < 16; ++k) { float dd = state[i*16 + k] - m2; v2 += dd*dd; }
    v2 *= (1.f/16.f);
    sn[t] = (state[i*16 + t] - m2) / sqrtf(v2 + 1e-5f);
  }
  __syncthreads();

  if (t < 32) {
    float a = b_en[t];
    for (int k = 0; k < 256; ++k) a = fmaf(x[k], W_en[k*32 + t], a);
    for (int k = 0; k < 16; ++k)  a = fmaf(sn[k], W_en[(256+k)*32 + t], a);
    n0[t] = a;
  }
  __syncthreads();
  if (t < 32) {
    float m = 0.f;
    for (int k = 0; k < 32; ++k) m += n0[k];
    m *= (1.f/32.f);
    float vv = 0.f;
    for (int k = 0; k < 32; ++k) { float dd = n0[k] - m; vv += dd*dd; }
    vv *= (1.f/32.f);
    tn[t] = (n0[t] - m) / sqrtf(vv + 1e-5f);
  }
  __syncthreads();
  if (t < 64) {
    float a = bn1[t];
    for (int k = 0; k < 32; ++k) a = fmaf(tn[k], Wn1[k*64 + t], a);
    hh[t] = fmaxf(a, 0.f);
  }
  __syncthreads();
  if (t < 32) {
    float a = n0[t] + bn2[t];
    for (int k = 0; k < 64; ++k) a = fmaf(hh[k], Wn2[k*32 + t], a);
    n1v[t] = a;
  }
  __syncthreads();
  if (t < 32) {
    float m = 0.f;
    for (int k = 0; k < 32; ++k) m += n1v[k];
    m *= (1.f/32.f);
    float vv = 0.f;
    for (int k = 0; k < 32; ++k) { float dd = n1v[k] - m; vv += dd*dd; }
    vv *= (1.f/32.f);
    nodeo[i*32 + t] = (n1v[t] - m) / sqrtf(vv + 1e-5f);
  }
}

// ---------------- Kernel B: top-128 nearest via 4-pass radix select --------
__global__ __launch_bounds__(256) void kernB(const float* __restrict__ xyz,
                                             int* __restrict__ nbr)
{
  const int i = blockIdx.x, t = threadIdx.x;
  const int lane = t & 63, wv = t >> 6;
  __shared__ unsigned hist[256];
  __shared__ int selBin, below;
  __shared__ unsigned wcL[4], wcE[4];

  const float cix = xyz[i*9+3], ciy = xyz[i*9+4], ciz = xyz[i*9+5];
  unsigned key[3];
#pragma unroll
  for (int r = 0; r < 3; ++r) {
    const int j = r*256 + t;
    float dx = __fadd_rn(cix, -xyz[j*9+3]);
    float dy = __fadd_rn(ciy, -xyz[j*9+4]);
    float dz = __fadd_rn(ciz, -xyz[j*9+5]);
    float Dv = sqrtf(__fadd_rn(__fadd_rn(__fadd_rn(__fmul_rn(dx,dx),
                       __fmul_rn(dy,dy)), __fmul_rn(dz,dz)), 1e-8f));
    key[r] = __float_as_uint(Dv);
  }

  unsigned prefix = 0;
  int rank = 127, cntLess = 0;
#pragma unroll
  for (int pass = 0; pass < 4; ++pass) {
    const int shift = 24 - pass*8;
    const unsigned hiMask = (pass == 0) ? 0u : (0xFFFFFFFFu << (shift + 8));
    hist[t] = 0;
    __syncthreads();
#pragma unroll
    for (int r = 0; r < 3; ++r)
      if ((key[r] & hiMask) == (prefix & hiMask))
        atomicAdd(&hist[(key[r] >> shift) & 0xffu], 1u);
    __syncthreads();
    if (t < 64) {
      unsigned s0 = hist[t*4], s1 = hist[t*4+1], s2 = hist[t*4+2], s3 = hist[t*4+3];
      int tot = (int)(s0 + s1 + s2 + s3);
      int inc = tot;
#pragma unroll
      for (int o = 1; o < 64; o <<= 1) {
        int v = __shfl_up(inc, o);
        if (t >= o) inc += v;
      }
      int excl = inc - tot;
      if (rank >= excl && rank < inc) {
        int c = excl, bsel = t*4;
        if (rank >= c + (int)s0) { c += (int)s0; bsel = t*4+1;
          if (rank >= c + (int)s1) { c += (int)s1; bsel = t*4+2;
            if (rank >= c + (int)s2) { c += (int)s2; bsel = t*4+3; } } }
        selBin = bsel; below = c;
      }
    }
    __syncthreads();
    prefix |= ((unsigned)selBin) << shift;
    rank -= below;
    cntLess += below;
    __syncthreads();
  }
  const unsigned thr = prefix;

  const unsigned long long lmask = (1ull << lane) - 1ull;
  unsigned baseLt = 0, baseEq = (unsigned)cntLess;
#pragma unroll
  for (int r = 0; r < 3; ++r) {
    const int j = r*256 + t;
    const bool pl = key[r] < thr;
    const bool pe = key[r] == thr;
    unsigned long long balL = __ballot(pl);
    unsigned long long balE = __ballot(pe);
    unsigned preL = (unsigned)__popcll(balL & lmask);
    unsigned preE = (unsigned)__popcll(balE & lmask);
    if (lane == 0) { wcL[wv] = (unsigned)__popcll(balL); wcE[wv] = (unsigned)__popcll(balE); }
    __syncthreads();
    unsigned wbL = 0, wbE = 0, totL = 0, totE = 0;
#pragma unroll
    for (int w = 0; w < 4; ++w) {
      if (w < wv) { wbL += wcL[w]; wbE += wcE[w]; }
      totL += wcL[w]; totE += wcE[w];
    }
    if (pl) nbr[i*TOPK + baseLt + wbL + preL] = j;
    if (pe) {
      unsigned pos = baseEq + wbE + preE;
      if (pos < TOPK) nbr[i*TOPK + pos] = j;
    }
    baseLt += totL; baseEq += totE;
    __syncthreads();
  }
}

// ---------------- Kernel C (FUSED C1+C2) ------------------------------------
// One block per residue i, 256 thr, 3 blocks/CU. C1-phase: two 64-edge
// sub-passes; pair rows staged coalesced -> bf16 LDS (union'd with Bb);
// lane = edge, wave = 8-channel strip => ALL weight loads wave-uniform
// (s_load). e0 lands directly in A; C2 phases identical to R9.
__global__ __launch_bounds__(256, 3) void kernC(
    const float* __restrict__ pair, const float* __restrict__ xyz,
    const int* __restrict__ idx, const unsigned char* __restrict__ rmask,
    const float* __restrict__ W_ee, const float* __restrict__ b_ee,
    const float* __restrict__ colsum_ee,
    const float* __restrict__ We1, const float* __restrict__ be1,
    const float* __restrict__ We2, const float* __restrict__ be2,
    const float* __restrict__ Wm1, const float* __restrict__ bm1,
    const float* __restrict__ Wm2, const float* __restrict__ bm2,
    const float* __restrict__ Wl0, const float* __restrict__ bl0,
    const float* __restrict__ node, const int* __restrict__ nbr,
    float* __restrict__ soutf, float* __restrict__ out)
{
  const int i = blockIdx.x, t = threadIdx.x;
  const int lane = t & 63;
  const int wv = __builtin_amdgcn_readfirstlane(t >> 6);   // uniform 0..3
  __shared__ float    A[128][33];      // e0 -> ed -> e2 -> ed2 (f32)
  __shared__ unsigned U[128*33];       // pairB[64][65] then Bb[128][33]
  __shared__ unsigned nd[128][17];     // node rows (bf16 pairs)
  __shared__ int   jl[128];
  __shared__ float Dvv[128], xsepv[128];
  __shared__ float relv[128][3];
  __shared__ float ni[32];
  __shared__ float sQ[64][5], ssQ[64][5];
  __shared__ float pmv[64], prsv[64];
  __shared__ float mA[128], sgA[128];
  __shared__ float P2[4][14];
  __shared__ float fin[44];

  // ---- phase 0: stage ni, nd, jl, relv, Dv, xsep ----
  if (t < 32) ni[t] = node[i*32 + t];
  {
    const int pp = t >> 1, hh2 = t & 1;
    const int jj = nbr[i*TOPK + pp];
    const float4* nr = (const float4*)(node + jj*32 + hh2*16);
    float4 a0 = nr[0], a1 = nr[1], a2 = nr[2], a3 = nr[3];
    unsigned* dst = &nd[pp][hh2*8];
    dst[0] = bfpack(a0.x, a0.y); dst[1] = bfpack(a0.z, a0.w);
    dst[2] = bfpack(a1.x, a1.y); dst[3] = bfpack(a1.z, a1.w);
    dst[4] = bfpack(a2.x, a2.y); dst[5] = bfpack(a2.z, a2.w);
    dst[6] = bfpack(a3.x, a3.y); dst[7] = bfpack(a3.z, a3.w);
    if (hh2 == 0) {
      jl[pp] = jj;
      const float cix = xyz[i*9+3], ciy = xyz[i*9+4], ciz = xyz[i*9+5];
      const float cjx = xyz[jj*9+3], cjy = xyz[jj*9+4], cjz = xyz[jj*9+5];
      relv[pp][0] = cjx - cix;
      relv[pp][1] = cjy - ciy;
      relv[pp][2] = cjz - ciz;
      const float dx = __fadd_rn(cix, -cjx), dy = __fadd_rn(ciy, -cjy),
                  dz = __fadd_rn(ciz, -cjz);
      Dvv[pp] = sqrtf(__fadd_rn(__fadd_rn(__fadd_rn(__fmul_rn(dx,dx),
                        __fmul_rn(dy,dy)), __fmul_rn(dz,dz)), 1e-8f));
      const float offv = (float)(idx[jj] - idx[i]);
      const float sg = (offv > 0.f) ? 1.f : ((offv < 0.f) ? -1.f : 0.f);
      xsepv[pp] = sg * logf(fabsf(offv) + 1.f);
    }
  }
  __syncthreads();

  // ---- phase C1': edge0 into A, two 64-edge sub-passes ----
  unsigned (*pairB)[65] = (unsigned (*)[65])U;
  for (int sub = 0; sub < 2; ++sub) {
    {  // coalesced stage of 64 pair rows -> bf16 LDS, f32 stats
      const int r = t >> 2, qq = t & 3;
      const float* prow = pair + ((size_t)i*LL + jl[sub*64 + r])*128 + qq*32;
      float s = 0.f, ss = 0.f;
#pragma unroll
      for (int n = 0; n < 8; ++n) {
        float4 v = ((const float4*)prow)[n];
        s  += (v.x + v.y) + (v.z + v.w);
        ss += v.x*v.x + v.y*v.y + v.z*v.z + v.w*v.w;
        pairB[r][qq*16 + n*2]     = bfpack(v.x, v.y);
        pairB[r][qq*16 + n*2 + 1] = bfpack(v.z, v.w);
      }
      sQ[r][qq] = s; ssQ[r][qq] = ss;
    }
    __syncthreads();
    if (t < 64) {
      const float s  = sQ[t][0] + sQ[t][1] + sQ[t][2] + sQ[t][3];
      const float ss = ssQ[t][0] + ssQ[t][1] + ssQ[t][2] + ssQ[t][3];
      const float pm = s * (1.f/128.f);
      const float pv = ss * (1.f/128.f) - pm*pm;
      pmv[t] = pm; prsv[t] = 1.f / sqrtf(pv + 1e-5f);
    }
    __syncthreads();
    {  // matvec: lane = local edge, wave = 8-ch strip (scalar weights)
      const int el = lane;
      const int e = sub*64 + el;
      float acc[8], acc2[8];
#pragma unroll
      for (int c = 0; c < 8; ++c) { acc[c] = 0.f; acc2[c] = 0.f; }
#pragma unroll 4
      for (int kk = 0; kk < 64; ++kk) {   // pair part, k = 2kk, 2kk+1
        const unsigned v = pairB[el][kk];
        const float al = bflo(v), ah = bfhi(v);
        const float* w0 = W_ee + (2*kk)*32   + 8*wv;   // uniform -> s_load
        const float* w1 = W_ee + (2*kk+1)*32 + 8*wv;
#pragma unroll
        for (int c = 0; c < 8; ++c)
          acc[c] = fmaf(al, w0[c], fmaf(ah, w1[c], acc[c]));
      }
      const float Dv = Dvv[e];
#pragma unroll 4
      for (int k = 0; k < 64; ++k) {      // RBF part
        const float mu = 2.f + (float)k * (20.f/63.f);
        const float u  = (Dv - mu) / 0.3125f;
        const float w  = expf(-(u*u));
        const float* wr = W_ee + (128+k)*32 + 8*wv;    // uniform
#pragma unroll
        for (int c = 0; c < 8; ++c) acc2[c] = fmaf(w, wr[c], acc2[c]);
      }
      const float pm = pmv[el], prs = prsv[el];
      const float corr = -prs * pm;
      const float xs = xsepv[e];
#pragma unroll
      for (int c = 0; c < 8; ++c) {
        const int ch = 8*wv + c;
        A[e][ch] = fmaf(prs, acc[c],
                     fmaf(corr, colsum_ee[ch],
                       fmaf(xs, W_ee[192*32 + ch], b_ee[ch] + acc2[c])));
      }
    }
    __syncthreads();
  }

  // ---- C2 phases (identical to R9) ----
  unsigned (*Bb)[33] = (unsigned (*)[33])U;

  // LN(A) in place; keep (mean, sigma) to recover raw e0 for the residual
  if (t < 128) {
    float mm = 0.f;
#pragma unroll
    for (int c = 0; c < 32; ++c) mm += A[t][c];
    mm *= (1.f/32.f);
    float vv = 0.f;
#pragma unroll
    for (int c = 0; c < 32; ++c) { float dd = A[t][c]-mm; vv += dd*dd; }
    vv *= (1.f/32.f);
    const float sg = sqrtf(vv + 1e-5f);
    const float rs = 1.f / sg;
#pragma unroll
    for (int c = 0; c < 32; ++c) A[t][c] = (A[t][c]-mm)*rs;
    mA[t] = mm; sgA[t] = sg;
  }
  __syncthreads();

  // ---- h = relu(ed @ We1 + be1): 2 edges x 16 ch (cols [16wv,16wv+16)) ----
  {
    float hacc[2][16];
#pragma unroll
    for (int m = 0; m < 2; ++m)
#pragma unroll
      for (int c = 0; c < 16; ++c) hacc[m][c] = 0.f;
#pragma unroll 4
    for (int k = 0; k < 32; ++k) {
      const float* wb = We1 + k*64 + 16*wv;     // uniform -> s_load
      const float a0 = A[lane][k], a1 = A[lane+64][k];
#pragma unroll
      for (int m = 0; m < 2; ++m) {
        const float av = m ? a1 : a0;
#pragma unroll
        for (int c = 0; c < 16; ++c) hacc[m][c] = fmaf(av, wb[c], hacc[m][c]);
      }
    }
#pragma unroll
    for (int m = 0; m < 2; ++m) {
      const int e = lane + 64*m;
#pragma unroll
      for (int n = 0; n < 8; ++n) {
        const float lo = fmaxf(hacc[m][2*n]   + be1[16*wv + 2*n],   0.f);
        const float hi = fmaxf(hacc[m][2*n+1] + be1[16*wv + 2*n+1], 0.f);
        Bb[e][8*wv + n] = bfpack(lo, hi);
      }
    }
  }
  __syncthreads();

  // ---- e2 = e0raw + h @ We2 + be2: 2 edges x 8 ch (cols [8wv,8wv+8)) ----
  {
    float e2a[2][8];
#pragma unroll
    for (int m = 0; m < 2; ++m)
#pragma unroll
      for (int c = 0; c < 8; ++c) e2a[m][c] = 0.f;
#pragma unroll 4
    for (int kk = 0; kk < 32; ++kk) {   // k = 2kk, 2kk+1
      const float* wbl = We2 + (2*kk)*32   + 8*wv;   // uniform
      const float* wbh = We2 + (2*kk+1)*32 + 8*wv;
      const unsigned v0 = Bb[lane][kk], v1 = Bb[lane+64][kk];
#pragma unroll
      for (int m = 0; m < 2; ++m) {
        const unsigned v = m ? v1 : v0;
        const float al = bflo(v), ah = bfhi(v);
#pragma unroll
        for (int c = 0; c < 8; ++c)
          e2a[m][c] = fmaf(al, wbl[c], fmaf(ah, wbh[c], e2a[m][c]));
      }
    }
#pragma unroll
    for (int m = 0; m < 2; ++m) {
      const int e = lane + 64*m;
      const float sg = sgA[e], mm = mA[e];
#pragma unroll
      for (int c = 0; c < 8; ++c) {
        const int ch = 8*wv + c;
        const float e0raw = fmaf(A[e][ch], sg, mm);   // undo LN
        A[e][ch] = e2a[m][c] + e0raw + be2[ch];
      }
    }
  }
  __syncthreads();

  // LN(e2) in place
  if (t < 128) {
    float mm = 0.f;
#pragma unroll
    for (int c = 0; c < 32; ++c) mm += A[t][c];
    mm *= (1.f/32.f);
    float vv = 0.f;
#pragma unroll
    for (int c = 0; c < 32; ++c) { float dd = A[t][c]-mm; vv += dd*dd; }
    vv *= (1.f/32.f);
    const float rs = 1.f / sqrtf(vv + 1e-5f);
#pragma unroll
    for (int c = 0; c < 32; ++c) A[t][c] = (A[t][c]-mm)*rs;
  }
  __syncthreads();

  // ---- m1 = relu([ni, nj, ed2] @ Wm1 + bm1): 2 edges x 16 ch ----
  {
    float tmp[16];   // ni part — identical for both edges
#pragma unroll
    for (int c = 0; c < 16; ++c) tmp[c] = bm1[16*wv + c];
#pragma unroll 4
    for (int k = 0; k < 32; ++k) {
      const float* wb = Wm1 + k*64 + 16*wv;   // uniform
      const float av = ni[k];
#pragma unroll
      for (int c = 0; c < 16; ++c) tmp[c] = fmaf(av, wb[c], tmp[c]);
    }
    float macc[2][16];
#pragma unroll
    for (int m = 0; m < 2; ++m)
#pragma unroll
      for (int c = 0; c < 16; ++c) macc[m][c] = 0.f;
#pragma unroll 4
    for (int kk = 0; kk < 16; ++kk) {   // h_j part (bf16 pairs)
      const float* wbl = Wm1 + (32+2*kk)*64 + 16*wv;   // uniform
      const float* wbh = Wm1 + (33+2*kk)*64 + 16*wv;
      const unsigned v0 = nd[lane][kk], v1 = nd[lane+64][kk];
#pragma unroll
      for (int m = 0; m < 2; ++m) {
        const unsigned v = m ? v1 : v0;
        const float al = bflo(v), ah = bfhi(v);
#pragma unroll
        for (int c = 0; c < 16; ++c)
          macc[m][c] = fmaf(al, wbl[c], fmaf(ah, wbh[c], macc[m][c]));
      }
    }
#pragma unroll 4
    for (int k = 0; k < 32; ++k) {  // edge part (f32 A)
      const float* wb = Wm1 + (64+k)*64 + 16*wv;   // uniform
      const float a0 = A[lane][k], a1 = A[lane+64][k];
#pragma unroll
      for (int m = 0; m < 2; ++m) {
        const float av = m ? a1 : a0;
#pragma unroll
        for (int c = 0; c < 16; ++c)
          macc[m][c] = fmaf(av, wb[c], macc[m][c]);
      }
    }
    __syncthreads();
#pragma unroll
    for (int m = 0; m < 2; ++m) {
      const int e = lane + 64*m;
#pragma unroll
      for (int n = 0; n < 8; ++n) {
        const float lo = fmaxf(macc[m][2*n]   + tmp[2*n],   0.f);
        const float hi = fmaxf(macc[m][2*n+1] + tmp[2*n+1], 0.f);
        Bb[e][8*wv + n] = bfpack(lo, hi);
      }
    }
  }
  __syncthreads();

  // ---- m2: 2 edges x 10 outs (cols [10wv,10wv+10)); expand + wave reduce ----
  {
    float p2[2][10];
#pragma unroll
    for (int m = 0; m < 2; ++m)
#pragma unroll
      for (int o = 0; o < 10; ++o) p2[m][o] = 0.f;
#pragma unroll 4
    for (int kk = 0; kk < 32; ++kk) {   // k = 2kk, 2kk+1
      const float* wr0 = Wm2 + (2*kk)*40   + 10*wv;   // uniform
      const float* wr1 = Wm2 + (2*kk+1)*40 + 10*wv;
      const unsigned v0 = Bb[lane][kk], v1 = Bb[lane+64][kk];
#pragma unroll
      for (int m = 0; m < 2; ++m) {
        const unsigned v = m ? v1 : v0;
        const float al = bflo(v), ah = bfhi(v);
#pragma unroll
        for (int o = 0; o < 10; ++o)
          p2[m][o] = fmaf(al, wr0[o], fmaf(ah, wr1[o], p2[m][o]));
      }
    }
    float outv[14];
#pragma unroll
    for (int s = 0; s < 14; ++s) outv[s] = 0.f;
#pragma unroll
    for (int m = 0; m < 2; ++m) {
      const int e = lane + 64*m;
      if (wv == 3) {   // outs 30..39: 30,31 plain; 32,33 x rel; 34..39 plain
        const float v0 = p2[m][0] + bm2[30], v1 = p2[m][1] + bm2[31];
        const float v2 = p2[m][2] + bm2[32], v3 = p2[m][3] + bm2[33];
        outv[0] += v0; outv[1] += v1;
        outv[2] = fmaf(v2, relv[e][0], outv[2]);
        outv[3] = fmaf(v2, relv[e][1], outv[3]);
        outv[4] = fmaf(v2, relv[e][2], outv[4]);
        outv[5] = fmaf(v3, relv[e][0], outv[5]);
        outv[6] = fmaf(v3, relv[e][1], outv[6]);
        outv[7] = fmaf(v3, relv[e][2], outv[7]);
#pragma unroll
        for (int o = 4; o < 10; ++o) outv[4 + o] += p2[m][o] + bm2[30 + o];
      } else {
#pragma unroll
        for (int o = 0; o < 10; ++o) outv[o] += p2[m][o] + bm2[10*wv + o];
      }
    }
#pragma unroll
    for (int s = 0; s < 14; ++s) {
      float v = outv[s];
#pragma unroll
      for (int o = 1; o < 64; o <<= 1) v += __shfl_xor(v, o);
      outv[s] = v;
    }
    if (lane == 0) {
      const int nsl = (wv == 3) ? 14 : 10;
      for (int s = 0; s < nsl; ++s) P2[wv][s] = outv[s];
    }
  }
  __syncthreads();
  if (t < 44) fin[t] = (t < 30) ? P2[t/10][t%10] : P2[3][t-30];
  __syncthreads();

  if (t < 16) {  // state_out = [node_i, m_l0] @ Wl0 + bl0
    float a = bl0[t];
#pragma unroll
    for (int k = 0; k < 32; ++k) a = fmaf(ni[k], Wl0[k*16 + t], a);
#pragma unroll
    for (int k = 0; k < 32; ++k) a = fmaf(fin[k] * (1.f/128.f), Wl0[(32+k)*16 + t], a);
    soutf[i*16 + t] = a;
    out[LL*9 + i*16 + t] = a;
  }
  if (t == 0) {  // frame update
    float ve[6], wa[6];
#pragma unroll
    for (int qq = 0; qq < 6; ++qq) ve[qq] = fin[32 + qq] * (1.f/128.f);
#pragma unroll
    for (int qq = 0; qq < 6; ++qq) wa[qq] = fin[38 + qq] * (1.f/128.f);
    float l1[9];
#pragma unroll
    for (int a = 0; a < 3; ++a)
#pragma unroll
      for (int d = 0; d < 3; ++d) l1[a*3 + d] = xyz[i*9 + a*3 + d] - xyz[i*9 + 3 + d];
    float T[3], Rv[3];
#pragma unroll
    for (int d = 0; d < 3; ++d) {
      float va0 = wa[0]*l1[d] + wa[1]*l1[3 + d] + wa[2]*l1[6 + d];
      float va1 = wa[3]*l1[d] + wa[4]*l1[3 + d] + wa[5]*l1[6 + d];
      T[d]  = (ve[d] + va0) / 10.f;
      Rv[d] = (ve[3 + d] + va1) / 100.f;
    }
    float qn = sqrtf(1.f + Rv[0]*Rv[0] + Rv[1]*Rv[1] + Rv[2]*Rv[2]);
    float qA = 1.f/qn, qB = Rv[0]/qn, qC = Rv[1]/qn, qD = Rv[2]/qn;
    float Rm[9];
    Rm[0] = qA*qA + qB*qB - qC*qC - qD*qD;
    Rm[1] = 2.f*qB*qC - 2.f*qA*qD;
    Rm[2] = 2.f*qB*qD + 2.f*qA*qC;
    Rm[3] = 2.f*qB*qC + 2.f*qA*qD;
    Rm[4] = qA*qA - qB*qB + qC*qC - qD*qD;
    Rm[5] = 2.f*qC*qD - 2.f*qA*qB;
    Rm[6] = 2.f*qB*qD - 2.f*qA*qC;
    Rm[7] = 2.f*qC*qD + 2.f*qA*qB;
    Rm[8] = qA*qA - qB*qB - qC*qC + qD*qD;
    if (rmask[i]) {
      Rm[0] = 1.f; Rm[1] = 0.f; Rm[2] = 0.f;
      Rm[3] = 0.f; Rm[4] = 1.f; Rm[5] = 0.f;
      Rm[6] = 0.f; Rm[7] = 0.f; Rm[8] = 1.f;
    }
#pragma unroll
    for (int a = 0; a < 3; ++a)
#pragma unroll
      for (int di = 0; di < 3; ++di) {
        float xn = Rm[di*3+0]*l1[a*3+0] + Rm[di*3+1]*l1[a*3+1] + Rm[di*3+2]*l1[a*3+2]
                 + xyz[i*9 + 3 + di] + T[di];
        out[i*9 + a*3 + di] = xn;
      }
  }
}

// ---------------- Kernel D: si MLP stack -> alpha ---------------------------
__global__ __launch_bounds__(128) void kernD(
    const float* __restrict__ seq_ln, const float* __restrict__ st_out,
    const float* __restrict__ Ws0, const float* __restrict__ bs0,
    const float* __restrict__ Wsi, const float* __restrict__ bsi,
    const float* __restrict__ Wp1, const float* __restrict__ bp1,
    const float* __restrict__ Wp2, const float* __restrict__ bp2,
    const float* __restrict__ Wp3, const float* __restrict__ bp3,
    const float* __restrict__ Wp4, const float* __restrict__ bp4,
    const float* __restrict__ Wout, const float* __restrict__ bout,
    float* __restrict__ out)
{
  const int i = blockIdx.x, t = threadIdx.x;
  __shared__ float x0[256], stn[16], ra[128], ga[128], rb[128], gb[128], rc[128];
  x0[t]       = seq_ln[i*256 + t];
  x0[128 + t] = seq_ln[i*256 + 128 + t];
  if (t < 16) {
    float m = 0.f;
    for (int k = 0; k < 16; ++k) m += st_out[i*16 + k];
    m *= (1.f/16.f);
    float v = 0.f;
    for (int k = 0; k < 16; ++k) { float dd = st_out[i*16 + k] - m; v += dd*dd; }
    v *= (1.f/16.f);
    stn[t] = (st_out[i*16 + t] - m) / sqrtf(v + 1e-5f);
  }
  __syncthreads();

  float si = bs0[t] + bsi[t];
  for (int k = 0; k < 256; ++k) si = fmaf(x0[k], Ws0[k*128 + t], si);
  for (int k = 0; k < 16; ++k)  si = fmaf(stn[k], Wsi[k*128 + t], si);
  ra[t] = fmaxf(si, 0.f);
  __syncthreads();
  float h = bp1[t];
  for (int k = 0; k < 128; ++k) h = fmaf(ra[k], Wp1[k*128 + t], h);
  ga[t] = fmaxf(h, 0.f);
  __syncthreads();
  float d2 = bp2[t];
  for (int k = 0; k < 128; ++k) d2 = fmaf(ga[k], Wp2[k*128 + t], d2);
  si += d2;
  rb[t] = fmaxf(si, 0.f);
  __syncthreads();
  float h2 = bp3[t];
  for (int k = 0; k < 128; ++k) h2 = fmaf(rb[k], Wp3[k*128 + t], h2);
  gb[t] = fmaxf(h2, 0.f);
  __syncthreads();
  float d4 = bp4[t];
  for (int k = 0; k < 128; ++k) d4 = fmaf(gb[k], Wp4[k*128 + t], d4);
  si += d4;
  rc[t] = fmaxf(si, 0.f);
  __syncthreads();
  if (t < 20) {
    float a = bout[t];
    for (int k = 0; k < 128; ++k) a = fmaf(rc[k], Wout[k*20 + t], a);
    out[19200 + i*20 + t] = a;
  }
}

extern "C" void kernel_launch(void* const* d_in, const int* in_sizes, int n_in,
                              void* d_out, int out_size, void* d_ws, size_t ws_size,
                              hipStream_t stream)
{
  (void)in_sizes; (void)n_in; (void)out_size; (void)ws_size;
  const float* msa   = (const float*)d_in[0];
  const float* pair  = (const float*)d_in[1];
  const float* xyz   = (const float*)d_in[2];
  const float* state = (const float*)d_in[3];
  const int*   idx   = (const int*)d_in[4];
  const unsigned char* rmask = (const unsigned char*)d_in[5];
  const float* W_en = (const float*)d_in[6];
  const float* b_en = (const float*)d_in[7];
  const float* Wn1  = (const float*)d_in[8];
  const float* bn1  = (const float*)d_in[9];
  const float* Wn2  = (const float*)d_in[10];
  const float* bn2  = (const float*)d_in[11];
  const float* W_ee = (const float*)d_in[12];
  const float* b_ee = (const float*)d_in[13];
  const float* We1  = (const float*)d_in[14];
  const float* be1  = (const float*)d_in[15];
  const float* We2  = (const float*)d_in[16];
  const float* be2  = (const float*)d_in[17];
  const float* Wm1  = (const float*)d_in[18];
  const float* bm1  = (const float*)d_in[19];
  const float* Wm2  = (const float*)d_in[20];
  const float* bm2  = (const float*)d_in[21];
  const float* Wl0  = (const float*)d_in[22];
  const float* bl0  = (const float*)d_in[23];
  const float* Ws0  = (const float*)d_in[24];
  const float* bs0  = (const float*)d_in[25];
  const float* Wsi  = (const float*)d_in[26];
  const float* bsi  = (const float*)d_in[27];
  const float* Wp1  = (const float*)d_in[28];
  const float* bp1  = (const float*)d_in[29];
  const float* Wp2  = (const float*)d_in[30];
  const float* bp2  = (const float*)d_in[31];
  const float* Wp3  = (const float*)d_in[32];
  const float* bp3  = (const float*)d_in[33];
  const float* Wp4  = (const float*)d_in[34];
  const float* bp4  = (const float*)d_in[35];
  const float* Wout = (const float*)d_in[36];
  const float* bout = (const float*)d_in[37];

  float* wsf    = (float*)d_ws;
  float* seq_ln = wsf + WS_SEQ;
  float* nodev  = wsf + WS_NODE;
  int*   nbr    = (int*)(wsf + WS_NBR);
  float* soutf  = wsf + WS_SOUT;
  float* csee   = wsf + WS_CSEE;
  float* out = (float*)d_out;

  kernP<<<1, 256, 0, stream>>>(W_ee, csee);
  kernA<<<LL, 256, 0, stream>>>(msa, state, W_en, b_en, Wn1, bn1, Wn2, bn2, seq_ln, nodev);
  kernB<<<LL, 256, 0, stream>>>(xyz, nbr);
  kernC<<<LL, 256, 0, stream>>>(pair, xyz, idx, rmask, W_ee, b_ee, csee,
                                We1, be1, We2, be2, Wm1, bm1, Wm2, bm2,
                                Wl0, bl0, nodev, nbr, soutf, out);
  kernD<<<LL, 128, 0, stream>>>(seq_ln, soutf, Ws0, bs0, Wsi, bsi, Wp1, bp1, Wp2, bp2,
                                Wp3, bp3, Wp4, bp4, Wout, bout, out);
}

// Round 11
// 130.419 us; speedup vs baseline: 1.7420x; 1.0051x over previous
//
#include <hip/hip_runtime.h>
#include <hip/hip_bf16.h>

#define LL 768
#define TOPK 128

// workspace layout (floats)
#define WS_SEQ  0                        // 768*256
#define WS_NODE (WS_SEQ + LL*256)        // 768*32
#define WS_NBR  (WS_NODE + LL*32)        // 768*128 ints
#define WS_SOUT (WS_NBR + LL*TOPK)       // 768*16
#define WS_CSEE (WS_SOUT + LL*16)        // 32

// bf16 pair pack/unpack (RNE)
__device__ __forceinline__ unsigned bfpack(float a, float b) {
  unsigned ua = __float_as_uint(a);
  ua = (ua + 0x7fffu + ((ua >> 16) & 1u)) >> 16;
  unsigned ub = __float_as_uint(b);
  ub = (ub + 0x7fffu + ((ub >> 16) & 1u)) & 0xffff0000u;
  return ua | ub;
}
__device__ __forceinline__ float bflo(unsigned v) { return __uint_as_float(v << 16); }
__device__ __forceinline__ float bfhi(unsigned v) { return __uint_as_float(v & 0xffff0000u); }

__device__ __forceinline__ float block_sum_256(float v, float* red, int t) {
#pragma unroll
  for (int o = 32; o > 0; o >>= 1) v += __shfl_xor(v, o, 64);
  __syncthreads();
  if ((t & 63) == 0) red[t >> 6] = v;
  __syncthreads();
  return red[0] + red[1] + red[2] + red[3];
}

// ---------------- Kernel P: column sums (LN-linearity hoist) ---------------
__global__ __launch_bounds__(256) void kernP(const float* __restrict__ W_ee,
                                             float* __restrict__ colsum_ee)
{
  __shared__ float part[8][33];
  const int c = threadIdx.x & 31, sg = threadIdx.x >> 5;
  float s = 0.f;
  for (int k = sg*16; k < sg*16 + 16; ++k) s += W_ee[k*32 + c];
  part[sg][c] = s;
  __syncthreads();
  if (threadIdx.x < 32) {
    float tot = 0.f;
#pragma unroll
    for (int g = 0; g < 8; ++g) tot += part[g][threadIdx.x];
    colsum_ee[threadIdx.x] = tot;
  }
}

// ---------------- Kernel A: seq LN, state LN, node MLP + LN ----------------
__global__ __launch_bounds__(256) void kernA(
    const float* __restrict__ msa, const float* __restrict__ state,
    const float* __restrict__ W_en, const float* __restrict__ b_en,
    const float* __restrict__ Wn1, const float* __restrict__ bn1,
    const float* __restrict__ Wn2, const float* __restrict__ bn2,
    float* __restrict__ seq_ln, float* __restrict__ nodeo)
{
  const int i = blockIdx.x, t = threadIdx.x;
  __shared__ float x[256];
  __shared__ float red[4];
  __shared__ float sn[16], n0[32], tn[32], hh[64], n1v[32];
  __shared__ float part[8][33];

  float v = msa[i*256 + t];
  float mean = block_sum_256(v, red, t) * (1.f/256.f);
  float d = v - mean;
  float var = block_sum_256(d*d, red, t) * (1.f/256.f);
  float xn = d / sqrtf(var + 1e-5f);
  x[t] = xn;
  seq_ln[i*256 + t] = xn;

  if (t < 16) {
    float m2 = 0.f;
    for (int k = 0; k < 16; ++k) m2 += state[i*16 + k];
    m2 *= (1.f/16.f);
    float v2 = 0.f;
    for (int k = 0; k < 16; ++k) { float dd = state[i*16 + k] - m2; v2 += dd*dd; }
    v2 *= (1.f/16.f);
    sn[t] = (state[i*16 + t] - m2) / sqrtf(v2 + 1e-5f);
  }
  __syncthreads();

  {  // k-split matvec over ALL 256 threads: g = k-group, c = channel
    const int g = t >> 5, c = t & 31;
    float p = 0.f;
    for (int k = g*32; k < g*32 + 32; ++k) p = fmaf(x[k], W_en[k*32 + c], p);
    if (g == 7)
      for (int k = 0; k < 16; ++k) p = fmaf(sn[k], W_en[(256+k)*32 + c], p);
    part[g][c] = p;
  }
  __syncthreads();
  if (t < 32) {
    float a = b_en[t];
#pragma unroll
    for (int g = 0; g < 8; ++g) a += part[g][t];
    n0[t] = a;
  }
  __syncthreads();
  if (t < 32) {
    float m = 0.f;
    for (int k = 0; k < 32; ++k) m += n0[k];
    m *= (1.f/32.f);
    float vv = 0.f;
    for (int k = 0; k < 32; ++k) { float dd = n0[k] - m; vv += dd*dd; }
    vv *= (1.f/32.f);
    tn[t] = (n0[t] - m) / sqrtf(vv + 1e-5f);
  }
  __syncthreads();
  if (t < 64) {
    float a = bn1[t];
    for (int k = 0; k < 32; ++k) a = fmaf(tn[k], Wn1[k*64 + t], a);
    hh[t] = fmaxf(a, 0.f);
  }
  __syncthreads();
  if (t < 32) {
    float a = n0[t] + bn2[t];
    for (int k = 0; k < 64; ++k) a = fmaf(hh[k], Wn2[k*32 + t], a);
    n1v[t] = a;
  }
  __syncthreads();
  if (t < 32) {
    float m = 0.f;
    for (int k = 0; k < 32; ++k) m += n1v[k];
    m *= (1.f/32.f);
    float vv = 0.f;
    for (int k = 0; k < 32; ++k) { float dd = n1v[k] - m; vv += dd*dd; }
    vv *= (1.f/32.f);
    nodeo[i*32 + t] = (n1v[t] - m) / sqrtf(vv + 1e-5f);
  }
}

// ---------------- Kernel B: top-128 nearest via 4-pass radix select --------
__global__ __launch_bounds__(256) void kernB(const float* __restrict__ xyz,
                                             int* __restrict__ nbr)
{
  const int i = blockIdx.x, t = threadIdx.x;
  const int lane = t & 63, wv = t >> 6;
  __shared__ unsigned hist[256];
  __shared__ int selBin, below;
  __shared__ unsigned wcL[4], wcE[4];

  const float cix = xyz[i*9+3], ciy = xyz[i*9+4], ciz = xyz[i*9+5];
  unsigned key[3];
#pragma unroll
  for (int r = 0; r < 3; ++r) {
    const int j = r*256 + t;
    float dx = __fadd_rn(cix, -xyz[j*9+3]);
    float dy = __fadd_rn(ciy, -xyz[j*9+4]);
    float dz = __fadd_rn(ciz, -xyz[j*9+5]);
    float Dv = sqrtf(__fadd_rn(__fadd_rn(__fadd_rn(__fmul_rn(dx,dx),
                       __fmul_rn(dy,dy)), __fmul_rn(dz,dz)), 1e-8f));
    key[r] = __float_as_uint(Dv);
  }

  unsigned prefix = 0;
  int rank = 127, cntLess = 0;
#pragma unroll
  for (int pass = 0; pass < 4; ++pass) {
    const int shift = 24 - pass*8;
    const unsigned hiMask = (pass == 0) ? 0u : (0xFFFFFFFFu << (shift + 8));
    hist[t] = 0;
    __syncthreads();
#pragma unroll
    for (int r = 0; r < 3; ++r)
      if ((key[r] & hiMask) == (prefix & hiMask))
        atomicAdd(&hist[(key[r] >> shift) & 0xffu], 1u);
    __syncthreads();
    if (t < 64) {
      unsigned s0 = hist[t*4], s1 = hist[t*4+1], s2 = hist[t*4+2], s3 = hist[t*4+3];
      int tot = (int)(s0 + s1 + s2 + s3);
      int inc = tot;
#pragma unroll
      for (int o = 1; o < 64; o <<= 1) {
        int v = __shfl_up(inc, o);
        if (t >= o) inc += v;
      }
      int excl = inc - tot;
      if (rank >= excl && rank < inc) {
        int c = excl, bsel = t*4;
        if (rank >= c + (int)s0) { c += (int)s0; bsel = t*4+1;
          if (rank >= c + (int)s1) { c += (int)s1; bsel = t*4+2;
            if (rank >= c + (int)s2) { c += (int)s2; bsel = t*4+3; } } }
        selBin = bsel; below = c;
      }
    }
    __syncthreads();
    prefix |= ((unsigned)selBin) << shift;
    rank -= below;
    cntLess += below;
    __syncthreads();
  }
  const unsigned thr = prefix;

  const unsigned long long lmask = (1ull << lane) - 1ull;
  unsigned baseLt = 0, baseEq = (unsigned)cntLess;
#pragma unroll
  for (int r = 0; r < 3; ++r) {
    const int j = r*256 + t;
    const bool pl = key[r] < thr;
    const bool pe = key[r] == thr;
    unsigned long long balL = __ballot(pl);
    unsigned long long balE = __ballot(pe);
    unsigned preL = (unsigned)__popcll(balL & lmask);
    unsigned preE = (unsigned)__popcll(balE & lmask);
    if (lane == 0) { wcL[wv] = (unsigned)__popcll(balL); wcE[wv] = (unsigned)__popcll(balE); }
    __syncthreads();
    unsigned wbL = 0, wbE = 0, totL = 0, totE = 0;
#pragma unroll
    for (int w = 0; w < 4; ++w) {
      if (w < wv) { wbL += wcL[w]; wbE += wcE[w]; }
      totL += wcL[w]; totE += wcE[w];
    }
    if (pl) nbr[i*TOPK + baseLt + wbL + preL] = j;
    if (pe) {
      unsigned pos = baseEq + wbE + preE;
      if (pos < TOPK) nbr[i*TOPK + pos] = j;
    }
    baseLt += totL; baseEq += totE;
    __syncthreads();
  }
}

// ---------------- Kernel C (FUSED C1+C2), 4 blocks/CU -----------------------
// A now bf16-pair-packed (Ab); staging stats via quad shuffle; LDS ~38 KB.
__global__ __launch_bounds__(256, 4) void kernC(
    const float* __restrict__ pair, const float* __restrict__ xyz,
    const int* __restrict__ idx, const unsigned char* __restrict__ rmask,
    const float* __restrict__ W_ee, const float* __restrict__ b_ee,
    const float* __restrict__ colsum_ee,
    const float* __restrict__ We1, const float* __restrict__ be1,
    const float* __restrict__ We2, const float* __restrict__ be2,
    const float* __restrict__ Wm1, const float* __restrict__ bm1,
    const float* __restrict__ Wm2, const float* __restrict__ bm2,
    const float* __restrict__ Wl0, const float* __restrict__ bl0,
    const float* __restrict__ node, const int* __restrict__ nbr,
    float* __restrict__ soutf, float* __restrict__ out)
{
  const int i = blockIdx.x, t = threadIdx.x;
  const int lane = t & 63;
  const int wv = __builtin_amdgcn_readfirstlane(t >> 6);   // uniform 0..3
  __shared__ unsigned Ab[128][17];     // e0 -> ed -> e2 -> ed2 (bf16 pairs)
  __shared__ unsigned U[128*33];       // pairB[64][65] then Bb[128][33]
  __shared__ unsigned nd[128][17];     // node rows (bf16 pairs)
  __shared__ int   jl[128];
  __shared__ float Dvv[128], xsepv[128];
  __shared__ float relv[128][3];
  __shared__ float ni[32];
  __shared__ float pmv[64], prsv[64];
  __shared__ float mA[128], sgA[128];
  __shared__ float P2[4][14];
  __shared__ float fin[44];

  // ---- phase 0: stage ni, nd, jl, relv, Dv, xsep ----
  if (t < 32) ni[t] = node[i*32 + t];
  {
    const int pp = t >> 1, hh2 = t & 1;
    const int jj = nbr[i*TOPK + pp];
    const float4* nr = (const float4*)(node + jj*32 + hh2*16);
    float4 a0 = nr[0], a1 = nr[1], a2 = nr[2], a3 = nr[3];
    unsigned* dst = &nd[pp][hh2*8];
    dst[0] = bfpack(a0.x, a0.y); dst[1] = bfpack(a0.z, a0.w);
    dst[2] = bfpack(a1.x, a1.y); dst[3] = bfpack(a1.z, a1.w);
    dst[4] = bfpack(a2.x, a2.y); dst[5] = bfpack(a2.z, a2.w);
    dst[6] = bfpack(a3.x, a3.y); dst[7] = bfpack(a3.z, a3.w);
    if (hh2 == 0) {
      jl[pp] = jj;
      const float cix = xyz[i*9+3], ciy = xyz[i*9+4], ciz = xyz[i*9+5];
      const float cjx = xyz[jj*9+3], cjy = xyz[jj*9+4], cjz = xyz[jj*9+5];
      relv[pp][0] = cjx - cix;
      relv[pp][1] = cjy - ciy;
      relv[pp][2] = cjz - ciz;
      const float dx = __fadd_rn(cix, -cjx), dy = __fadd_rn(ciy, -cjy),
                  dz = __fadd_rn(ciz, -cjz);
      Dvv[pp] = sqrtf(__fadd_rn(__fadd_rn(__fadd_rn(__fmul_rn(dx,dx),
                        __fmul_rn(dy,dy)), __fmul_rn(dz,dz)), 1e-8f));
      const float offv = (float)(idx[jj] - idx[i]);
      const float sg = (offv > 0.f) ? 1.f : ((offv < 0.f) ? -1.f : 0.f);
      xsepv[pp] = sg * logf(fabsf(offv) + 1.f);
    }
  }
  __syncthreads();

  // ---- phase C1': edge0 into Ab, two 64-edge sub-passes ----
  unsigned (*pairB)[65] = (unsigned (*)[65])U;
  for (int sub = 0; sub < 2; ++sub) {
    {  // coalesced stage of 64 pair rows -> bf16 LDS; stats via quad shuffle
      const int r = t >> 2, qq = t & 3;
      const float* prow = pair + ((size_t)i*LL + jl[sub*64 + r])*128 + qq*32;
      float s = 0.f, ss = 0.f;
#pragma unroll
      for (int n = 0; n < 8; ++n) {
        float4 v = ((const float4*)prow)[n];
        s  += (v.x + v.y) + (v.z + v.w);
        ss += v.x*v.x + v.y*v.y + v.z*v.z + v.w*v.w;
        pairB[r][qq*16 + n*2]     = bfpack(v.x, v.y);
        pairB[r][qq*16 + n*2 + 1] = bfpack(v.z, v.w);
      }
      s  += __shfl_xor(s, 1);  s  += __shfl_xor(s, 2);
      ss += __shfl_xor(ss, 1); ss += __shfl_xor(ss, 2);
      if (qq == 0) {
        const float pm = s * (1.f/128.f);
        const float pv = ss * (1.f/128.f) - pm*pm;
        pmv[r] = pm; prsv[r] = 1.f / sqrtf(pv + 1e-5f);
      }
    }
    __syncthreads();
    {  // matvec: lane = local edge, wave = 8-ch strip (scalar weights)
      const int el = lane;
      const int e = sub*64 + el;
      float acc[8], acc2[8];
#pragma unroll
      for (int c = 0; c < 8; ++c) { acc[c] = 0.f; acc2[c] = 0.f; }
#pragma unroll 4
      for (int kk = 0; kk < 64; ++kk) {   // pair part, k = 2kk, 2kk+1
        const unsigned v = pairB[el][kk];
        const float al = bflo(v), ah = bfhi(v);
        const float* w0 = W_ee + (2*kk)*32   + 8*wv;   // uniform -> s_load
        const float* w1 = W_ee + (2*kk+1)*32 + 8*wv;
#pragma unroll
        for (int c = 0; c < 8; ++c)
          acc[c] = fmaf(al, w0[c], fmaf(ah, w1[c], acc[c]));
      }
      const float Dv = Dvv[e];
#pragma unroll 4
      for (int k = 0; k < 64; ++k) {      // RBF part
        const float mu = 2.f + (float)k * (20.f/63.f);
        const float u  = (Dv - mu) / 0.3125f;
        const float w  = expf(-(u*u));
        const float* wr = W_ee + (128+k)*32 + 8*wv;    // uniform
#pragma unroll
        for (int c = 0; c < 8; ++c) acc2[c] = fmaf(w, wr[c], acc2[c]);
      }
      const float pm = pmv[el], prs = prsv[el];
      const float corr = -prs * pm;
      const float xs = xsepv[e];
      float val[8];
#pragma unroll
      for (int c = 0; c < 8; ++c) {
        const int ch = 8*wv + c;
        val[c] = fmaf(prs, acc[c],
                   fmaf(corr, colsum_ee[ch],
                     fmaf(xs, W_ee[192*32 + ch], b_ee[ch] + acc2[c])));
      }
#pragma unroll
      for (int n = 0; n < 4; ++n)
        Ab[e][4*wv + n] = bfpack(val[2*n], val[2*n+1]);
    }
    __syncthreads();
  }

  // ---- C2 phases ----
  unsigned (*Bb)[33] = (unsigned (*)[33])U;

  // LN(Ab) in place; keep (mean, sigma) for the residual undo
  if (t < 128) {
    float av[32];
#pragma unroll
    for (int kk = 0; kk < 16; ++kk) {
      const unsigned v = Ab[t][kk];
      av[2*kk] = bflo(v); av[2*kk+1] = bfhi(v);
    }
    float mm = 0.f;
#pragma unroll
    for (int c = 0; c < 32; ++c) mm += av[c];
    mm *= (1.f/32.f);
    float vv = 0.f;
#pragma unroll
    for (int c = 0; c < 32; ++c) { float dd = av[c]-mm; vv += dd*dd; }
    vv *= (1.f/32.f);
    const float sg = sqrtf(vv + 1e-5f);
    const float rs = 1.f / sg;
#pragma unroll
    for (int kk = 0; kk < 16; ++kk)
      Ab[t][kk] = bfpack((av[2*kk]-mm)*rs, (av[2*kk+1]-mm)*rs);
    mA[t] = mm; sgA[t] = sg;
  }
  __syncthreads();

  // ---- h = relu(ed @ We1 + be1): 2 edges x 16 ch (cols [16wv,16wv+16)) ----
  {
    float hacc[2][16];
#pragma unroll
    for (int m = 0; m < 2; ++m)
#pragma unroll
      for (int c = 0; c < 16; ++c) hacc[m][c] = 0.f;
#pragma unroll 4
    for (int kk = 0; kk < 16; ++kk) {   // k = 2kk, 2kk+1
      const float* wbl = We1 + (2*kk)*64 + 16*wv;     // uniform -> s_load
      const float* wbh = We1 + (2*kk+1)*64 + 16*wv;
      const unsigned v0 = Ab[lane][kk], v1 = Ab[lane+64][kk];
#pragma unroll
      for (int m = 0; m < 2; ++m) {
        const unsigned v = m ? v1 : v0;
        const float al = bflo(v), ah = bfhi(v);
#pragma unroll
        for (int c = 0; c < 16; ++c)
          hacc[m][c] = fmaf(al, wbl[c], fmaf(ah, wbh[c], hacc[m][c]));
      }
    }
#pragma unroll
    for (int m = 0; m < 2; ++m) {
      const int e = lane + 64*m;
#pragma unroll
      for (int n = 0; n < 8; ++n) {
        const float lo = fmaxf(hacc[m][2*n]   + be1[16*wv + 2*n],   0.f);
        const float hi = fmaxf(hacc[m][2*n+1] + be1[16*wv + 2*n+1], 0.f);
        Bb[e][8*wv + n] = bfpack(lo, hi);
      }
    }
  }
  __syncthreads();

  // ---- e2 = e0raw + h @ We2 + be2: 2 edges x 8 ch (cols [8wv,8wv+8)) ----
  {
    float e2a[2][8];
#pragma unroll
    for (int m = 0; m < 2; ++m)
#pragma unroll
      for (int c = 0; c < 8; ++c) e2a[m][c] = 0.f;
#pragma unroll 4
    for (int kk = 0; kk < 32; ++kk) {   // k = 2kk, 2kk+1
      const float* wbl = We2 + (2*kk)*32   + 8*wv;   // uniform
      const float* wbh = We2 + (2*kk+1)*32 + 8*wv;
      const unsigned v0 = Bb[lane][kk], v1 = Bb[lane+64][kk];
#pragma unroll
      for (int m = 0; m < 2; ++m) {
        const unsigned v = m ? v1 : v0;
        const float al = bflo(v), ah = bfhi(v);
#pragma unroll
        for (int c = 0; c < 8; ++c)
          e2a[m][c] = fmaf(al, wbl[c], fmaf(ah, wbh[c], e2a[m][c]));
      }
    }
#pragma unroll
    for (int m = 0; m < 2; ++m) {
      const int e = lane + 64*m;
      const float sg = sgA[e], mm = mA[e];
#pragma unroll
      for (int n = 0; n < 4; ++n) {
        const int ch0 = 8*wv + 2*n;
        const unsigned old = Ab[e][4*wv + n];
        const float e0lo = fmaf(bflo(old), sg, mm);
        const float e0hi = fmaf(bfhi(old), sg, mm);
        Ab[e][4*wv + n] = bfpack(e2a[m][2*n]   + e0lo + be2[ch0],
                                 e2a[m][2*n+1] + e0hi + be2[ch0+1]);
      }
    }
  }
  __syncthreads();

  // LN(e2) in place
  if (t < 128) {
    float av[32];
#pragma unroll
    for (int kk = 0; kk < 16; ++kk) {
      const unsigned v = Ab[t][kk];
      av[2*kk] = bflo(v); av[2*kk+1] = bfhi(v);
    }
    float mm = 0.f;
#pragma unroll
    for (int c = 0; c < 32; ++c) mm += av[c];
    mm *= (1.f/32.f);
    float vv = 0.f;
#pragma unroll
    for (int c = 0; c < 32; ++c) { float dd = av[c]-mm; vv += dd*dd; }
    vv *= (1.f/32.f);
    const float rs = 1.f / sqrtf(vv + 1e-5f);
#pragma unroll
    for (int kk = 0; kk < 16; ++kk)
      Ab[t][kk] = bfpack((av[2*kk]-mm)*rs, (av[2*kk+1]-mm)*rs);
  }
  __syncthreads();

  // ---- m1 = relu([ni, nj, ed2] @ Wm1 + bm1): 2 edges x 16 ch ----
  {
    float tmp[16];   // ni part — identical for both edges
#pragma unroll
    for (int c = 0; c < 16; ++c) tmp[c] = bm1[16*wv + c];
#pragma unroll 4
    for (int k = 0; k < 32; ++k) {
      const float* wb = Wm1 + k*64 + 16*wv;   // uniform
      const float av = ni[k];
#pragma unroll
      for (int c = 0; c < 16; ++c) tmp[c] = fmaf(av, wb[c], tmp[c]);
    }
    float macc[2][16];
#pragma unroll
    for (int m = 0; m < 2; ++m)
#pragma unroll
      for (int c = 0; c < 16; ++c) macc[m][c] = 0.f;
#pragma unroll 4
    for (int kk = 0; kk < 16; ++kk) {   // h_j part (bf16 pairs)
      const float* wbl = Wm1 + (32+2*kk)*64 + 16*wv;   // uniform
      const float* wbh = Wm1 + (33+2*kk)*64 + 16*wv;
      const unsigned v0 = nd[lane][kk], v1 = nd[lane+64][kk];
#pragma unroll
      for (int m = 0; m < 2; ++m) {
        const unsigned v = m ? v1 : v0;
        const float al = bflo(v), ah = bfhi(v);
#pragma unroll
        for (int c = 0; c < 16; ++c)
          macc[m][c] = fmaf(al, wbl[c], fmaf(ah, wbh[c], macc[m][c]));
      }
    }
#pragma unroll 4
    for (int kk = 0; kk < 16; ++kk) {   // edge part (bf16 pairs from Ab)
      const float* wbl = Wm1 + (64+2*kk)*64 + 16*wv;   // uniform
      const float* wbh = Wm1 + (65+2*kk)*64 + 16*wv;
      const unsigned v0 = Ab[lane][kk], v1 = Ab[lane+64][kk];
#pragma unroll
      for (int m = 0; m < 2; ++m) {
        const unsigned v = m ? v1 : v0;
        const float al = bflo(v), ah = bfhi(v);
#pragma unroll
        for (int c = 0; c < 16; ++c)
          macc[m][c] = fmaf(al, wbl[c], fmaf(ah, wbh[c], macc[m][c]));
      }
    }
    __syncthreads();   // all Bb reads (e2 phase) complete before overwrite
#pragma unroll
    for (int m = 0; m < 2; ++m) {
      const int e = lane + 64*m;
#pragma unroll
      for (int n = 0; n < 8; ++n) {
        const float lo = fmaxf(macc[m][2*n]   + tmp[2*n],   0.f);
        const float hi = fmaxf(macc[m][2*n+1] + tmp[2*n+1], 0.f);
        Bb[e][8*wv + n] = bfpack(lo, hi);
      }
    }
  }
  __syncthreads();

  // ---- m2: 2 edges x 10 outs (cols [10wv,10wv+10)); expand + wave reduce ----
  {
    float p2[2][10];
#pragma unroll
    for (int m = 0; m < 2; ++m)
#pragma unroll
      for (int o = 0; o < 10; ++o) p2[m][o] = 0.f;
#pragma unroll 4
    for (int kk = 0; kk < 32; ++kk) {   // k = 2kk, 2kk+1
      const float* wr0 = Wm2 + (2*kk)*40   + 10*wv;   // uniform
      const float* wr1 = Wm2 + (2*kk+1)*40 + 10*wv;
      const unsigned v0 = Bb[lane][kk], v1 = Bb[lane+64][kk];
#pragma unroll
      for (int m = 0; m < 2; ++m) {
        const unsigned v = m ? v1 : v0;
        const float al = bflo(v), ah = bfhi(v);
#pragma unroll
        for (int o = 0; o < 10; ++o)
          p2[m][o] = fmaf(al, wr0[o], fmaf(ah, wr1[o], p2[m][o]));
      }
    }
    float outv[14];
#pragma unroll
    for (int s = 0; s < 14; ++s) outv[s] = 0.f;
#pragma unroll
    for (int m = 0; m < 2; ++m) {
      const int e = lane + 64*m;
      if (wv == 3) {   // outs 30..39: 30,31 plain; 32,33 x rel; 34..39 plain
        const float v0 = p2[m][0] + bm2[30], v1 = p2[m][1] + bm2[31];
        const float v2 = p2[m][2] + bm2[32], v3 = p2[m][3] + bm2[33];
        outv[0] += v0; outv[1] += v1;
        outv[2] = fmaf(v2, relv[e][0], outv[2]);
        outv[3] = fmaf(v2, relv[e][1], outv[3]);
        outv[4] = fmaf(v2, relv[e][2], outv[4]);
        outv[5] = fmaf(v3, relv[e][0], outv[5]);
        outv[6] = fmaf(v3, relv[e][1], outv[6]);
        outv[7] = fmaf(v3, relv[e][2], outv[7]);
#pragma unroll
        for (int o = 4; o < 10; ++o) outv[4 + o] += p2[m][o] + bm2[30 + o];
      } else {
#pragma unroll
        for (int o = 0; o < 10; ++o) outv[o] += p2[m][o] + bm2[10*wv + o];
      }
    }
#pragma unroll
    for (int s = 0; s < 14; ++s) {
      float v = outv[s];
#pragma unroll
      for (int o = 1; o < 64; o <<= 1) v += __shfl_xor(v, o);
      outv[s] = v;
    }
    if (lane == 0) {
      const int nsl = (wv == 3) ? 14 : 10;
      for (int s = 0; s < nsl; ++s) P2[wv][s] = outv[s];
    }
  }
  __syncthreads();
  if (t < 44) fin[t] = (t < 30) ? P2[t/10][t%10] : P2[3][t-30];
  __syncthreads();

  if (t < 16) {  // state_out = [node_i, m_l0] @ Wl0 + bl0
    float a = bl0[t];
#pragma unroll
    for (int k = 0; k < 32; ++k) a = fmaf(ni[k], Wl0[k*16 + t], a);
#pragma unroll
    for (int k = 0; k < 32; ++k) a = fmaf(fin[k] * (1.f/128.f), Wl0[(32+k)*16 + t], a);
    soutf[i*16 + t] = a;
    out[LL*9 + i*16 + t] = a;
  }
  if (t == 0) {  // frame update
    float ve[6], wa[6];
#pragma unroll
    for (int qq = 0; qq < 6; ++qq) ve[qq] = fin[32 + qq] * (1.f/128.f);
#pragma unroll
    for (int qq = 0; qq < 6; ++qq) wa[qq] = fin[38 + qq] * (1.f/128.f);
    float l1[9];
#pragma unroll
    for (int a = 0; a < 3; ++a)
#pragma unroll
      for (int d = 0; d < 3; ++d) l1[a*3 + d] = xyz[i*9 + a*3 + d] - xyz[i*9 + 3 + d];
    float T[3], Rv[3];
#pragma unroll
    for (int d = 0; d < 3; ++d) {
      float va0 = wa[0]*l1[d] + wa[1]*l1[3 + d] + wa[2]*l1[6 + d];
      float va1 = wa[3]*l1[d] + wa[4]*l1[3 + d] + wa[5]*l1[6 + d];
      T[d]  = (ve[d] + va0) / 10.f;
      Rv[d] = (ve[3 + d] + va1) / 100.f;
    }
    float qn = sqrtf(1.f + Rv[0]*Rv[0] + Rv[1]*Rv[1] + Rv[2]*Rv[2]);
    float qA = 1.f/qn, qB = Rv[0]/qn, qC = Rv[1]/qn, qD = Rv[2]/qn;
    float Rm[9];
    Rm[0] = qA*qA + qB*qB - qC*qC - qD*qD;
    Rm[1] = 2.f*qB*qC - 2.f*qA*qD;
    Rm[2] = 2.f*qB*qD + 2.f*qA*qC;
    Rm[3] = 2.f*qB*qC + 2.f*qA*qD;
    Rm[4] = qA*qA - qB*qB + qC*qC - qD*qD;
    Rm[5] = 2.f*qC*qD - 2.f*qA*qB;
    Rm[6] = 2.f*qB*qD - 2.f*qA*qC;
    Rm[7] = 2.f*qC*qD + 2.f*qA*qB;
    Rm[8] = qA*qA - qB*qB - qC*qC + qD*qD;
    if (rmask[i]) {
      Rm[0] = 1.f; Rm[1] = 0.f; Rm[2] = 0.f;
      Rm[3] = 0.f; Rm[4] = 1.f; Rm[5] = 0.f;
      Rm[6] = 0.f; Rm[7] = 0.f; Rm[8] = 1.f;
    }
#pragma unroll
    for (int a = 0; a < 3; ++a)
#pragma unroll
      for (int di = 0; di < 3; ++di) {
        float xn = Rm[di*3+0]*l1[a*3+0] + Rm[di*3+1]*l1[a*3+1] + Rm[di*3+2]*l1[a*3+2]
                 + xyz[i*9 + 3 + di] + T[di];
        out[i*9 + a*3 + di] = xn;
      }
  }
}

// ---------------- Kernel D: si MLP stack -> alpha (512 thr, 4-way k-split) --
__global__ __launch_bounds__(512) void kernD(
    const float* __restrict__ seq_ln, const float* __restrict__ st_out,
    const float* __restrict__ Ws0, const float* __restrict__ bs0,
    const float* __restrict__ Wsi, const float* __restrict__ bsi,
    const float* __restrict__ Wp1, const float* __restrict__ bp1,
    const float* __restrict__ Wp2, const float* __restrict__ bp2,
    const float* __restrict__ Wp3, const float* __restrict__ bp3,
    const float* __restrict__ Wp4, const float* __restrict__ bp4,
    const float* __restrict__ Wout, const float* __restrict__ bout,
    float* __restrict__ out)
{
  const int i = blockIdx.x, t = threadIdx.x;
  const int c = t & 127, g = t >> 7;   // g = 0..3 k-group
  __shared__ float x0[256], stn[16], act[128], resid[128], part[4][129];

  if (t < 256) x0[t] = seq_ln[i*256 + t];
  if (t < 16) {
    float m = 0.f;
    for (int k = 0; k < 16; ++k) m += st_out[i*16 + k];
    m *= (1.f/16.f);
    float v = 0.f;
    for (int k = 0; k < 16; ++k) { float dd = st_out[i*16 + k] - m; v += dd*dd; }
    v *= (1.f/16.f);
    stn[t] = (st_out[i*16 + t] - m) / sqrtf(v + 1e-5f);
  }
  __syncthreads();

  // L0: si = x0 @ Ws0 + stn @ Wsi + bs0 + bsi
  {
    float p = 0.f;
    for (int k = g*64; k < g*64 + 64; ++k) p = fmaf(x0[k], Ws0[k*128 + c], p);
    if (g == 0)
      for (int k = 0; k < 16; ++k) p = fmaf(stn[k], Wsi[k*128 + c], p);
    part[g][c] = p;
  }
  __syncthreads();
  if (t < 128) {
    const float si = part[0][t] + part[1][t] + part[2][t] + part[3][t]
                   + bs0[t] + bsi[t];
    resid[t] = si;
    act[t] = fmaxf(si, 0.f);
  }
  __syncthreads();

  // L1: h = relu(act @ Wp1 + bp1)
  {
    float p = 0.f;
    for (int k = g*32; k < g*32 + 32; ++k) p = fmaf(act[k], Wp1[k*128 + c], p);
    part[g][c] = p;
  }
  __syncthreads();
  if (t < 128)
    act[t] = fmaxf(part[0][t] + part[1][t] + part[2][t] + part[3][t] + bp1[t], 0.f);
  __syncthreads();

  // L2: si += h @ Wp2 + bp2; act = relu(si)
  {
    float p = 0.f;
    for (int k = g*32; k < g*32 + 32; ++k) p = fmaf(act[k], Wp2[k*128 + c], p);
    part[g][c] = p;
  }
  __syncthreads();
  if (t < 128) {
    const float si = resid[t] + part[0][t] + part[1][t] + part[2][t] + part[3][t] + bp2[t];
    resid[t] = si;
    act[t] = fmaxf(si, 0.f);
  }
  __syncthreads();

  // L3: h = relu(act @ Wp3 + bp3)
  {
    float p = 0.f;
    for (int k = g*32; k < g*32 + 32; ++k) p = fmaf(act[k], Wp3[k*128 + c], p);
    part[g][c] = p;
  }
  __syncthreads();
  if (t < 128)
    act[t] = fmaxf(part[0][t] + part[1][t] + part[2][t] + part[3][t] + bp3[t], 0.f);
  __syncthreads();

  // L4: si += h @ Wp4 + bp4; rc = relu(si)
  {
    float p = 0.f;
    for (int k = g*32; k < g*32 + 32; ++k) p = fmaf(act[k], Wp4[k*128 + c], p);
    part[g][c] = p;
  }
  __syncthreads();
  if (t < 128)
    act[t] = fmaxf(resid[t] + part[0][t] + part[1][t] + part[2][t] + part[3][t] + bp4[t], 0.f);
  __syncthreads();

  // out: alpha = rc @ Wout + bout (20 outputs)
  if (t < 20) {
    float a = bout[t];
    for (int k = 0; k < 128; ++k) a = fmaf(act[k], Wout[k*20 + t], a);
    out[19200 + i*20 + t] = a;
  }
}

extern "C" void kernel_launch(void* const* d_in, const int* in_sizes, int n_in,
                              void* d_out, int out_size, void* d_ws, size_t ws_size,
                              hipStream_t stream)
{
  (void)in_sizes; (void)n_in; (void)out_size; (void)ws_size;
  const float* msa   = (const float*)d_in[0];
  const float* pair  = (const float*)d_in[1];
  const float* xyz   = (const float*)d_in[2];
  const float* state = (const float*)d_in[3];
  const int*   idx   = (const int*)d_in[4];
  const unsigned char* rmask = (const unsigned char*)d_in[5];
  const float* W_en = (const float*)d_in[6];
  const float* b_en = (const float*)d_in[7];
  const float* Wn1  = (const float*)d_in[8];
  const float* bn1  = (const float*)d_in[9];
  const float* Wn2  = (const float*)d_in[10];
  const float* bn2  = (const float*)d_in[11];
  const float* W_ee = (const float*)d_in[12];
  const float* b_ee = (const float*)d_in[13];
  const float* We1  = (const float*)d_in[14];
  const float* be1  = (const float*)d_in[15];
  const float* We2  = (const float*)d_in[16];
  const float* be2  = (const float*)d_in[17];
  const float* Wm1  = (const float*)d_in[18];
  const float* bm1  = (const float*)d_in[19];
  const float* Wm2  = (const float*)d_in[20];
  const float* bm2  = (const float*)d_in[21];
  const float* Wl0  = (const float*)d_in[22];
  const float* bl0  = (const float*)d_in[23];
  const float* Ws0  = (const float*)d_in[24];
  const float* bs0  = (const float*)d_in[25];
  const float* Wsi  = (const float*)d_in[26];
  const float* bsi  = (const float*)d_in[27];
  const float* Wp1  = (const float*)d_in[28];
  const float* bp1  = (const float*)d_in[29];
  const float* Wp2  = (const float*)d_in[30];
  const float* bp2  = (const float*)d_in[31];
  const float* Wp3  = (const float*)d_in[32];
  const float* bp3  = (const float*)d_in[33];
  const float* Wp4  = (const float*)d_in[34];
  const float* bp4  = (const float*)d_in[35];
  const float* Wout = (const float*)d_in[36];
  const float* bout = (const float*)d_in[37];

  float* wsf    = (float*)d_ws;
  float* seq_ln = wsf + WS_SEQ;
  float* nodev  = wsf + WS_NODE;
  int*   nbr    = (int*)(wsf + WS_NBR);
  float* soutf  = wsf + WS_SOUT;
  float* csee   = wsf + WS_CSEE;
  float* out = (float*)d_out;

  kernP<<<1, 256, 0, stream>>>(W_ee, csee);
  kernA<<<LL, 256, 0, stream>>>(msa, state, W_en, b_en, Wn1, bn1, Wn2, bn2, seq_ln, nodev);
  kernB<<<LL, 256, 0, stream>>>(xyz, nbr);
  kernC<<<LL, 256, 0, stream>>>(pair, xyz, idx, rmask, W_ee, b_ee, csee,
                                We1, be1, We2, be2, Wm1, bm1, Wm2, bm2,
                                Wl0, bl0, nodev, nbr, soutf, out);
  kernD<<<LL, 512, 0, stream>>>(seq_ln, soutf, Ws0, bs0, Wsi, bsi, Wp1, bp1, Wp2, bp2,
                                Wp3, bp3, Wp4, bp4, Wout, bout, out);
}